// Round 14
// baseline (187.311 us; speedup 1.0000x reference)
//
#include <hip/hip_runtime.h>
#include <math.h>

#define NN 512
#define NN2 (NN*NN)
#define NB 32
#define NM 64

typedef __attribute__((ext_vector_type(8))) short short8v;   // 8 bf16 (4 VGPR)
typedef __attribute__((ext_vector_type(4))) float f32x4;     // MFMA acc

typedef const unsigned int __attribute__((address_space(1)))* gas_ptr;
typedef unsigned int __attribute__((address_space(3)))* las_ptr;

__device__ __forceinline__ float sigm(float x) { return 1.0f / (1.0f + expf(-x)); }

__device__ __forceinline__ unsigned short f2bf(float x) {
  unsigned u = __float_as_uint(x);
  return (unsigned short)((u + 0x7fffu + ((u >> 16) & 1u)) >> 16);   // RNE
}
__device__ __forceinline__ float bf2f(unsigned short h) {
  return __uint_as_float(((unsigned)h) << 16);
}
__device__ __forceinline__ unsigned long long u64min(unsigned long long a,
                                                     unsigned long long b) {
  return (b < a) ? b : a;
}
// u64 atomic-min on LDS via CAS loop (proven r4-r13)
__device__ __forceinline__ void amin64(unsigned long long* p, unsigned long long v) {
  unsigned long long old = *p;
  while (v < old) {
    unsigned long long assumed = old;
    old = atomicCAS(p, assumed, v);
    if (old == assumed) break;
  }
}
template <int CTRL>
__device__ __forceinline__ unsigned long long dpp_min_u64(unsigned long long x) {
  int xlo = (int)(unsigned)x, xhi = (int)(unsigned)(x >> 32);
  int ylo = __builtin_amdgcn_update_dpp(xlo, xlo, CTRL, 0xf, 0xf, false);
  int yhi = __builtin_amdgcn_update_dpp(xhi, xhi, CTRL, 0xf, 0xf, false);
  unsigned long long y = ((unsigned long long)(unsigned)yhi << 32) | (unsigned)ylo;
  return (y < x) ? y : x;
}
__device__ __forceinline__ unsigned long long grp16_min_u64(unsigned long long k) {
  k = dpp_min_u64<0x111>(k); k = dpp_min_u64<0x112>(k);
  k = dpp_min_u64<0x114>(k); k = dpp_min_u64<0x118>(k);
  return k;
}

// -------- sigmoid + bf16 hi/lo split + fused row sums-of-squares ----------------
__global__ __launch_bounds__(256) void split_kernel(const float* __restrict__ model,
                                                    const float* __restrict__ labels,
                                                    unsigned short* __restrict__ Hi,
                                                    unsigned short* __restrict__ Lo,
                                                    float* __restrict__ sq, int m0) {
  int b = blockIdx.x;
  int mL = b >> 8;
  int m = m0 + mL;
  int tid = threadIdx.x;
  size_t off = (size_t)(b & 255) * 1024 + tid * 4;
  const float* src = ((m & 1) ? labels + (size_t)(m >> 1) * NN2
                              : model + (size_t)(m >> 1) * NN2) + off;
  float4 v = *(const float4*)src;
  if (!(m & 1)) { v.x = sigm(v.x); v.y = sigm(v.y); v.z = sigm(v.z); v.w = sigm(v.w); }
  ushort4 h, l;
  h.x = f2bf(v.x); l.x = f2bf(v.x - bf2f(h.x));
  h.y = f2bf(v.y); l.y = f2bf(v.y - bf2f(h.y));
  h.z = f2bf(v.z); l.z = f2bf(v.z - bf2f(h.z));
  h.w = f2bf(v.w); l.w = f2bf(v.w - bf2f(h.w));
  *(ushort4*)(Hi + (size_t)mL * NN2 + off) = h;
  *(ushort4*)(Lo + (size_t)mL * NN2 + off) = l;
  float s = v.x * v.x + v.y * v.y + v.z * v.z + v.w * v.w;
  #pragma unroll
  for (int o = 32; o > 0; o >>= 1) s += __shfl_down(s, o);
  __shared__ float red[4];
  if ((tid & 63) == 0) red[tid >> 6] = s;
  __syncthreads();
  if (tid == 0) {
    int row0 = (b & 255) * 2;
    sq[(size_t)m * NN + row0]     = red[0] + red[1];
    sq[(size_t)m * NN + row0 + 1] = red[2] + red[3];
  }
}

// ------- distance matrix: 3-pass split-bf16 MFMA, global_load_lds staging,
//         register-lean frag scheduling + per-mi key reduction (r13, unchanged) --
__global__ __launch_bounds__(256, 3) void gemm_dist(const unsigned short* __restrict__ Hi,
                                                    const unsigned short* __restrict__ Lo,
                                                    const float* __restrict__ sq,
                                                    float* __restrict__ Dreg,
                                                    unsigned* __restrict__ maxBits,
                                                    unsigned long long* __restrict__ best1,
                                                    int m0, int nm) {
  __shared__ unsigned short P[4][128 * 32];   // Ah, Al, Bh, Bl (8 KB each)
  int id = blockIdx.x;
  int p, mL;
  if ((nm & 7) == 0) {
    int x = id & 7, t = id >> 3;
    p = t % 10;
    mL = x + 8 * (t / 10);
  } else {
    p = id % 10;
    mL = id / 10;
  }
  int by = (p >= 4) + (p >= 7) + (p >= 9);
  int bx = p - ((by * (7 - by)) >> 1);
  bool diag = (by == bx);
  int m = m0 + mL;
  const unsigned short* Hm = Hi + (size_t)mL * NN2;
  const unsigned short* Lm = Lo + (size_t)mL * NN2;

  int tid = threadIdx.x;
  int wid = tid >> 6, lane = tid & 63;
  int wy = wid >> 1, wx = wid & 1;
  int lr = lane & 15, lk = lane >> 4;

  const unsigned short* wsrcM = (wid & 1) ? Lm : Hm;
  int wrow0 = (wid < 2) ? by * 128 : bx * 128;
  bool stage = (!diag) || (wid < 2);
  int srow = lane >> 2;
  int schunk = (lane & 3) ^ ((lane >> 3) & 3);
  const unsigned short* gsrc = wsrcM + (size_t)(wrow0 + srow) * NN + schunk * 8;
  unsigned short* ldst = &P[wid & 3][0];

  f32x4 acc[4][4];
  #pragma unroll
  for (int i = 0; i < 4; ++i)
    #pragma unroll
    for (int j = 0; j < 4; ++j) acc[i][j] = (f32x4){0.f, 0.f, 0.f, 0.f};

  const unsigned short* bAh = &P[0][0];
  const unsigned short* bAl = &P[1][0];
  const unsigned short* bBh = diag ? &P[0][0] : &P[2][0];
  const unsigned short* bBl = diag ? &P[1][0] : &P[3][0];
  int sw = (lr >> 1) & 3;
  int rao = (wy * 64 + lr) * 32 + (lk ^ sw) * 8;
  int rbo = (wx * 64 + lr) * 32 + (lk ^ sw) * 8;

  for (int s = 0; s < 16; ++s) {
    int k0 = s * 32;
    if (stage) {
      #pragma unroll
      for (int i = 0; i < 8; ++i)
        __builtin_amdgcn_global_load_lds(
            (gas_ptr)(const void*)(gsrc + k0 + (size_t)i * 16 * NN),
            (las_ptr)(void*)(ldst + i * 512), 16, 0, 0);
    }
    __syncthreads();

    short8v fa[4], fb[4], fb2[4];
    #pragma unroll
    for (int i = 0; i < 4; ++i) {
      fa[i] = *(const short8v*)(bAh + rao + i * 16 * 32);   // Ah
      fb[i] = *(const short8v*)(bBh + rbo + i * 16 * 32);   // Bh
    }
    #pragma unroll
    for (int mi = 0; mi < 4; ++mi)
      #pragma unroll
      for (int ni = 0; ni < 4; ++ni)
        acc[mi][ni] = __builtin_amdgcn_mfma_f32_16x16x32_bf16(fa[mi], fb[ni], acc[mi][ni], 0, 0, 0);
    #pragma unroll
    for (int i = 0; i < 4; ++i)
      fb2[i] = *(const short8v*)(bBl + rbo + i * 16 * 32);  // Bl
    #pragma unroll
    for (int mi = 0; mi < 4; ++mi)
      #pragma unroll
      for (int ni = 0; ni < 4; ++ni)
        acc[mi][ni] = __builtin_amdgcn_mfma_f32_16x16x32_bf16(fa[mi], fb2[ni], acc[mi][ni], 0, 0, 0);
    #pragma unroll
    for (int i = 0; i < 4; ++i)
      fa[i] = *(const short8v*)(bAl + rao + i * 16 * 32);   // Al
    #pragma unroll
    for (int mi = 0; mi < 4; ++mi)
      #pragma unroll
      for (int ni = 0; ni < 4; ++ni)
        acc[mi][ni] = __builtin_amdgcn_mfma_f32_16x16x32_bf16(fa[mi], fb[ni], acc[mi][ni], 0, 0, 0);
    __syncthreads();
  }

  const float* sqm = sq + (size_t)m * NN;
  float* Dm = Dreg + (size_t)mL * NN2;
  int gr0 = by * 128 + wy * 64;
  int gc0 = bx * 128 + wx * 64;
  float tmax = 0.f;
  unsigned long long* b1 = best1 + (size_t)m * NN;
  unsigned long long ck[4];
  #pragma unroll
  for (int i = 0; i < 4; ++i) ck[i] = ~0ull;

  #pragma unroll
  for (int mi = 0; mi < 4; ++mi) {
    int rb = gr0 + mi * 16 + lk * 4;
    float sqi0 = sqm[rb + 0], sqi1 = sqm[rb + 1], sqi2 = sqm[rb + 2], sqi3 = sqm[rb + 3];
    unsigned long long rk[4];
    #pragma unroll
    for (int j = 0; j < 4; ++j) rk[j] = ~0ull;
    #pragma unroll
    for (int ni = 0; ni < 4; ++ni) {
      int col = gc0 + ni * 16 + lr;
      float sqj = sqm[col];
      f32x4 a = acc[mi][ni];
      float v0 = sqrtf(fmaxf(sqi0 + sqj - 2.f * a[0], 0.f));
      float v1 = sqrtf(fmaxf(sqi1 + sqj - 2.f * a[1], 0.f));
      float v2 = sqrtf(fmaxf(sqi2 + sqj - 2.f * a[2], 0.f));
      float v3 = sqrtf(fmaxf(sqi3 + sqj - 2.f * a[3], 0.f));
      Dm[(size_t)(rb + 0) * NN + col] = v0;
      Dm[(size_t)(rb + 1) * NN + col] = v1;
      Dm[(size_t)(rb + 2) * NN + col] = v2;
      Dm[(size_t)(rb + 3) * NN + col] = v3;
      if (!diag)
        *(float4*)(Dm + (size_t)col * NN + rb) = make_float4(v0, v1, v2, v3);
      tmax = fmaxf(tmax, fmaxf(fmaxf(v0, v1), fmaxf(v2, v3)));
      float vv[4] = {v0, v1, v2, v3};
      #pragma unroll
      for (int rg = 0; rg < 4; ++rg) {
        int row = rb + rg;
        if (!diag || col != row) {
          unsigned lo = (row < col) ? (unsigned)(row * NN + col)
                                    : (unsigned)(col * NN + row);
          unsigned long long key =
              ((unsigned long long)__float_as_uint(vv[rg]) << 32) | lo;
          rk[rg] = u64min(rk[rg], key);
          ck[ni] = u64min(ck[ni], key);
        }
      }
    }
    #pragma unroll
    for (int rg = 0; rg < 4; ++rg) {
      unsigned long long k = grp16_min_u64(rk[rg]);
      if (lr == 15) atomicMin(&b1[rb + rg], k);
    }
  }
  if (!diag) {
    #pragma unroll
    for (int ni = 0; ni < 4; ++ni) {
      unsigned long long k = ck[ni];
      k = u64min(k, __shfl_xor(k, 16));
      k = u64min(k, __shfl_xor(k, 32));
      if (lk == 0) atomicMin(&b1[gc0 + ni * 16 + lr], k);
    }
  }
  #pragma unroll
  for (int off = 32; off > 0; off >>= 1) tmax = fmaxf(tmax, __shfl_down(tmax, off));
  if (lane == 0) atomicMax(&maxBits[m], __float_as_uint(tmax));
}

// -------- phase-1 hook: emit edges, write DENSE comp labels (<=256) -------------
__global__ __launch_bounds__(512) void hook1_kernel(const unsigned long long* __restrict__ best1,
                                                    int* __restrict__ compG,
                                                    int* __restrict__ cntG,
                                                    int2* __restrict__ eo_all,
                                                    int* __restrict__ ecntG, int m0) {
  int mL = blockIdx.x, m = m0 + mL;
  const unsigned long long* b1 = best1 + (size_t)m * NN;
  int2* eo = eo_all + (size_t)m * (NN - 1);
  __shared__ int hook[NN], parent[NN], dmap[NN];
  __shared__ int ecnt, ccnt;
  int tid = threadIdx.x;
  if (tid == 0) { ecnt = 0; ccnt = 0; }
  unsigned long long b = b1[tid];
  int h;
  if (b != ~0ull) {
    int idx = (int)(unsigned)b;
    int er = idx >> 9, ec = idx & 511;
    h = (er == tid) ? ec : er;
  } else h = tid;
  hook[tid] = h;
  __syncthreads();
  bool active = (b != ~0ull);
  int p = h;
  bool mutual = active && (hook[p] == tid);
  parent[tid] = (!active) ? tid : ((mutual && tid < p) ? tid : p);
  if (active && (!mutual || tid > p)) {
    int idx = (int)(unsigned)b;
    int e = atomicAdd(&ecnt, 1);
    eo[e] = make_int2(idx >> 9, idx & 511);
  }
  __syncthreads();
  int c = tid, pp = parent[c];
  while (pp != c) { c = pp; pp = parent[c]; }
  if (parent[tid] == tid) dmap[tid] = atomicAdd(&ccnt, 1);   // roots get dense ids
  __syncthreads();
  compG[(size_t)m * NN + tid] = dmap[c];
  if (tid == 0) { ecntG[m] = ecnt; cntG[m] = ccnt; }
}

// -------- single full-D pass: build global Dc256 via per-block LDS partials -----
__global__ __launch_bounds__(512) void scan2c_kernel(const float* __restrict__ Dreg,
                                                     const int* __restrict__ compG,
                                                     unsigned long long* __restrict__ DcG,
                                                     int m0) {
  int q = blockIdx.x, mL = blockIdx.y, m = m0 + mL;
  const float* D = Dreg + (size_t)mL * NN2;
  __shared__ unsigned long long Dp[64 * 256];   // 128 KB partial (rows q*64..q*64+63)
  __shared__ int compP[NN + 64];
  __shared__ int rowc[64];
  int tid = threadIdx.x;
  int wave = tid >> 6, lane = tid & 63;
  int c0 = lane * 8;
  if (tid < NN) compP[tid + (tid >> 3)] = compG[(size_t)m * NN + tid];
  for (int i = tid; i < 16384; i += 512) Dp[i] = ~0ull;
  __syncthreads();
  #pragma unroll
  for (int rr = 0; rr < 8; ++rr) {
    int rslot = wave * 8 + rr;
    int r = q * 64 + rslot;
    int da = compP[r + (r >> 3)];
    if (lane == 0) rowc[rslot] = da;
    const float4* rp = (const float4*)(D + (size_t)r * NN + c0);
    float4 v0 = rp[0], v1 = rp[1];
    int4 cc0 = *(const int4*)(compP + c0 + (c0 >> 3));
    int4 cc1 = *(const int4*)(compP + c0 + 4 + (c0 >> 3));
    float vv[8] = {v0.x, v0.y, v0.z, v0.w, v1.x, v1.y, v1.z, v1.w};
    int cv[8] = {cc0.x, cc0.y, cc0.z, cc0.w, cc1.x, cc1.y, cc1.z, cc1.w};
    #pragma unroll
    for (int e = 0; e < 8; ++e) {
      if (cv[e] != da) {
        int col = c0 + e;
        int lo = (r < col) ? r * NN + col : col * NN + r;
        unsigned long long key = ((unsigned long long)__float_as_uint(vv[e]) << 32) | (unsigned)lo;
        amin64(&Dp[rslot * 256 + cv[e]], key);
      }
    }
  }
  __syncthreads();
  unsigned long long* dg = DcG + (size_t)mL * 65536;
  for (int i = tid; i < 16384; i += 512) {
    unsigned long long v = Dp[i];
    if (v != ~0ull) atomicMin(&dg[(size_t)rowc[i >> 8] * 256 + (i & 255)], v);
  }
}

// -------- all remaining phases on Dc256 (global, L2-hot) + fused gather ---------
__global__ __launch_bounds__(1024) void finishAll_kernel(const float* __restrict__ Dreg,
                                                         const unsigned long long* __restrict__ DcG,
                                                         const int* __restrict__ compG,
                                                         const int* __restrict__ cntG,
                                                         int2* __restrict__ eo_all,
                                                         int* __restrict__ ecntG,
                                                         const unsigned* __restrict__ maxBits,
                                                         float* __restrict__ out, int m0) {
  int mL = blockIdx.x, m = m0 + mL;
  __shared__ int c1n[NN];
  __shared__ unsigned long long best[256];
  __shared__ int compD[256], hookD[256], parentD[256];
  __shared__ float fred[16];
  __shared__ int ecnt;
  int tid = threadIdx.x;
  int wave = tid >> 6, lane = tid & 63;
  const unsigned long long* dg = DcG + (size_t)mL * 65536;
  if (tid < NN) c1n[tid] = compG[(size_t)m * NN + tid];
  if (tid < 256) compD[tid] = tid;
  if (tid == 0) ecnt = ecntG[m];
  __syncthreads();
  int C = cntG[m];
  int total = C * 256;
  int2* eo = eo_all + (size_t)m * (NN - 1);

  for (int ph = 0; ph < 8; ++ph) {
    if (ecnt >= NN - 1) break;
    if (tid < 256) best[tid] = ~0ull;
    __syncthreads();
    for (int i = tid; i < total; i += 1024) {
      unsigned long long key = dg[i];
      if (key == ~0ull) continue;
      int a = i >> 8, bb = i & 255;
      int ca = compD[a], cb = compD[bb];
      if (ca != cb) amin64(&best[ca], key);
    }
    __syncthreads();
    if (tid < C) {
      unsigned long long b = best[tid];
      int h;
      if (b != ~0ull) {
        int pid = (int)(unsigned)b;
        int er = pid >> 9, ec = pid & 511;
        int c1 = compD[c1n[er]], c2v = compD[c1n[ec]];
        h = (c1 == tid) ? c2v : c1;
      } else h = tid;
      hookD[tid] = h;
    }
    __syncthreads();
    if (tid < C) {
      unsigned long long b = best[tid];
      bool active = (b != ~0ull);
      int p = hookD[tid];
      bool mutual = active && (hookD[p] == tid);
      parentD[tid] = (!active) ? tid : ((mutual && tid < p) ? tid : p);
      if (active && (!mutual || tid > p)) {
        int pid = (int)(unsigned)b;
        int e = atomicAdd(&ecnt, 1);
        eo[e] = make_int2(pid >> 9, pid & 511);
      }
    }
    __syncthreads();
    if (tid < C) {
      int c = compD[tid], pp = parentD[c];
      while (pp != c) { c = pp; pp = parentD[c]; }
      compD[tid] = c;
    }
    __syncthreads();
  }
  __syncthreads();

  // fused loss gather
  int b = m >> 1;
  float mxX = fmaxf(__uint_as_float(maxBits[2 * b]), 1e-12f);
  float mxZ = fmaxf(__uint_as_float(maxBits[2 * b + 1]), 1e-12f);
  float rX = 1.0f / mxX, rZ = 1.0f / mxZ;
  const float* Dx = Dreg + (size_t)(mL & ~1) * NN2;
  const float* Dz = Dx + NN2;
  float acc = 0.f;
  if (tid < NN - 1) {
    int2 e = eo[tid];
    size_t off = (size_t)e.x * NN + e.y;
    float d = Dx[off] * rX - Dz[off] * rZ;
    acc = d * d;
  }
  #pragma unroll
  for (int o = 32; o > 0; o >>= 1) acc += __shfl_down(acc, o);
  if (lane == 0) fred[wave] = acc;
  __syncthreads();
  if (tid == 0) {
    float t = 0.f;
    #pragma unroll
    for (int i = 0; i < 16; ++i) t += fred[i];
    atomicAdd(out, t * (1.0f / NB));
  }
}

extern "C" void kernel_launch(void* const* d_in, const int* in_sizes, int n_in,
                              void* d_out, int out_size, void* d_ws, size_t ws_size,
                              hipStream_t stream) {
  const float* model = (const float*)d_in[0];
  const float* labels = (const float*)d_in[1];
  float* out = (float*)d_out;
  char* ws = (char*)d_ws;

  float*              sq      = (float*)(ws);                       // 131072
  unsigned*           maxBits = (unsigned*)(ws + 131072);           // -> 132096
  int2*               eo      = (int2*)(ws + 132096);               // -> 393728
  unsigned long long* best1   = (unsigned long long*)(ws + 393728); // -> 655872
  int*                compG   = (int*)(ws + 655872);                // -> 786944
  int*                ecntG   = (int*)(ws + 786944);                // -> 787200
  int*                cntG    = (int*)(ws + 787200);                // -> 787456
  size_t base = 787456;

  // per batch (2 matrices): D 2MB + Hi 1MB + Lo 1MB + Dc256 1MB = 5MB
  size_t perBatch = 2ull * (NN2 * sizeof(float) + 2ull * NN2 * 2 + 65536ull * 8);
  size_t dcap = (ws_size > base) ? (ws_size - base) : 0;
  int cb = (int)(dcap / perBatch);
  if (cb > NB) cb = NB;
  if (cb < 1) cb = 1;
  int nmc = 2 * cb;

  float* Dreg = (float*)(ws + base);
  unsigned short* Hi = (unsigned short*)(ws + base + (size_t)nmc * NN2 * sizeof(float));
  unsigned short* Lo = Hi + (size_t)nmc * NN2;
  unsigned long long* DcG = (unsigned long long*)(Lo + (size_t)nmc * NN2);

  hipMemsetAsync(d_out, 0, sizeof(float), stream);
  hipMemsetAsync(maxBits, 0, 64 * sizeof(unsigned), stream);

  for (int b0 = 0; b0 < NB; b0 += cb) {
    int nb = (NB - b0 < cb) ? (NB - b0) : cb;
    int nm = 2 * nb, m0 = 2 * b0;
    hipMemsetAsync(best1 + (size_t)m0 * NN, 0xFF, (size_t)nm * NN * 8, stream);
    hipMemsetAsync(DcG, 0xFF, (size_t)nm * 65536 * 8, stream);
    split_kernel<<<nm * 256, 256, 0, stream>>>(model, labels, Hi, Lo, sq, m0);
    gemm_dist<<<10 * nm, 256, 0, stream>>>(Hi, Lo, sq, Dreg, maxBits, best1, m0, nm);
    hook1_kernel<<<nm, 512, 0, stream>>>(best1, compG, cntG, eo, ecntG, m0);
    scan2c_kernel<<<dim3(8, nm), 512, 0, stream>>>(Dreg, compG, DcG, m0);
    finishAll_kernel<<<nm, 1024, 0, stream>>>(Dreg, DcG, compG, cntG, eo, ecntG,
                                              maxBits, out, m0);
  }
}

// Round 15
// 154.795 us; speedup vs baseline: 1.2101x; 1.2101x over previous
//
#include <hip/hip_runtime.h>
#include <math.h>

#define NN 512
#define NN2 (NN*NN)
#define NB 32
#define NM 64

typedef __attribute__((ext_vector_type(8))) short short8v;   // 8 bf16 (4 VGPR)
typedef __attribute__((ext_vector_type(4))) float f32x4;     // MFMA acc

typedef const unsigned int __attribute__((address_space(1)))* gas_ptr;
typedef unsigned int __attribute__((address_space(3)))* las_ptr;

__device__ __forceinline__ float sigm(float x) { return 1.0f / (1.0f + expf(-x)); }

__device__ __forceinline__ unsigned short f2bf(float x) {
  unsigned u = __float_as_uint(x);
  return (unsigned short)((u + 0x7fffu + ((u >> 16) & 1u)) >> 16);   // RNE
}
__device__ __forceinline__ float bf2f(unsigned short h) {
  return __uint_as_float(((unsigned)h) << 16);
}
__device__ __forceinline__ unsigned long long u64min(unsigned long long a,
                                                     unsigned long long b) {
  return (b < a) ? b : a;
}
__device__ __forceinline__ void amin64(unsigned long long* p, unsigned long long v) {
  unsigned long long old = *p;
  while (v < old) {
    unsigned long long assumed = old;
    old = atomicCAS(p, assumed, v);
    if (old == assumed) break;
  }
}
template <int CTRL>
__device__ __forceinline__ unsigned long long dpp_min_u64(unsigned long long x) {
  int xlo = (int)(unsigned)x, xhi = (int)(unsigned)(x >> 32);
  int ylo = __builtin_amdgcn_update_dpp(xlo, xlo, CTRL, 0xf, 0xf, false);
  int yhi = __builtin_amdgcn_update_dpp(xhi, xhi, CTRL, 0xf, 0xf, false);
  unsigned long long y = ((unsigned long long)(unsigned)yhi << 32) | (unsigned)ylo;
  return (y < x) ? y : x;
}
__device__ __forceinline__ unsigned long long wave_min_u64(unsigned long long k) {
  k = dpp_min_u64<0x111>(k); k = dpp_min_u64<0x112>(k);
  k = dpp_min_u64<0x114>(k); k = dpp_min_u64<0x118>(k);
  k = dpp_min_u64<0x142>(k); k = dpp_min_u64<0x143>(k);
  return k;
}
__device__ __forceinline__ unsigned long long grp16_min_u64(unsigned long long k) {
  k = dpp_min_u64<0x111>(k); k = dpp_min_u64<0x112>(k);
  k = dpp_min_u64<0x114>(k); k = dpp_min_u64<0x118>(k);
  return k;
}

// -------- sigmoid + bf16 hi/lo split + fused row sums-of-squares ----------------
__global__ __launch_bounds__(256) void split_kernel(const float* __restrict__ model,
                                                    const float* __restrict__ labels,
                                                    unsigned short* __restrict__ Hi,
                                                    unsigned short* __restrict__ Lo,
                                                    float* __restrict__ sq, int m0) {
  int b = blockIdx.x;
  int mL = b >> 8;
  int m = m0 + mL;
  int tid = threadIdx.x;
  size_t off = (size_t)(b & 255) * 1024 + tid * 4;
  const float* src = ((m & 1) ? labels + (size_t)(m >> 1) * NN2
                              : model + (size_t)(m >> 1) * NN2) + off;
  float4 v = *(const float4*)src;
  if (!(m & 1)) { v.x = sigm(v.x); v.y = sigm(v.y); v.z = sigm(v.z); v.w = sigm(v.w); }
  ushort4 h, l;
  h.x = f2bf(v.x); l.x = f2bf(v.x - bf2f(h.x));
  h.y = f2bf(v.y); l.y = f2bf(v.y - bf2f(h.y));
  h.z = f2bf(v.z); l.z = f2bf(v.z - bf2f(h.z));
  h.w = f2bf(v.w); l.w = f2bf(v.w - bf2f(h.w));
  *(ushort4*)(Hi + (size_t)mL * NN2 + off) = h;
  *(ushort4*)(Lo + (size_t)mL * NN2 + off) = l;
  float s = v.x * v.x + v.y * v.y + v.z * v.z + v.w * v.w;
  #pragma unroll
  for (int o = 32; o > 0; o >>= 1) s += __shfl_down(s, o);
  __shared__ float red[4];
  if ((tid & 63) == 0) red[tid >> 6] = s;
  __syncthreads();
  if (tid == 0) {
    int row0 = (b & 255) * 2;
    sq[(size_t)m * NN + row0]     = red[0] + red[1];
    sq[(size_t)m * NN + row0 + 1] = red[2] + red[3];
  }
}

// ------- distance matrix: 3-pass split-bf16 MFMA, DOUBLE-BUFFERED gload_lds -----
__global__ __launch_bounds__(256, 3) void gemm_dist(const unsigned short* __restrict__ Hi,
                                                    const unsigned short* __restrict__ Lo,
                                                    const float* __restrict__ sq,
                                                    float* __restrict__ Dreg,
                                                    unsigned* __restrict__ maxBits,
                                                    unsigned long long* __restrict__ best1,
                                                    int m0, int nm) {
  __shared__ unsigned short P[2][4][4096];    // 2 bufs x {Ah,Al,Bh,Bl} x 8KB = 64KB
  int id = blockIdx.x;
  int p, mL;
  if ((nm & 7) == 0) {
    int x = id & 7, t = id >> 3;
    p = t % 10;
    mL = x + 8 * (t / 10);
  } else {
    p = id % 10;
    mL = id / 10;
  }
  int by = (p >= 4) + (p >= 7) + (p >= 9);
  int bx = p - ((by * (7 - by)) >> 1);
  bool diag = (by == bx);
  int m = m0 + mL;
  const unsigned short* Hm = Hi + (size_t)mL * NN2;
  const unsigned short* Lm = Lo + (size_t)mL * NN2;

  int tid = threadIdx.x;
  int wid = tid >> 6, lane = tid & 63;
  int wy = wid >> 1, wx = wid & 1;
  int lr = lane & 15, lk = lane >> 4;

  const unsigned short* wsrcM = (wid & 1) ? Lm : Hm;
  int wrow0 = (wid < 2) ? by * 128 : bx * 128;
  bool stg = (!diag) || (wid < 2);
  int srow = lane >> 2;
  int schunk = (lane & 3) ^ ((lane >> 3) & 3);
  const unsigned short* gsrc = wsrcM + (size_t)(wrow0 + srow) * NN + schunk * 8;
  unsigned short* ldst0 = &P[0][wid & 3][0];  // + buf*16384 shorts

  f32x4 acc[4][4];
  #pragma unroll
  for (int i = 0; i < 4; ++i)
    #pragma unroll
    for (int j = 0; j < 4; ++j) acc[i][j] = (f32x4){0.f, 0.f, 0.f, 0.f};

  const unsigned short* base0 = &P[0][0][0];
  int offAh = 0, offAl = 4096;
  int offBh = diag ? 0 : 8192, offBl = diag ? 4096 : 12288;
  int sw = (lr >> 1) & 3;
  int rao = (wy * 64 + lr) * 32 + (lk ^ sw) * 8;
  int rbo = (wx * 64 + lr) * 32 + (lk ^ sw) * 8;

  // prologue: stage buffer 0 for k0 = 0
  if (stg) {
    #pragma unroll
    for (int i = 0; i < 8; ++i)
      __builtin_amdgcn_global_load_lds(
          (gas_ptr)(const void*)(gsrc + (size_t)i * 16 * NN),
          (las_ptr)(void*)(ldst0 + i * 512), 16, 0, 0);
  }

  int cur = 0;
  for (int s = 0; s < 16; ++s) {
    __syncthreads();                 // buf[cur] landed (vmcnt drained at barrier)
    if (s < 15 && stg) {             // prefetch next step into buf[cur^1];
      int k0 = (s + 1) * 32;         // latency hides under ds_reads + 48 MFMAs
      unsigned short* ld = ldst0 + (cur ^ 1) * 16384;
      #pragma unroll
      for (int i = 0; i < 8; ++i)
        __builtin_amdgcn_global_load_lds(
            (gas_ptr)(const void*)(gsrc + k0 + (size_t)i * 16 * NN),
            (las_ptr)(void*)(ld + i * 512), 16, 0, 0);
    }
    const unsigned short* bb = base0 + cur * 16384;

    short8v fa[4], fb[4], fb2[4];
    #pragma unroll
    for (int i = 0; i < 4; ++i) {
      fa[i] = *(const short8v*)(bb + offAh + rao + i * 512);   // Ah
      fb[i] = *(const short8v*)(bb + offBh + rbo + i * 512);   // Bh
    }
    #pragma unroll
    for (int mi = 0; mi < 4; ++mi)
      #pragma unroll
      for (int ni = 0; ni < 4; ++ni)
        acc[mi][ni] = __builtin_amdgcn_mfma_f32_16x16x32_bf16(fa[mi], fb[ni], acc[mi][ni], 0, 0, 0);
    #pragma unroll
    for (int i = 0; i < 4; ++i)
      fb2[i] = *(const short8v*)(bb + offBl + rbo + i * 512);  // Bl
    #pragma unroll
    for (int mi = 0; mi < 4; ++mi)
      #pragma unroll
      for (int ni = 0; ni < 4; ++ni)
        acc[mi][ni] = __builtin_amdgcn_mfma_f32_16x16x32_bf16(fa[mi], fb2[ni], acc[mi][ni], 0, 0, 0);
    #pragma unroll
    for (int i = 0; i < 4; ++i)
      fa[i] = *(const short8v*)(bb + offAl + rao + i * 512);   // Al
    #pragma unroll
    for (int mi = 0; mi < 4; ++mi)
      #pragma unroll
      for (int ni = 0; ni < 4; ++ni)
        acc[mi][ni] = __builtin_amdgcn_mfma_f32_16x16x32_bf16(fa[mi], fb[ni], acc[mi][ni], 0, 0, 0);
    cur ^= 1;
  }

  const float* sqm = sq + (size_t)m * NN;
  float* Dm = Dreg + (size_t)mL * NN2;
  int gr0 = by * 128 + wy * 64;
  int gc0 = bx * 128 + wx * 64;
  float tmax = 0.f;
  unsigned long long* b1 = best1 + (size_t)m * NN;
  unsigned long long ck[4];
  #pragma unroll
  for (int i = 0; i < 4; ++i) ck[i] = ~0ull;

  #pragma unroll
  for (int mi = 0; mi < 4; ++mi) {
    int rb = gr0 + mi * 16 + lk * 4;
    float sqi0 = sqm[rb + 0], sqi1 = sqm[rb + 1], sqi2 = sqm[rb + 2], sqi3 = sqm[rb + 3];
    unsigned long long rk[4];
    #pragma unroll
    for (int j = 0; j < 4; ++j) rk[j] = ~0ull;
    #pragma unroll
    for (int ni = 0; ni < 4; ++ni) {
      int col = gc0 + ni * 16 + lr;
      float sqj = sqm[col];
      f32x4 a = acc[mi][ni];
      float v0 = sqrtf(fmaxf(sqi0 + sqj - 2.f * a[0], 0.f));
      float v1 = sqrtf(fmaxf(sqi1 + sqj - 2.f * a[1], 0.f));
      float v2 = sqrtf(fmaxf(sqi2 + sqj - 2.f * a[2], 0.f));
      float v3 = sqrtf(fmaxf(sqi3 + sqj - 2.f * a[3], 0.f));
      Dm[(size_t)(rb + 0) * NN + col] = v0;
      Dm[(size_t)(rb + 1) * NN + col] = v1;
      Dm[(size_t)(rb + 2) * NN + col] = v2;
      Dm[(size_t)(rb + 3) * NN + col] = v3;
      if (!diag)
        *(float4*)(Dm + (size_t)col * NN + rb) = make_float4(v0, v1, v2, v3);
      tmax = fmaxf(tmax, fmaxf(fmaxf(v0, v1), fmaxf(v2, v3)));
      float vv[4] = {v0, v1, v2, v3};
      #pragma unroll
      for (int rg = 0; rg < 4; ++rg) {
        int row = rb + rg;
        if (!diag || col != row) {
          unsigned lo = (row < col) ? (unsigned)(row * NN + col)
                                    : (unsigned)(col * NN + row);
          unsigned long long key =
              ((unsigned long long)__float_as_uint(vv[rg]) << 32) | lo;
          rk[rg] = u64min(rk[rg], key);
          ck[ni] = u64min(ck[ni], key);
        }
      }
    }
    #pragma unroll
    for (int rg = 0; rg < 4; ++rg) {
      unsigned long long k = grp16_min_u64(rk[rg]);
      if (lr == 15) atomicMin(&b1[rb + rg], k);
    }
  }
  if (!diag) {
    #pragma unroll
    for (int ni = 0; ni < 4; ++ni) {
      unsigned long long k = ck[ni];
      k = u64min(k, __shfl_xor(k, 16));
      k = u64min(k, __shfl_xor(k, 32));
      if (lk == 0) atomicMin(&b1[gc0 + ni * 16 + lr], k);
    }
  }
  #pragma unroll
  for (int off = 32; off > 0; off >>= 1) tmax = fmaxf(tmax, __shfl_down(tmax, off));
  if (lane == 0) atomicMax(&maxBits[m], __float_as_uint(tmax));
}

// -------- phase-1 hook (comp = identity), emit edges, write comp labels ---------
__global__ __launch_bounds__(512) void hook1_kernel(const unsigned long long* __restrict__ best1,
                                                    int* __restrict__ compG,
                                                    int2* __restrict__ eo_all,
                                                    int* __restrict__ ecntG, int m0) {
  int mL = blockIdx.x, m = m0 + mL;
  const unsigned long long* b1 = best1 + (size_t)m * NN;
  int2* eo = eo_all + (size_t)m * (NN - 1);
  __shared__ int hook[NN], parent[NN];
  __shared__ int ecnt;
  int tid = threadIdx.x;
  if (tid == 0) ecnt = 0;
  unsigned long long b = b1[tid];
  int h;
  if (b != ~0ull) {
    int idx = (int)(unsigned)b;
    int er = idx >> 9, ec = idx & 511;
    h = (er == tid) ? ec : er;
  } else h = tid;
  hook[tid] = h;
  __syncthreads();
  bool active = (b != ~0ull);
  int p = h;
  bool mutual = active && (hook[p] == tid);
  parent[tid] = (!active) ? tid : ((mutual && tid < p) ? tid : p);
  if (active && (!mutual || tid > p)) {
    int idx = (int)(unsigned)b;
    int e = atomicAdd(&ecnt, 1);
    eo[e] = make_int2(idx >> 9, idx & 511);
  }
  __syncthreads();
  int c = tid, pp = parent[c];
  while (pp != c) { c = pp; pp = parent[c]; }
  compG[(size_t)m * NN + tid] = c;
  if (tid == 0) ecntG[m] = ecnt;
}

// -------- phase-2 scan: 8 blocks/matrix, wave-per-row, atomicMin per comp -------
__global__ __launch_bounds__(512) void scan2_kernel(const float* __restrict__ Dreg,
                                                    const int* __restrict__ compG,
                                                    unsigned long long* __restrict__ best2,
                                                    int m0) {
  int sblk = blockIdx.x, mL = blockIdx.y, m = m0 + mL;
  const float* D = Dreg + (size_t)mL * NN2;
  __shared__ int compP[NN + 64];
  int tid = threadIdx.x;
  int wave = tid >> 6, lane = tid & 63;
  int c0 = lane * 8;
  if (tid < NN) compP[tid + (tid >> 3)] = compG[(size_t)m * NN + tid];
  __syncthreads();
  unsigned long long* b2 = best2 + (size_t)m * NN;
  #pragma unroll
  for (int rr = 0; rr < 8; ++rr) {
    int r = sblk * 64 + wave * 8 + rr;
    int cr = compP[r + (r >> 3)];
    const float4* rp = (const float4*)(D + (size_t)r * NN + c0);
    float4 v0 = rp[0], v1 = rp[1];
    int4 cc0 = *(const int4*)(compP + c0 + (c0 >> 3));
    int4 cc1 = *(const int4*)(compP + c0 + 4 + (c0 >> 3));
    float vv[8] = {v0.x, v0.y, v0.z, v0.w, v1.x, v1.y, v1.z, v1.w};
    int cv[8] = {cc0.x, cc0.y, cc0.z, cc0.w, cc1.x, cc1.y, cc1.z, cc1.w};
    unsigned long long k = ~0ull;
    #pragma unroll
    for (int e = 0; e < 8; ++e) {
      if (cv[e] != cr) {
        int col = c0 + e;
        int lo = (r < col) ? r * NN + col : col * NN + r;
        unsigned long long key = ((unsigned long long)__float_as_uint(vv[e]) << 32) | (unsigned)lo;
        k = u64min(k, key);
      }
    }
    k = dpp_min_u64<0x111>(k); k = dpp_min_u64<0x112>(k);
    k = dpp_min_u64<0x114>(k); k = dpp_min_u64<0x118>(k);
    k = dpp_min_u64<0x142>(k); k = dpp_min_u64<0x143>(k);
    if (lane == 63 && k != ~0ull) atomicMin(&b2[cr], k);
  }
}

// -------- phase-2 hook + dense remap (C <= 128 guaranteed) ----------------------
__global__ __launch_bounds__(512) void hook2_kernel(const unsigned long long* __restrict__ best2,
                                                    const int* __restrict__ compG,
                                                    int* __restrict__ comp2g,
                                                    int2* __restrict__ eo_all,
                                                    int* __restrict__ ecntG,
                                                    int* __restrict__ cntG, int m0) {
  int mL = blockIdx.x, m = m0 + mL;
  const unsigned long long* b2 = best2 + (size_t)m * NN;
  int2* eo = eo_all + (size_t)m * (NN - 1);
  __shared__ int comp[NN], hook[NN], parent[NN], dmap[NN];
  __shared__ int ecnt, ccnt;
  int tid = threadIdx.x;
  if (tid == 0) { ecnt = ecntG[m]; ccnt = 0; }
  comp[tid] = compG[(size_t)m * NN + tid];
  __syncthreads();
  unsigned long long b = b2[tid];
  int h;
  if (b != ~0ull) {
    int idx = (int)(unsigned)b;
    int er = idx >> 9, ec = idx & 511;
    int c1 = comp[er], c2 = comp[ec];
    h = (c1 == tid) ? c2 : c1;
  } else h = tid;
  hook[tid] = h;
  __syncthreads();
  bool active = (b != ~0ull);
  int p = h;
  bool mutual = active && (hook[p] == tid);
  parent[tid] = (!active) ? tid : ((mutual && tid < p) ? tid : p);
  if (active && (!mutual || tid > p)) {
    int idx = (int)(unsigned)b;
    int e = atomicAdd(&ecnt, 1);
    eo[e] = make_int2(idx >> 9, idx & 511);
  }
  __syncthreads();
  int c = comp[tid], pp = parent[c];
  while (pp != c) { c = pp; pp = parent[c]; }
  __syncthreads();
  comp[tid] = c;
  __syncthreads();
  if (comp[tid] == tid) dmap[tid] = atomicAdd(&ccnt, 1);
  __syncthreads();
  comp2g[(size_t)m * NN + tid] = dmap[comp[tid]];
  if (tid == 0) { ecntG[m] = ecnt; cntG[m] = ccnt; }
}

// -------- contraction: 4 blocks/matrix build LDS-partial Dc, merge to global ----
__global__ __launch_bounds__(512) void contract_kernel(const float* __restrict__ Dreg,
                                                       const int* __restrict__ comp2g,
                                                       unsigned long long* __restrict__ DcG,
                                                       int m0) {
  int q = blockIdx.x, mL = blockIdx.y, m = m0 + mL;
  const float* D = Dreg + (size_t)mL * NN2;
  __shared__ unsigned long long Dc[128 * 128];
  __shared__ int c2P[NN + 64];
  int tid = threadIdx.x;
  int wave = tid >> 6, lane = tid & 63;
  int c0 = lane * 8;
  if (tid < NN) c2P[tid + (tid >> 3)] = comp2g[(size_t)m * NN + tid];
  for (int i = tid; i < 16384; i += 512) Dc[i] = ~0ull;
  __syncthreads();
  #pragma unroll
  for (int rr = 0; rr < 16; ++rr) {
    int r = q * 128 + wave * 16 + rr;
    int di = c2P[r + (r >> 3)];
    const float4* rp = (const float4*)(D + (size_t)r * NN + c0);
    float4 v0 = rp[0], v1 = rp[1];
    int4 cc0 = *(const int4*)(c2P + c0 + (c0 >> 3));
    int4 cc1 = *(const int4*)(c2P + c0 + 4 + (c0 >> 3));
    float vv[8] = {v0.x, v0.y, v0.z, v0.w, v1.x, v1.y, v1.z, v1.w};
    int cv[8] = {cc0.x, cc0.y, cc0.z, cc0.w, cc1.x, cc1.y, cc1.z, cc1.w};
    #pragma unroll
    for (int e = 0; e < 8; ++e) {
      if (cv[e] != di) {
        int col = c0 + e;
        int lo = (r < col) ? r * NN + col : col * NN + r;
        unsigned long long key = ((unsigned long long)__float_as_uint(vv[e]) << 32) | (unsigned)lo;
        amin64(&Dc[di * 128 + cv[e]], key);
      }
    }
  }
  __syncthreads();
  unsigned long long* dg = DcG + (size_t)mL * 16384;
  for (int i = tid; i < 16384; i += 512) {
    unsigned long long v = Dc[i];
    if (v != ~0ull) atomicMin(&dg[i], v);
  }
}

// -------- finish: LDS-resident phases on contracted matrix + fused gather -------
__global__ __launch_bounds__(1024) void finish_kernel(const float* __restrict__ Dreg,
                                                      const unsigned long long* __restrict__ DcG,
                                                      const int* __restrict__ comp2g,
                                                      const int* __restrict__ cntG,
                                                      int2* __restrict__ eo_all,
                                                      int* __restrict__ ecntG,
                                                      const unsigned* __restrict__ maxBits,
                                                      float* __restrict__ out, int m0) {
  int mL = blockIdx.x, m = m0 + mL;
  __shared__ unsigned long long Dc[16384];
  __shared__ int c2n[NN];
  __shared__ unsigned long long best[128];
  __shared__ int comp2[128], hook128[128], parent128[128];
  __shared__ float fred[16];
  __shared__ int ecnt;
  int tid = threadIdx.x;
  int wave = tid >> 6, lane = tid & 63;
  const unsigned long long* dg = DcG + (size_t)mL * 16384;
  for (int i = tid; i < 16384; i += 1024) Dc[i] = dg[i];
  if (tid < NN) c2n[tid] = comp2g[(size_t)m * NN + tid];
  if (tid < 128) comp2[tid] = tid;
  if (tid == 0) ecnt = ecntG[m];
  __syncthreads();
  int C = cntG[m];
  int2* eo = eo_all + (size_t)m * (NN - 1);

  for (int ph = 0; ph < 7; ++ph) {
    if (ecnt >= NN - 1) break;
    if (tid < 128) best[tid] = ~0ull;
    __syncthreads();
    for (int i = tid; i < C * 128; i += 1024) {
      unsigned long long key = Dc[i];
      if (key == ~0ull) continue;
      int a = i >> 7, bb = i & 127;
      int ca = comp2[a], cb = comp2[bb];
      if (ca != cb) amin64(&best[ca], key);
    }
    __syncthreads();
    if (tid < C) {
      unsigned long long b = best[tid];
      int h;
      if (b != ~0ull) {
        int pid = (int)(unsigned)b;
        int er = pid >> 9, ec = pid & 511;
        int c1 = comp2[c2n[er]], c2v = comp2[c2n[ec]];
        h = (c1 == tid) ? c2v : c1;
      } else h = tid;
      hook128[tid] = h;
    }
    __syncthreads();
    if (tid < C) {
      unsigned long long b = best[tid];
      bool active = (b != ~0ull);
      int p = hook128[tid];
      bool mutual = active && (hook128[p] == tid);
      parent128[tid] = (!active) ? tid : ((mutual && tid < p) ? tid : p);
      if (active && (!mutual || tid > p)) {
        int pid = (int)(unsigned)b;
        int e = atomicAdd(&ecnt, 1);
        eo[e] = make_int2(pid >> 9, pid & 511);
      }
    }
    __syncthreads();
    if (tid < C) {
      int c = comp2[tid], pp = parent128[c];
      while (pp != c) { c = pp; pp = parent128[c]; }
      comp2[tid] = c;
    }
    __syncthreads();
  }
  __syncthreads();

  // fused loss gather
  int b = m >> 1;
  float mxX = fmaxf(__uint_as_float(maxBits[2 * b]), 1e-12f);
  float mxZ = fmaxf(__uint_as_float(maxBits[2 * b + 1]), 1e-12f);
  float rX = 1.0f / mxX, rZ = 1.0f / mxZ;
  const float* Dx = Dreg + (size_t)(mL & ~1) * NN2;
  const float* Dz = Dx + NN2;
  float acc = 0.f;
  if (tid < NN - 1) {
    int2 e = eo[tid];
    size_t off = (size_t)e.x * NN + e.y;
    float d = Dx[off] * rX - Dz[off] * rZ;
    acc = d * d;
  }
  #pragma unroll
  for (int o = 32; o > 0; o >>= 1) acc += __shfl_down(acc, o);
  if (lane == 0) fred[wave] = acc;
  __syncthreads();
  if (tid == 0) {
    float t = 0.f;
    #pragma unroll
    for (int i = 0; i < 16; ++i) t += fred[i];
    atomicAdd(out, t * (1.0f / NB));
  }
}

extern "C" void kernel_launch(void* const* d_in, const int* in_sizes, int n_in,
                              void* d_out, int out_size, void* d_ws, size_t ws_size,
                              hipStream_t stream) {
  const float* model = (const float*)d_in[0];
  const float* labels = (const float*)d_in[1];
  float* out = (float*)d_out;
  char* ws = (char*)d_ws;

  float*              sq      = (float*)(ws);                       // 131072
  unsigned*           maxBits = (unsigned*)(ws + 131072);           // -> 132096
  int2*               eo      = (int2*)(ws + 132096);               // -> 393728
  unsigned long long* best1   = (unsigned long long*)(ws + 393728); // -> 655872
  unsigned long long* best2   = (unsigned long long*)(ws + 655872); // -> 918016
  int*                compG   = (int*)(ws + 918016);                // -> 1049088
  int*                comp2g  = (int*)(ws + 1049088);               // -> 1180160
  int*                ecntG   = (int*)(ws + 1180160);               // -> 1180416
  int*                cntG    = (int*)(ws + 1180416);               // -> 1180672
  size_t base = 1181696;

  // per batch (2 matrices): D 2MB + Hi 1MB + Lo 1MB + Dc 256KB
  size_t perBatch = 2ull * (NN2 * sizeof(float) + 2ull * NN2 * 2 + 16384 * 8);
  size_t dcap = (ws_size > base) ? (ws_size - base) : 0;
  int cb = (int)(dcap / perBatch);
  if (cb > NB) cb = NB;
  if (cb < 1) cb = 1;
  int nmc = 2 * cb;

  float* Dreg = (float*)(ws + base);
  unsigned short* Hi = (unsigned short*)(ws + base + (size_t)nmc * NN2 * sizeof(float));
  unsigned short* Lo = Hi + (size_t)nmc * NN2;
  unsigned long long* DcG = (unsigned long long*)(Lo + (size_t)nmc * NN2);

  hipMemsetAsync(d_out, 0, sizeof(float), stream);
  hipMemsetAsync(maxBits, 0, 64 * sizeof(unsigned), stream);

  for (int b0 = 0; b0 < NB; b0 += cb) {
    int nb = (NB - b0 < cb) ? (NB - b0) : cb;
    int nm = 2 * nb, m0 = 2 * b0;
    // best1 and best2 are contiguous: one 0xFF memset covers both
    hipMemsetAsync(best1 + (size_t)m0 * NN, 0xFF, (size_t)nm * NN * 16, stream);
    hipMemsetAsync(DcG, 0xFF, (size_t)nm * 16384 * 8, stream);
    split_kernel<<<nm * 256, 256, 0, stream>>>(model, labels, Hi, Lo, sq, m0);
    gemm_dist<<<10 * nm, 256, 0, stream>>>(Hi, Lo, sq, Dreg, maxBits, best1, m0, nm);
    hook1_kernel<<<nm, 512, 0, stream>>>(best1, compG, eo, ecntG, m0);
    scan2_kernel<<<dim3(8, nm), 512, 0, stream>>>(Dreg, compG, best2, m0);
    hook2_kernel<<<nm, 512, 0, stream>>>(best2, compG, comp2g, eo, ecntG, cntG, m0);
    contract_kernel<<<dim3(4, nm), 512, 0, stream>>>(Dreg, comp2g, DcG, m0);
    finish_kernel<<<nm, 1024, 0, stream>>>(Dreg, DcG, comp2g, cntG, eo, ecntG,
                                           maxBits, out, m0);
  }
}

// Round 16
// 144.839 us; speedup vs baseline: 1.2932x; 1.0687x over previous
//
#include <hip/hip_runtime.h>
#include <math.h>

#define NN 512
#define NN2 (NN*NN)
#define NB 32
#define NM 64

typedef __attribute__((ext_vector_type(8))) short short8v;   // 8 bf16 (4 VGPR)
typedef __attribute__((ext_vector_type(4))) float f32x4;     // MFMA acc

typedef const unsigned int __attribute__((address_space(1)))* gas_ptr;
typedef unsigned int __attribute__((address_space(3)))* las_ptr;

__device__ __forceinline__ float sigm(float x) { return 1.0f / (1.0f + expf(-x)); }

__device__ __forceinline__ unsigned short f2bf(float x) {
  unsigned u = __float_as_uint(x);
  return (unsigned short)((u + 0x7fffu + ((u >> 16) & 1u)) >> 16);   // RNE
}
__device__ __forceinline__ float bf2f(unsigned short h) {
  return __uint_as_float(((unsigned)h) << 16);
}
__device__ __forceinline__ unsigned long long u64min(unsigned long long a,
                                                     unsigned long long b) {
  return (b < a) ? b : a;
}
__device__ __forceinline__ void amin64(unsigned long long* p, unsigned long long v) {
  unsigned long long old = *p;
  while (v < old) {
    unsigned long long assumed = old;
    old = atomicCAS(p, assumed, v);
    if (old == assumed) break;
  }
}
template <int CTRL>
__device__ __forceinline__ unsigned long long dpp_min_u64(unsigned long long x) {
  int xlo = (int)(unsigned)x, xhi = (int)(unsigned)(x >> 32);
  int ylo = __builtin_amdgcn_update_dpp(xlo, xlo, CTRL, 0xf, 0xf, false);
  int yhi = __builtin_amdgcn_update_dpp(xhi, xhi, CTRL, 0xf, 0xf, false);
  unsigned long long y = ((unsigned long long)(unsigned)yhi << 32) | (unsigned)ylo;
  return (y < x) ? y : x;
}
__device__ __forceinline__ unsigned long long wave_min_u64(unsigned long long k) {
  k = dpp_min_u64<0x111>(k); k = dpp_min_u64<0x112>(k);
  k = dpp_min_u64<0x114>(k); k = dpp_min_u64<0x118>(k);
  k = dpp_min_u64<0x142>(k); k = dpp_min_u64<0x143>(k);
  return k;
}
__device__ __forceinline__ unsigned long long grp16_min_u64(unsigned long long k) {
  k = dpp_min_u64<0x111>(k); k = dpp_min_u64<0x112>(k);
  k = dpp_min_u64<0x114>(k); k = dpp_min_u64<0x118>(k);
  return k;
}

// -------- sigmoid + bf16 hi/lo split + fused row sums-of-squares ----------------
__global__ __launch_bounds__(256) void split_kernel(const float* __restrict__ model,
                                                    const float* __restrict__ labels,
                                                    unsigned short* __restrict__ Hi,
                                                    unsigned short* __restrict__ Lo,
                                                    float* __restrict__ sq, int m0) {
  int b = blockIdx.x;
  int mL = b >> 8;
  int m = m0 + mL;
  int tid = threadIdx.x;
  size_t off = (size_t)(b & 255) * 1024 + tid * 4;
  const float* src = ((m & 1) ? labels + (size_t)(m >> 1) * NN2
                              : model + (size_t)(m >> 1) * NN2) + off;
  float4 v = *(const float4*)src;
  if (!(m & 1)) { v.x = sigm(v.x); v.y = sigm(v.y); v.z = sigm(v.z); v.w = sigm(v.w); }
  ushort4 h, l;
  h.x = f2bf(v.x); l.x = f2bf(v.x - bf2f(h.x));
  h.y = f2bf(v.y); l.y = f2bf(v.y - bf2f(h.y));
  h.z = f2bf(v.z); l.z = f2bf(v.z - bf2f(h.z));
  h.w = f2bf(v.w); l.w = f2bf(v.w - bf2f(h.w));
  *(ushort4*)(Hi + (size_t)mL * NN2 + off) = h;
  *(ushort4*)(Lo + (size_t)mL * NN2 + off) = l;
  float s = v.x * v.x + v.y * v.y + v.z * v.z + v.w * v.w;
  #pragma unroll
  for (int o = 32; o > 0; o >>= 1) s += __shfl_down(s, o);
  __shared__ float red[4];
  if ((tid & 63) == 0) red[tid >> 6] = s;
  __syncthreads();
  if (tid == 0) {
    int row0 = (b & 255) * 2;
    sq[(size_t)m * NN + row0]     = red[0] + red[1];
    sq[(size_t)m * NN + row0 + 1] = red[2] + red[3];
  }
}

// ------- distance matrix: r13 k-loop + coalesced D stores via LDS transpose -----
__global__ __launch_bounds__(256, 3) void gemm_dist(const unsigned short* __restrict__ Hi,
                                                    const unsigned short* __restrict__ Lo,
                                                    const float* __restrict__ sq,
                                                    float* __restrict__ Dreg,
                                                    unsigned* __restrict__ maxBits,
                                                    unsigned long long* __restrict__ best1,
                                                    int m0, int nm) {
  __shared__ unsigned short P[4][4096];   // Ah, Al, Bh, Bl (8 KB each; 32 KB)
  int id = blockIdx.x;
  int p, mL;
  if ((nm & 7) == 0) {
    int x = id & 7, t = id >> 3;
    p = t % 10;
    mL = x + 8 * (t / 10);
  } else {
    p = id % 10;
    mL = id / 10;
  }
  int by = (p >= 4) + (p >= 7) + (p >= 9);
  int bx = p - ((by * (7 - by)) >> 1);
  bool diag = (by == bx);
  int m = m0 + mL;
  const unsigned short* Hm = Hi + (size_t)mL * NN2;
  const unsigned short* Lm = Lo + (size_t)mL * NN2;

  int tid = threadIdx.x;
  int wid = tid >> 6, lane = tid & 63;
  int wy = wid >> 1, wx = wid & 1;
  int lr = lane & 15, lk = lane >> 4;

  const unsigned short* wsrcM = (wid & 1) ? Lm : Hm;
  int wrow0 = (wid < 2) ? by * 128 : bx * 128;
  bool stage = (!diag) || (wid < 2);
  int srow = lane >> 2;
  int schunk = (lane & 3) ^ ((lane >> 3) & 3);
  const unsigned short* gsrc = wsrcM + (size_t)(wrow0 + srow) * NN + schunk * 8;
  unsigned short* ldst = &P[wid & 3][0];

  f32x4 acc[4][4];
  #pragma unroll
  for (int i = 0; i < 4; ++i)
    #pragma unroll
    for (int j = 0; j < 4; ++j) acc[i][j] = (f32x4){0.f, 0.f, 0.f, 0.f};

  const unsigned short* bAh = &P[0][0];
  const unsigned short* bAl = &P[1][0];
  const unsigned short* bBh = diag ? &P[0][0] : &P[2][0];
  const unsigned short* bBl = diag ? &P[1][0] : &P[3][0];
  int sw = (lr >> 1) & 3;
  int rao = (wy * 64 + lr) * 32 + (lk ^ sw) * 8;
  int rbo = (wx * 64 + lr) * 32 + (lk ^ sw) * 8;

  for (int s = 0; s < 16; ++s) {
    int k0 = s * 32;
    if (stage) {
      #pragma unroll
      for (int i = 0; i < 8; ++i)
        __builtin_amdgcn_global_load_lds(
            (gas_ptr)(const void*)(gsrc + k0 + (size_t)i * 16 * NN),
            (las_ptr)(void*)(ldst + i * 512), 16, 0, 0);
    }
    __syncthreads();

    short8v fa[4], fb[4], fb2[4];
    #pragma unroll
    for (int i = 0; i < 4; ++i) {
      fa[i] = *(const short8v*)(bAh + rao + i * 512);   // Ah
      fb[i] = *(const short8v*)(bBh + rbo + i * 512);   // Bh
    }
    #pragma unroll
    for (int mi = 0; mi < 4; ++mi)
      #pragma unroll
      for (int ni = 0; ni < 4; ++ni)
        acc[mi][ni] = __builtin_amdgcn_mfma_f32_16x16x32_bf16(fa[mi], fb[ni], acc[mi][ni], 0, 0, 0);
    #pragma unroll
    for (int i = 0; i < 4; ++i)
      fb2[i] = *(const short8v*)(bBl + rbo + i * 512);  // Bl
    #pragma unroll
    for (int mi = 0; mi < 4; ++mi)
      #pragma unroll
      for (int ni = 0; ni < 4; ++ni)
        acc[mi][ni] = __builtin_amdgcn_mfma_f32_16x16x32_bf16(fa[mi], fb2[ni], acc[mi][ni], 0, 0, 0);
    #pragma unroll
    for (int i = 0; i < 4; ++i)
      fa[i] = *(const short8v*)(bAl + rao + i * 512);   // Al
    #pragma unroll
    for (int mi = 0; mi < 4; ++mi)
      #pragma unroll
      for (int ni = 0; ni < 4; ++ni)
        acc[mi][ni] = __builtin_amdgcn_mfma_f32_16x16x32_bf16(fa[mi], fb[ni], acc[mi][ni], 0, 0, 0);
    __syncthreads();
  }

  const float* sqm = sq + (size_t)m * NN;
  float* Dm = Dreg + (size_t)mL * NN2;
  int gr0 = by * 128 + wy * 64;
  int gc0 = bx * 128 + wx * 64;
  float tmax = 0.f;
  unsigned long long* b1 = best1 + (size_t)m * NN;
  unsigned long long ck[4];
  #pragma unroll
  for (int i = 0; i < 4; ++i) ck[i] = ~0ull;

  // per-mi: distances in place + keys (no global stores here)
  #pragma unroll
  for (int mi = 0; mi < 4; ++mi) {
    int rb = gr0 + mi * 16 + lk * 4;
    float sqi0 = sqm[rb + 0], sqi1 = sqm[rb + 1], sqi2 = sqm[rb + 2], sqi3 = sqm[rb + 3];
    unsigned long long rk[4];
    #pragma unroll
    for (int j = 0; j < 4; ++j) rk[j] = ~0ull;
    #pragma unroll
    for (int ni = 0; ni < 4; ++ni) {
      int col = gc0 + ni * 16 + lr;
      float sqj = sqm[col];
      f32x4 a = acc[mi][ni];
      float v0 = sqrtf(fmaxf(sqi0 + sqj - 2.f * a[0], 0.f));
      float v1 = sqrtf(fmaxf(sqi1 + sqj - 2.f * a[1], 0.f));
      float v2 = sqrtf(fmaxf(sqi2 + sqj - 2.f * a[2], 0.f));
      float v3 = sqrtf(fmaxf(sqi3 + sqj - 2.f * a[3], 0.f));
      acc[mi][ni][0] = v0; acc[mi][ni][1] = v1;
      acc[mi][ni][2] = v2; acc[mi][ni][3] = v3;
      tmax = fmaxf(tmax, fmaxf(fmaxf(v0, v1), fmaxf(v2, v3)));
      float vv[4] = {v0, v1, v2, v3};
      #pragma unroll
      for (int rg = 0; rg < 4; ++rg) {
        int row = rb + rg;
        if (!diag || col != row) {
          unsigned lo = (row < col) ? (unsigned)(row * NN + col)
                                    : (unsigned)(col * NN + row);
          unsigned long long key =
              ((unsigned long long)__float_as_uint(vv[rg]) << 32) | lo;
          rk[rg] = u64min(rk[rg], key);
          ck[ni] = u64min(ck[ni], key);
        }
      }
    }
    #pragma unroll
    for (int rg = 0; rg < 4; ++rg) {
      unsigned long long k = grp16_min_u64(rk[rg]);
      if (lr == 15) atomicMin(&b1[rb + rg], k);
    }
  }
  if (!diag) {
    #pragma unroll
    for (int ni = 0; ni < 4; ++ni) {
      unsigned long long k = ck[ni];
      k = u64min(k, __shfl_xor(k, 16));
      k = u64min(k, __shfl_xor(k, 32));
      if (lk == 0) atomicMin(&b1[gc0 + ni * 16 + lr], k);
    }
  }

  // ---- coalesced D stores via per-wave LDS transpose (r11, verified) ----
  __syncthreads();                           // staging LDS dead for all waves
  float* W = (float*)&P[0][0] + wid * 1088;  // 16 x 68 f32 per-wave scratch
  int rlo = lane >> 4, cq = lane & 15;
  #pragma unroll
  for (int mi = 0; mi < 4; ++mi) {
    #pragma unroll
    for (int ni = 0; ni < 4; ++ni)
      #pragma unroll
      for (int j = 0; j < 4; ++j)
        W[(lk * 4 + j) * 68 + ni * 16 + lr] = acc[mi][ni][j];
    #pragma unroll
    for (int g = 0; g < 4; ++g) {
      int r16 = g * 4 + rlo;
      float4 t = *(const float4*)&W[r16 * 68 + cq * 4];
      *(float4*)(Dm + (size_t)(gr0 + mi * 16 + r16) * NN + gc0 + cq * 4) = t;
    }
  }
  if (!diag) {
    #pragma unroll
    for (int ni = 0; ni < 4; ++ni) {
      #pragma unroll
      for (int mi = 0; mi < 4; ++mi) {
        f32x4 a = acc[mi][ni];
        *(float4*)&W[lr * 68 + mi * 16 + lk * 4] = make_float4(a[0], a[1], a[2], a[3]);
      }
      #pragma unroll
      for (int g = 0; g < 4; ++g) {
        int r16 = g * 4 + rlo;
        float4 t = *(const float4*)&W[r16 * 68 + cq * 4];
        *(float4*)(Dm + (size_t)(gc0 + ni * 16 + r16) * NN + gr0 + cq * 4) = t;
      }
    }
  }

  #pragma unroll
  for (int off = 32; off > 0; off >>= 1) tmax = fmaxf(tmax, __shfl_down(tmax, off));
  if (lane == 0) atomicMax(&maxBits[m], __float_as_uint(tmax));
}

// -------- phase-2 scan + inlined phase-1 hook + DcG init ------------------------
// All 8 blocks recompute comp from best1 (deterministic); block 0 writes
// edges/compG/ecnt. Each block inits its 1/8 slice of DcG (replaces memset).
__global__ __launch_bounds__(512) void scan2_kernel(const float* __restrict__ Dreg,
                                                    const unsigned long long* __restrict__ best1,
                                                    int* __restrict__ compG,
                                                    unsigned long long* __restrict__ best2,
                                                    unsigned long long* __restrict__ DcG,
                                                    int2* __restrict__ eo_all,
                                                    int* __restrict__ ecntG, int m0) {
  int sblk = blockIdx.x, mL = blockIdx.y, m = m0 + mL;
  const float* D = Dreg + (size_t)mL * NN2;
  __shared__ int compP[NN + 64];
  __shared__ int hook[NN], parent[NN];
  __shared__ int ecnt;
  int tid = threadIdx.x;
  int wave = tid >> 6, lane = tid & 63;
  int c0 = lane * 8;

  // DcG slice init (before contract's atomicMin; stream-ordered)
  unsigned long long* dginit = DcG + (size_t)mL * 16384 + sblk * 2048;
  #pragma unroll
  for (int i = 0; i < 4; ++i) dginit[tid + i * 512] = ~0ull;

  // ---- inlined hook1 (identical semantics to r13's hook1_kernel)
  if (tid == 0) ecnt = 0;
  unsigned long long b = best1[(size_t)m * NN + tid];
  int h;
  if (b != ~0ull) {
    int idx = (int)(unsigned)b;
    int er = idx >> 9, ec = idx & 511;
    h = (er == tid) ? ec : er;
  } else h = tid;
  hook[tid] = h;
  __syncthreads();
  bool active = (b != ~0ull);
  int p = h;
  bool mutual = active && (hook[p] == tid);
  parent[tid] = (!active) ? tid : ((mutual && tid < p) ? tid : p);
  if (sblk == 0 && active && (!mutual || tid > p)) {
    int idx = (int)(unsigned)b;
    int e = atomicAdd(&ecnt, 1);
    eo_all[(size_t)m * (NN - 1) + e] = make_int2(idx >> 9, idx & 511);
  }
  __syncthreads();
  int c = tid, pp = parent[c];
  while (pp != c) { c = pp; pp = parent[c]; }
  compP[tid + (tid >> 3)] = c;
  if (sblk == 0) {
    compG[(size_t)m * NN + tid] = c;
    if (tid == 0) ecntG[m] = ecnt;
  }
  __syncthreads();

  // ---- phase-2 scan (r13)
  unsigned long long* b2 = best2 + (size_t)m * NN;
  #pragma unroll
  for (int rr = 0; rr < 8; ++rr) {
    int r = sblk * 64 + wave * 8 + rr;
    int cr = compP[r + (r >> 3)];
    const float4* rp = (const float4*)(D + (size_t)r * NN + c0);
    float4 v0 = rp[0], v1 = rp[1];
    int4 cc0 = *(const int4*)(compP + c0 + (c0 >> 3));
    int4 cc1 = *(const int4*)(compP + c0 + 4 + (c0 >> 3));
    float vv[8] = {v0.x, v0.y, v0.z, v0.w, v1.x, v1.y, v1.z, v1.w};
    int cv[8] = {cc0.x, cc0.y, cc0.z, cc0.w, cc1.x, cc1.y, cc1.z, cc1.w};
    unsigned long long k = ~0ull;
    #pragma unroll
    for (int e = 0; e < 8; ++e) {
      if (cv[e] != cr) {
        int col = c0 + e;
        int lo = (r < col) ? r * NN + col : col * NN + r;
        unsigned long long key = ((unsigned long long)__float_as_uint(vv[e]) << 32) | (unsigned)lo;
        k = u64min(k, key);
      }
    }
    k = wave_min_u64(k);
    if (lane == 63 && k != ~0ull) atomicMin(&b2[cr], k);
  }
}

// -------- phase-2 hook + dense remap (C <= 128 guaranteed) ----------------------
__global__ __launch_bounds__(512) void hook2_kernel(const unsigned long long* __restrict__ best2,
                                                    const int* __restrict__ compG,
                                                    int* __restrict__ comp2g,
                                                    int2* __restrict__ eo_all,
                                                    int* __restrict__ ecntG,
                                                    int* __restrict__ cntG, int m0) {
  int mL = blockIdx.x, m = m0 + mL;
  const unsigned long long* b2 = best2 + (size_t)m * NN;
  int2* eo = eo_all + (size_t)m * (NN - 1);
  __shared__ int comp[NN], hook[NN], parent[NN], dmap[NN];
  __shared__ int ecnt, ccnt;
  int tid = threadIdx.x;
  if (tid == 0) { ecnt = ecntG[m]; ccnt = 0; }
  comp[tid] = compG[(size_t)m * NN + tid];
  __syncthreads();
  unsigned long long b = b2[tid];
  int h;
  if (b != ~0ull) {
    int idx = (int)(unsigned)b;
    int er = idx >> 9, ec = idx & 511;
    int c1 = comp[er], c2 = comp[ec];
    h = (c1 == tid) ? c2 : c1;
  } else h = tid;
  hook[tid] = h;
  __syncthreads();
  bool active = (b != ~0ull);
  int p = h;
  bool mutual = active && (hook[p] == tid);
  parent[tid] = (!active) ? tid : ((mutual && tid < p) ? tid : p);
  if (active && (!mutual || tid > p)) {
    int idx = (int)(unsigned)b;
    int e = atomicAdd(&ecnt, 1);
    eo[e] = make_int2(idx >> 9, idx & 511);
  }
  __syncthreads();
  int c = comp[tid], pp = parent[c];
  while (pp != c) { c = pp; pp = parent[c]; }
  __syncthreads();
  comp[tid] = c;
  __syncthreads();
  if (comp[tid] == tid) dmap[tid] = atomicAdd(&ccnt, 1);
  __syncthreads();
  comp2g[(size_t)m * NN + tid] = dmap[comp[tid]];
  if (tid == 0) { ecntG[m] = ecnt; cntG[m] = ccnt; }
}

// -------- contraction: 4 blocks/matrix build LDS-partial Dc, merge to global ----
__global__ __launch_bounds__(512) void contract_kernel(const float* __restrict__ Dreg,
                                                       const int* __restrict__ comp2g,
                                                       unsigned long long* __restrict__ DcG,
                                                       int m0) {
  int q = blockIdx.x, mL = blockIdx.y, m = m0 + mL;
  const float* D = Dreg + (size_t)mL * NN2;
  __shared__ unsigned long long Dc[128 * 128];
  __shared__ int c2P[NN + 64];
  int tid = threadIdx.x;
  int wave = tid >> 6, lane = tid & 63;
  int c0 = lane * 8;
  if (tid < NN) c2P[tid + (tid >> 3)] = comp2g[(size_t)m * NN + tid];
  for (int i = tid; i < 16384; i += 512) Dc[i] = ~0ull;
  __syncthreads();
  #pragma unroll
  for (int rr = 0; rr < 16; ++rr) {
    int r = q * 128 + wave * 16 + rr;
    int di = c2P[r + (r >> 3)];
    const float4* rp = (const float4*)(D + (size_t)r * NN + c0);
    float4 v0 = rp[0], v1 = rp[1];
    int4 cc0 = *(const int4*)(c2P + c0 + (c0 >> 3));
    int4 cc1 = *(const int4*)(c2P + c0 + 4 + (c0 >> 3));
    float vv[8] = {v0.x, v0.y, v0.z, v0.w, v1.x, v1.y, v1.z, v1.w};
    int cv[8] = {cc0.x, cc0.y, cc0.z, cc0.w, cc1.x, cc1.y, cc1.z, cc1.w};
    #pragma unroll
    for (int e = 0; e < 8; ++e) {
      if (cv[e] != di) {
        int col = c0 + e;
        int lo = (r < col) ? r * NN + col : col * NN + r;
        unsigned long long key = ((unsigned long long)__float_as_uint(vv[e]) << 32) | (unsigned)lo;
        amin64(&Dc[di * 128 + cv[e]], key);
      }
    }
  }
  __syncthreads();
  unsigned long long* dg = DcG + (size_t)mL * 16384;
  for (int i = tid; i < 16384; i += 512) {
    unsigned long long v = Dc[i];
    if (v != ~0ull) atomicMin(&dg[i], v);
  }
}

// -------- finish: LDS-resident phases on contracted matrix + fused gather -------
__global__ __launch_bounds__(1024) void finish_kernel(const float* __restrict__ Dreg,
                                                      const unsigned long long* __restrict__ DcG,
                                                      const int* __restrict__ comp2g,
                                                      const int* __restrict__ cntG,
                                                      int2* __restrict__ eo_all,
                                                      int* __restrict__ ecntG,
                                                      const unsigned* __restrict__ maxBits,
                                                      float* __restrict__ out, int m0) {
  int mL = blockIdx.x, m = m0 + mL;
  __shared__ unsigned long long Dc[16384];
  __shared__ int c2n[NN];
  __shared__ unsigned long long best[128];
  __shared__ int comp2[128], hook128[128], parent128[128];
  __shared__ float fred[16];
  __shared__ int ecnt;
  int tid = threadIdx.x;
  int wave = tid >> 6, lane = tid & 63;
  const unsigned long long* dg = DcG + (size_t)mL * 16384;
  for (int i = tid; i < 16384; i += 1024) Dc[i] = dg[i];
  if (tid < NN) c2n[tid] = comp2g[(size_t)m * NN + tid];
  if (tid < 128) comp2[tid] = tid;
  if (tid == 0) ecnt = ecntG[m];
  __syncthreads();
  int C = cntG[m];
  int2* eo = eo_all + (size_t)m * (NN - 1);

  for (int ph = 0; ph < 7; ++ph) {
    if (ecnt >= NN - 1) break;
    if (tid < 128) best[tid] = ~0ull;
    __syncthreads();
    for (int i = tid; i < C * 128; i += 1024) {
      unsigned long long key = Dc[i];
      if (key == ~0ull) continue;
      int a = i >> 7, bb = i & 127;
      int ca = comp2[a], cb = comp2[bb];
      if (ca != cb) amin64(&best[ca], key);
    }
    __syncthreads();
    if (tid < C) {
      unsigned long long b = best[tid];
      int h;
      if (b != ~0ull) {
        int pid = (int)(unsigned)b;
        int er = pid >> 9, ec = pid & 511;
        int c1 = comp2[c2n[er]], c2v = comp2[c2n[ec]];
        h = (c1 == tid) ? c2v : c1;
      } else h = tid;
      hook128[tid] = h;
    }
    __syncthreads();
    if (tid < C) {
      unsigned long long b = best[tid];
      bool active = (b != ~0ull);
      int p = hook128[tid];
      bool mutual = active && (hook128[p] == tid);
      parent128[tid] = (!active) ? tid : ((mutual && tid < p) ? tid : p);
      if (active && (!mutual || tid > p)) {
        int pid = (int)(unsigned)b;
        int e = atomicAdd(&ecnt, 1);
        eo[e] = make_int2(pid >> 9, pid & 511);
      }
    }
    __syncthreads();
    if (tid < C) {
      int c = comp2[tid], pp = parent128[c];
      while (pp != c) { c = pp; pp = parent128[c]; }
      comp2[tid] = c;
    }
    __syncthreads();
  }
  __syncthreads();

  // fused loss gather
  int b = m >> 1;
  float mxX = fmaxf(__uint_as_float(maxBits[2 * b]), 1e-12f);
  float mxZ = fmaxf(__uint_as_float(maxBits[2 * b + 1]), 1e-12f);
  float rX = 1.0f / mxX, rZ = 1.0f / mxZ;
  const float* Dx = Dreg + (size_t)(mL & ~1) * NN2;
  const float* Dz = Dx + NN2;
  float acc = 0.f;
  if (tid < NN - 1) {
    int2 e = eo[tid];
    size_t off = (size_t)e.x * NN + e.y;
    float d = Dx[off] * rX - Dz[off] * rZ;
    acc = d * d;
  }
  #pragma unroll
  for (int o = 32; o > 0; o >>= 1) acc += __shfl_down(acc, o);
  if (lane == 0) fred[wave] = acc;
  __syncthreads();
  if (tid == 0) {
    float t = 0.f;
    #pragma unroll
    for (int i = 0; i < 16; ++i) t += fred[i];
    atomicAdd(out, t * (1.0f / NB));
  }
}

extern "C" void kernel_launch(void* const* d_in, const int* in_sizes, int n_in,
                              void* d_out, int out_size, void* d_ws, size_t ws_size,
                              hipStream_t stream) {
  const float* model = (const float*)d_in[0];
  const float* labels = (const float*)d_in[1];
  float* out = (float*)d_out;
  char* ws = (char*)d_ws;

  float*              sq      = (float*)(ws);                       // 131072
  unsigned*           maxBits = (unsigned*)(ws + 131072);           // -> 132096
  int2*               eo      = (int2*)(ws + 132096);               // -> 393728
  unsigned long long* best1   = (unsigned long long*)(ws + 393728); // -> 655872
  unsigned long long* best2   = (unsigned long long*)(ws + 655872); // -> 918016
  int*                compG   = (int*)(ws + 918016);                // -> 1049088
  int*                comp2g  = (int*)(ws + 1049088);               // -> 1180160
  int*                ecntG   = (int*)(ws + 1180160);               // -> 1180416
  int*                cntG    = (int*)(ws + 1180416);               // -> 1180672
  size_t base = 1181696;

  // per batch (2 matrices): D 2MB + Hi 1MB + Lo 1MB + Dc 256KB
  size_t perBatch = 2ull * (NN2 * sizeof(float) + 2ull * NN2 * 2 + 16384 * 8);
  size_t dcap = (ws_size > base) ? (ws_size - base) : 0;
  int cb = (int)(dcap / perBatch);
  if (cb > NB) cb = NB;
  if (cb < 1) cb = 1;
  int nmc = 2 * cb;

  float* Dreg = (float*)(ws + base);
  unsigned short* Hi = (unsigned short*)(ws + base + (size_t)nmc * NN2 * sizeof(float));
  unsigned short* Lo = Hi + (size_t)nmc * NN2;
  unsigned long long* DcG = (unsigned long long*)(Lo + (size_t)nmc * NN2);

  hipMemsetAsync(d_out, 0, sizeof(float), stream);
  hipMemsetAsync(maxBits, 0, 64 * sizeof(unsigned), stream);

  for (int b0 = 0; b0 < NB; b0 += cb) {
    int nb = (NB - b0 < cb) ? (NB - b0) : cb;
    int nm = 2 * nb, m0 = 2 * b0;
    // best1 and best2 are contiguous: one 0xFF memset covers both
    hipMemsetAsync(best1 + (size_t)m0 * NN, 0xFF, (size_t)nm * NN * 16, stream);
    split_kernel<<<nm * 256, 256, 0, stream>>>(model, labels, Hi, Lo, sq, m0);
    gemm_dist<<<10 * nm, 256, 0, stream>>>(Hi, Lo, sq, Dreg, maxBits, best1, m0, nm);
    scan2_kernel<<<dim3(8, nm), 512, 0, stream>>>(Dreg, best1, compG, best2, DcG,
                                                  eo, ecntG, m0);
    hook2_kernel<<<nm, 512, 0, stream>>>(best2, compG, comp2g, eo, ecntG, cntG, m0);
    contract_kernel<<<dim3(4, nm), 512, 0, stream>>>(Dreg, comp2g, DcG, m0);
    finish_kernel<<<nm, 1024, 0, stream>>>(Dreg, DcG, comp2g, cntG, eo, ecntG,
                                           maxBits, out, m0);
  }
}

// Round 17
// 140.688 us; speedup vs baseline: 1.3314x; 1.0295x over previous
//
#include <hip/hip_runtime.h>
#include <math.h>

#define NN 512
#define NN2 (NN*NN)
#define NB 32
#define NM 64

typedef __attribute__((ext_vector_type(8))) short short8v;   // 8 bf16 (4 VGPR)
typedef __attribute__((ext_vector_type(4))) float f32x4;     // MFMA acc

typedef const unsigned int __attribute__((address_space(1)))* gas_ptr;
typedef unsigned int __attribute__((address_space(3)))* las_ptr;

__device__ __forceinline__ float sigm(float x) { return 1.0f / (1.0f + expf(-x)); }

__device__ __forceinline__ unsigned short f2bf(float x) {
  unsigned u = __float_as_uint(x);
  return (unsigned short)((u + 0x7fffu + ((u >> 16) & 1u)) >> 16);   // RNE
}
__device__ __forceinline__ float bf2f(unsigned short h) {
  return __uint_as_float(((unsigned)h) << 16);
}
__device__ __forceinline__ unsigned long long u64min(unsigned long long a,
                                                     unsigned long long b) {
  return (b < a) ? b : a;
}
__device__ __forceinline__ void amin64(unsigned long long* p, unsigned long long v) {
  unsigned long long old = *p;
  while (v < old) {
    unsigned long long assumed = old;
    old = atomicCAS(p, assumed, v);
    if (old == assumed) break;
  }
}
template <int CTRL>
__device__ __forceinline__ unsigned long long dpp_min_u64(unsigned long long x) {
  int xlo = (int)(unsigned)x, xhi = (int)(unsigned)(x >> 32);
  int ylo = __builtin_amdgcn_update_dpp(xlo, xlo, CTRL, 0xf, 0xf, false);
  int yhi = __builtin_amdgcn_update_dpp(xhi, xhi, CTRL, 0xf, 0xf, false);
  unsigned long long y = ((unsigned long long)(unsigned)yhi << 32) | (unsigned)ylo;
  return (y < x) ? y : x;
}
__device__ __forceinline__ unsigned long long wave_min_u64(unsigned long long k) {
  k = dpp_min_u64<0x111>(k); k = dpp_min_u64<0x112>(k);
  k = dpp_min_u64<0x114>(k); k = dpp_min_u64<0x118>(k);
  k = dpp_min_u64<0x142>(k); k = dpp_min_u64<0x143>(k);
  return k;
}
__device__ __forceinline__ unsigned long long grp16_min_u64(unsigned long long k) {
  k = dpp_min_u64<0x111>(k); k = dpp_min_u64<0x112>(k);
  k = dpp_min_u64<0x114>(k); k = dpp_min_u64<0x118>(k);
  return k;
}

// -------- sigmoid + bf16 hi/lo split + fused row sums-of-squares ----------------
__global__ __launch_bounds__(256) void split_kernel(const float* __restrict__ model,
                                                    const float* __restrict__ labels,
                                                    unsigned short* __restrict__ Hi,
                                                    unsigned short* __restrict__ Lo,
                                                    float* __restrict__ sq, int m0) {
  int b = blockIdx.x;
  int mL = b >> 8;
  int m = m0 + mL;
  int tid = threadIdx.x;
  size_t off = (size_t)(b & 255) * 1024 + tid * 4;
  const float* src = ((m & 1) ? labels + (size_t)(m >> 1) * NN2
                              : model + (size_t)(m >> 1) * NN2) + off;
  float4 v = *(const float4*)src;
  if (!(m & 1)) { v.x = sigm(v.x); v.y = sigm(v.y); v.z = sigm(v.z); v.w = sigm(v.w); }
  ushort4 h, l;
  h.x = f2bf(v.x); l.x = f2bf(v.x - bf2f(h.x));
  h.y = f2bf(v.y); l.y = f2bf(v.y - bf2f(h.y));
  h.z = f2bf(v.z); l.z = f2bf(v.z - bf2f(h.z));
  h.w = f2bf(v.w); l.w = f2bf(v.w - bf2f(h.w));
  *(ushort4*)(Hi + (size_t)mL * NN2 + off) = h;
  *(ushort4*)(Lo + (size_t)mL * NN2 + off) = l;
  float s = v.x * v.x + v.y * v.y + v.z * v.z + v.w * v.w;
  #pragma unroll
  for (int o = 32; o > 0; o >>= 1) s += __shfl_down(s, o);
  __shared__ float red[4];
  if ((tid & 63) == 0) red[tid >> 6] = s;
  __syncthreads();
  if (tid == 0) {
    int row0 = (b & 255) * 2;
    sq[(size_t)m * NN + row0]     = red[0] + red[1];
    sq[(size_t)m * NN + row0 + 1] = red[2] + red[3];
  }
}

// ------- distance matrix: r13 k-loop; D stored as BF16; keys from bf16 bits -----
__global__ __launch_bounds__(256, 3) void gemm_dist(const unsigned short* __restrict__ Hi,
                                                    const unsigned short* __restrict__ Lo,
                                                    const float* __restrict__ sq,
                                                    unsigned short* __restrict__ Dreg,
                                                    unsigned* __restrict__ maxBits,
                                                    unsigned long long* __restrict__ best1,
                                                    int m0, int nm) {
  __shared__ unsigned short P[4][4096];   // Ah, Al, Bh, Bl (8 KB each; 32 KB)
  int id = blockIdx.x;
  int p, mL;
  if ((nm & 7) == 0) {
    int x = id & 7, t = id >> 3;
    p = t % 10;
    mL = x + 8 * (t / 10);
  } else {
    p = id % 10;
    mL = id / 10;
  }
  int by = (p >= 4) + (p >= 7) + (p >= 9);
  int bx = p - ((by * (7 - by)) >> 1);
  bool diag = (by == bx);
  int m = m0 + mL;
  const unsigned short* Hm = Hi + (size_t)mL * NN2;
  const unsigned short* Lm = Lo + (size_t)mL * NN2;

  int tid = threadIdx.x;
  int wid = tid >> 6, lane = tid & 63;
  int wy = wid >> 1, wx = wid & 1;
  int lr = lane & 15, lk = lane >> 4;

  const unsigned short* wsrcM = (wid & 1) ? Lm : Hm;
  int wrow0 = (wid < 2) ? by * 128 : bx * 128;
  bool stage = (!diag) || (wid < 2);
  int srow = lane >> 2;
  int schunk = (lane & 3) ^ ((lane >> 3) & 3);
  const unsigned short* gsrc = wsrcM + (size_t)(wrow0 + srow) * NN + schunk * 8;
  unsigned short* ldst = &P[wid & 3][0];

  f32x4 acc[4][4];
  #pragma unroll
  for (int i = 0; i < 4; ++i)
    #pragma unroll
    for (int j = 0; j < 4; ++j) acc[i][j] = (f32x4){0.f, 0.f, 0.f, 0.f};

  const unsigned short* bAh = &P[0][0];
  const unsigned short* bAl = &P[1][0];
  const unsigned short* bBh = diag ? &P[0][0] : &P[2][0];
  const unsigned short* bBl = diag ? &P[1][0] : &P[3][0];
  int sw = (lr >> 1) & 3;
  int rao = (wy * 64 + lr) * 32 + (lk ^ sw) * 8;
  int rbo = (wx * 64 + lr) * 32 + (lk ^ sw) * 8;

  for (int s = 0; s < 16; ++s) {
    int k0 = s * 32;
    if (stage) {
      #pragma unroll
      for (int i = 0; i < 8; ++i)
        __builtin_amdgcn_global_load_lds(
            (gas_ptr)(const void*)(gsrc + k0 + (size_t)i * 16 * NN),
            (las_ptr)(void*)(ldst + i * 512), 16, 0, 0);
    }
    __syncthreads();

    short8v fa[4], fb[4], fb2[4];
    #pragma unroll
    for (int i = 0; i < 4; ++i) {
      fa[i] = *(const short8v*)(bAh + rao + i * 512);   // Ah
      fb[i] = *(const short8v*)(bBh + rbo + i * 512);   // Bh
    }
    #pragma unroll
    for (int mi = 0; mi < 4; ++mi)
      #pragma unroll
      for (int ni = 0; ni < 4; ++ni)
        acc[mi][ni] = __builtin_amdgcn_mfma_f32_16x16x32_bf16(fa[mi], fb[ni], acc[mi][ni], 0, 0, 0);
    #pragma unroll
    for (int i = 0; i < 4; ++i)
      fb2[i] = *(const short8v*)(bBl + rbo + i * 512);  // Bl
    #pragma unroll
    for (int mi = 0; mi < 4; ++mi)
      #pragma unroll
      for (int ni = 0; ni < 4; ++ni)
        acc[mi][ni] = __builtin_amdgcn_mfma_f32_16x16x32_bf16(fa[mi], fb2[ni], acc[mi][ni], 0, 0, 0);
    #pragma unroll
    for (int i = 0; i < 4; ++i)
      fa[i] = *(const short8v*)(bAl + rao + i * 512);   // Al
    #pragma unroll
    for (int mi = 0; mi < 4; ++mi)
      #pragma unroll
      for (int ni = 0; ni < 4; ++ni)
        acc[mi][ni] = __builtin_amdgcn_mfma_f32_16x16x32_bf16(fa[mi], fb[ni], acc[mi][ni], 0, 0, 0);
    __syncthreads();
  }

  const float* sqm = sq + (size_t)m * NN;
  unsigned short* Dm = Dreg + (size_t)mL * NN2;
  int gr0 = by * 128 + wy * 64;
  int gc0 = bx * 128 + wx * 64;
  float tmax = 0.f;
  unsigned long long* b1 = best1 + (size_t)m * NN;
  unsigned long long ck[4];
  #pragma unroll
  for (int i = 0; i < 4; ++i) ck[i] = ~0ull;

  // per-mi: bf16-rounded distances in acc + keys from the SAME bf16 bits
  #pragma unroll
  for (int mi = 0; mi < 4; ++mi) {
    int rb = gr0 + mi * 16 + lk * 4;
    float sqi0 = sqm[rb + 0], sqi1 = sqm[rb + 1], sqi2 = sqm[rb + 2], sqi3 = sqm[rb + 3];
    unsigned long long rk[4];
    #pragma unroll
    for (int j = 0; j < 4; ++j) rk[j] = ~0ull;
    #pragma unroll
    for (int ni = 0; ni < 4; ++ni) {
      int col = gc0 + ni * 16 + lr;
      float sqj = sqm[col];
      f32x4 a = acc[mi][ni];
      unsigned short h0 = f2bf(sqrtf(fmaxf(sqi0 + sqj - 2.f * a[0], 0.f)));
      unsigned short h1 = f2bf(sqrtf(fmaxf(sqi1 + sqj - 2.f * a[1], 0.f)));
      unsigned short h2 = f2bf(sqrtf(fmaxf(sqi2 + sqj - 2.f * a[2], 0.f)));
      unsigned short h3 = f2bf(sqrtf(fmaxf(sqi3 + sqj - 2.f * a[3], 0.f)));
      float v0 = bf2f(h0), v1 = bf2f(h1), v2 = bf2f(h2), v3 = bf2f(h3);
      acc[mi][ni][0] = v0; acc[mi][ni][1] = v1;
      acc[mi][ni][2] = v2; acc[mi][ni][3] = v3;
      tmax = fmaxf(tmax, fmaxf(fmaxf(v0, v1), fmaxf(v2, v3)));
      unsigned short hh[4] = {h0, h1, h2, h3};
      #pragma unroll
      for (int rg = 0; rg < 4; ++rg) {
        int row = rb + rg;
        if (!diag || col != row) {
          unsigned lo = (row < col) ? (unsigned)(row * NN + col)
                                    : (unsigned)(col * NN + row);
          unsigned long long key = ((unsigned long long)hh[rg] << 48) | lo;
          rk[rg] = u64min(rk[rg], key);
          ck[ni] = u64min(ck[ni], key);
        }
      }
    }
    #pragma unroll
    for (int rg = 0; rg < 4; ++rg) {
      unsigned long long k = grp16_min_u64(rk[rg]);
      if (lr == 15) atomicMin(&b1[rb + rg], k);
    }
  }
  if (!diag) {
    #pragma unroll
    for (int ni = 0; ni < 4; ++ni) {
      unsigned long long k = ck[ni];
      k = u64min(k, __shfl_xor(k, 16));
      k = u64min(k, __shfl_xor(k, 32));
      if (lk == 0) atomicMin(&b1[gc0 + ni * 16 + lr], k);
    }
  }

  // ---- coalesced bf16 D stores via per-wave LDS transpose ----
  __syncthreads();                           // staging LDS dead for all waves
  float* W = (float*)&P[0][0] + wid * 1088;  // 16 x 68 f32 per-wave scratch
  int rlo = lane >> 4, cq = lane & 15;
  #pragma unroll
  for (int mi = 0; mi < 4; ++mi) {
    #pragma unroll
    for (int ni = 0; ni < 4; ++ni)
      #pragma unroll
      for (int j = 0; j < 4; ++j)
        W[(lk * 4 + j) * 68 + ni * 16 + lr] = acc[mi][ni][j];
    #pragma unroll
    for (int g = 0; g < 4; ++g) {
      int r16 = g * 4 + rlo;
      float4 t = *(const float4*)&W[r16 * 68 + cq * 4];
      ushort4 o = make_ushort4(f2bf(t.x), f2bf(t.y), f2bf(t.z), f2bf(t.w));
      *(ushort4*)(Dm + (size_t)(gr0 + mi * 16 + r16) * NN + gc0 + cq * 4) = o;
    }
  }
  if (!diag) {
    #pragma unroll
    for (int ni = 0; ni < 4; ++ni) {
      #pragma unroll
      for (int mi = 0; mi < 4; ++mi) {
        f32x4 a = acc[mi][ni];
        *(float4*)&W[lr * 68 + mi * 16 + lk * 4] = make_float4(a[0], a[1], a[2], a[3]);
      }
      #pragma unroll
      for (int g = 0; g < 4; ++g) {
        int r16 = g * 4 + rlo;
        float4 t = *(const float4*)&W[r16 * 68 + cq * 4];
        ushort4 o = make_ushort4(f2bf(t.x), f2bf(t.y), f2bf(t.z), f2bf(t.w));
        *(ushort4*)(Dm + (size_t)(gc0 + ni * 16 + r16) * NN + gr0 + cq * 4) = o;
      }
    }
  }

  #pragma unroll
  for (int off = 32; off > 0; off >>= 1) tmax = fmaxf(tmax, __shfl_down(tmax, off));
  if (lane == 0) atomicMax(&maxBits[m], __float_as_uint(tmax));
}

// -------- phase-2 scan + inlined phase-1 hook + DcG init (bf16 D reads) ---------
__global__ __launch_bounds__(512) void scan2_kernel(const unsigned short* __restrict__ Dreg,
                                                    const unsigned long long* __restrict__ best1,
                                                    int* __restrict__ compG,
                                                    unsigned long long* __restrict__ best2,
                                                    unsigned long long* __restrict__ DcG,
                                                    int2* __restrict__ eo_all,
                                                    int* __restrict__ ecntG, int m0) {
  int sblk = blockIdx.x, mL = blockIdx.y, m = m0 + mL;
  const unsigned short* D = Dreg + (size_t)mL * NN2;
  __shared__ int compP[NN + 64];
  __shared__ int hook[NN], parent[NN];
  __shared__ int ecnt;
  int tid = threadIdx.x;
  int wave = tid >> 6, lane = tid & 63;
  int c0 = lane * 8;

  unsigned long long* dginit = DcG + (size_t)mL * 16384 + sblk * 2048;
  #pragma unroll
  for (int i = 0; i < 4; ++i) dginit[tid + i * 512] = ~0ull;

  if (tid == 0) ecnt = 0;
  unsigned long long b = best1[(size_t)m * NN + tid];
  int h;
  if (b != ~0ull) {
    int idx = (int)(unsigned)b & 0x3ffff;
    int er = idx >> 9, ec = idx & 511;
    h = (er == tid) ? ec : er;
  } else h = tid;
  hook[tid] = h;
  __syncthreads();
  bool active = (b != ~0ull);
  int p = h;
  bool mutual = active && (hook[p] == tid);
  parent[tid] = (!active) ? tid : ((mutual && tid < p) ? tid : p);
  if (sblk == 0 && active && (!mutual || tid > p)) {
    int idx = (int)(unsigned)b & 0x3ffff;
    int e = atomicAdd(&ecnt, 1);
    eo_all[(size_t)m * (NN - 1) + e] = make_int2(idx >> 9, idx & 511);
  }
  __syncthreads();
  int c = tid, pp = parent[c];
  while (pp != c) { c = pp; pp = parent[c]; }
  compP[tid + (tid >> 3)] = c;
  if (sblk == 0) {
    compG[(size_t)m * NN + tid] = c;
    if (tid == 0) ecntG[m] = ecnt;
  }
  __syncthreads();

  unsigned long long* b2 = best2 + (size_t)m * NN;
  #pragma unroll
  for (int rr = 0; rr < 8; ++rr) {
    int r = sblk * 64 + wave * 8 + rr;
    int cr = compP[r + (r >> 3)];
    uint4 dv = *(const uint4*)(D + (size_t)r * NN + c0);
    int4 cc0 = *(const int4*)(compP + c0 + (c0 >> 3));
    int4 cc1 = *(const int4*)(compP + c0 + 4 + (c0 >> 3));
    unsigned hh[8] = {dv.x & 0xffffu, dv.x >> 16, dv.y & 0xffffu, dv.y >> 16,
                      dv.z & 0xffffu, dv.z >> 16, dv.w & 0xffffu, dv.w >> 16};
    int cv[8] = {cc0.x, cc0.y, cc0.z, cc0.w, cc1.x, cc1.y, cc1.z, cc1.w};
    unsigned long long k = ~0ull;
    #pragma unroll
    for (int e = 0; e < 8; ++e) {
      if (cv[e] != cr) {
        int col = c0 + e;
        int lo = (r < col) ? r * NN + col : col * NN + r;
        unsigned long long key = ((unsigned long long)hh[e] << 48) | (unsigned)lo;
        k = u64min(k, key);
      }
    }
    k = wave_min_u64(k);
    if (lane == 63 && k != ~0ull) atomicMin(&b2[cr], k);
  }
}

// -------- phase-2 hook + dense remap (C <= 128 guaranteed) ----------------------
__global__ __launch_bounds__(512) void hook2_kernel(const unsigned long long* __restrict__ best2,
                                                    const int* __restrict__ compG,
                                                    int* __restrict__ comp2g,
                                                    int2* __restrict__ eo_all,
                                                    int* __restrict__ ecntG,
                                                    int* __restrict__ cntG, int m0) {
  int mL = blockIdx.x, m = m0 + mL;
  const unsigned long long* b2 = best2 + (size_t)m * NN;
  int2* eo = eo_all + (size_t)m * (NN - 1);
  __shared__ int comp[NN], hook[NN], parent[NN], dmap[NN];
  __shared__ int ecnt, ccnt;
  int tid = threadIdx.x;
  if (tid == 0) { ecnt = ecntG[m]; ccnt = 0; }
  comp[tid] = compG[(size_t)m * NN + tid];
  __syncthreads();
  unsigned long long b = b2[tid];
  int h;
  if (b != ~0ull) {
    int idx = (int)(unsigned)b & 0x3ffff;
    int er = idx >> 9, ec = idx & 511;
    int c1 = comp[er], c2 = comp[ec];
    h = (c1 == tid) ? c2 : c1;
  } else h = tid;
  hook[tid] = h;
  __syncthreads();
  bool active = (b != ~0ull);
  int p = h;
  bool mutual = active && (hook[p] == tid);
  parent[tid] = (!active) ? tid : ((mutual && tid < p) ? tid : p);
  if (active && (!mutual || tid > p)) {
    int idx = (int)(unsigned)b & 0x3ffff;
    int e = atomicAdd(&ecnt, 1);
    eo[e] = make_int2(idx >> 9, idx & 511);
  }
  __syncthreads();
  int c = comp[tid], pp = parent[c];
  while (pp != c) { c = pp; pp = parent[c]; }
  __syncthreads();
  comp[tid] = c;
  __syncthreads();
  if (comp[tid] == tid) dmap[tid] = atomicAdd(&ccnt, 1);
  __syncthreads();
  comp2g[(size_t)m * NN + tid] = dmap[comp[tid]];
  if (tid == 0) { ecntG[m] = ecnt; cntG[m] = ccnt; }
}

// -------- contraction: 4 blocks/matrix build LDS-partial Dc, merge to global ----
__global__ __launch_bounds__(512) void contract_kernel(const unsigned short* __restrict__ Dreg,
                                                       const int* __restrict__ comp2g,
                                                       unsigned long long* __restrict__ DcG,
                                                       int m0) {
  int q = blockIdx.x, mL = blockIdx.y, m = m0 + mL;
  const unsigned short* D = Dreg + (size_t)mL * NN2;
  __shared__ unsigned long long Dc[128 * 128];
  __shared__ int c2P[NN + 64];
  int tid = threadIdx.x;
  int wave = tid >> 6, lane = tid & 63;
  int c0 = lane * 8;
  if (tid < NN) c2P[tid + (tid >> 3)] = comp2g[(size_t)m * NN + tid];
  for (int i = tid; i < 16384; i += 512) Dc[i] = ~0ull;
  __syncthreads();
  #pragma unroll
  for (int rr = 0; rr < 16; ++rr) {
    int r = q * 128 + wave * 16 + rr;
    int di = c2P[r + (r >> 3)];
    uint4 dv = *(const uint4*)(D + (size_t)r * NN + c0);
    int4 cc0 = *(const int4*)(c2P + c0 + (c0 >> 3));
    int4 cc1 = *(const int4*)(c2P + c0 + 4 + (c0 >> 3));
    unsigned hh[8] = {dv.x & 0xffffu, dv.x >> 16, dv.y & 0xffffu, dv.y >> 16,
                      dv.z & 0xffffu, dv.z >> 16, dv.w & 0xffffu, dv.w >> 16};
    int cv[8] = {cc0.x, cc0.y, cc0.z, cc0.w, cc1.x, cc1.y, cc1.z, cc1.w};
    #pragma unroll
    for (int e = 0; e < 8; ++e) {
      if (cv[e] != di) {
        int col = c0 + e;
        int lo = (r < col) ? r * NN + col : col * NN + r;
        unsigned long long key = ((unsigned long long)hh[e] << 48) | (unsigned)lo;
        amin64(&Dc[di * 128 + cv[e]], key);
      }
    }
  }
  __syncthreads();
  unsigned long long* dg = DcG + (size_t)mL * 16384;
  for (int i = tid; i < 16384; i += 512) {
    unsigned long long v = Dc[i];
    if (v != ~0ull) atomicMin(&dg[i], v);
  }
}

// -------- finish: LDS-resident phases on contracted matrix + fused gather -------
__global__ __launch_bounds__(1024) void finish_kernel(const unsigned short* __restrict__ Dreg,
                                                      const unsigned long long* __restrict__ DcG,
                                                      const int* __restrict__ comp2g,
                                                      const int* __restrict__ cntG,
                                                      int2* __restrict__ eo_all,
                                                      int* __restrict__ ecntG,
                                                      const unsigned* __restrict__ maxBits,
                                                      float* __restrict__ out, int m0) {
  int mL = blockIdx.x, m = m0 + mL;
  __shared__ unsigned long long Dc[16384];
  __shared__ int c2n[NN];
  __shared__ unsigned long long best[128];
  __shared__ int comp2[128], hook128[128], parent128[128];
  __shared__ float fred[16];
  __shared__ int ecnt;
  int tid = threadIdx.x;
  int wave = tid >> 6, lane = tid & 63;
  const unsigned long long* dg = DcG + (size_t)mL * 16384;
  for (int i = tid; i < 16384; i += 1024) Dc[i] = dg[i];
  if (tid < NN) c2n[tid] = comp2g[(size_t)m * NN + tid];
  if (tid < 128) comp2[tid] = tid;
  if (tid == 0) ecnt = ecntG[m];
  __syncthreads();
  int C = cntG[m];
  int2* eo = eo_all + (size_t)m * (NN - 1);

  for (int ph = 0; ph < 7; ++ph) {
    if (ecnt >= NN - 1) break;
    if (tid < 128) best[tid] = ~0ull;
    __syncthreads();
    for (int i = tid; i < C * 128; i += 1024) {
      unsigned long long key = Dc[i];
      if (key == ~0ull) continue;
      int a = i >> 7, bb = i & 127;
      int ca = comp2[a], cb = comp2[bb];
      if (ca != cb) amin64(&best[ca], key);
    }
    __syncthreads();
    if (tid < C) {
      unsigned long long b = best[tid];
      int h;
      if (b != ~0ull) {
        int pid = (int)(unsigned)b & 0x3ffff;
        int er = pid >> 9, ec = pid & 511;
        int c1 = comp2[c2n[er]], c2v = comp2[c2n[ec]];
        h = (c1 == tid) ? c2v : c1;
      } else h = tid;
      hook128[tid] = h;
    }
    __syncthreads();
    if (tid < C) {
      unsigned long long b = best[tid];
      bool active = (b != ~0ull);
      int p = hook128[tid];
      bool mutual = active && (hook128[p] == tid);
      parent128[tid] = (!active) ? tid : ((mutual && tid < p) ? tid : p);
      if (active && (!mutual || tid > p)) {
        int pid = (int)(unsigned)b & 0x3ffff;
        int e = atomicAdd(&ecnt, 1);
        eo[e] = make_int2(pid >> 9, pid & 511);
      }
    }
    __syncthreads();
    if (tid < C) {
      int c = comp2[tid], pp = parent128[c];
      while (pp != c) { c = pp; pp = parent128[c]; }
      comp2[tid] = c;
    }
    __syncthreads();
  }
  __syncthreads();

  // fused loss gather (bf16 D)
  int b = m >> 1;
  float mxX = fmaxf(__uint_as_float(maxBits[2 * b]), 1e-12f);
  float mxZ = fmaxf(__uint_as_float(maxBits[2 * b + 1]), 1e-12f);
  float rX = 1.0f / mxX, rZ = 1.0f / mxZ;
  const unsigned short* Dx = Dreg + (size_t)(mL & ~1) * NN2;
  const unsigned short* Dz = Dx + NN2;
  float acc = 0.f;
  if (tid < NN - 1) {
    int2 e = eo[tid];
    size_t off = (size_t)e.x * NN + e.y;
    float d = bf2f(Dx[off]) * rX - bf2f(Dz[off]) * rZ;
    acc = d * d;
  }
  #pragma unroll
  for (int o = 32; o > 0; o >>= 1) acc += __shfl_down(acc, o);
  if (lane == 0) fred[wave] = acc;
  __syncthreads();
  if (tid == 0) {
    float t = 0.f;
    #pragma unroll
    for (int i = 0; i < 16; ++i) t += fred[i];
    atomicAdd(out, t * (1.0f / NB));
  }
}

extern "C" void kernel_launch(void* const* d_in, const int* in_sizes, int n_in,
                              void* d_out, int out_size, void* d_ws, size_t ws_size,
                              hipStream_t stream) {
  const float* model = (const float*)d_in[0];
  const float* labels = (const float*)d_in[1];
  float* out = (float*)d_out;
  char* ws = (char*)d_ws;

  float*              sq      = (float*)(ws);                       // 131072
  unsigned*           maxBits = (unsigned*)(ws + 131072);           // -> 132096
  int2*               eo      = (int2*)(ws + 132096);               // -> 393728
  unsigned long long* best1   = (unsigned long long*)(ws + 393728); // -> 655872
  unsigned long long* best2   = (unsigned long long*)(ws + 655872); // -> 918016
  int*                compG   = (int*)(ws + 918016);                // -> 1049088
  int*                comp2g  = (int*)(ws + 1049088);               // -> 1180160
  int*                ecntG   = (int*)(ws + 1180160);               // -> 1180416
  int*                cntG    = (int*)(ws + 1180416);               // -> 1180672
  size_t base = 1181696;

  // per batch (2 matrices): D bf16 1MB + Hi 1MB + Lo 1MB + Dc 256KB
  size_t perBatch = 2ull * (NN2 * 2 + 2ull * NN2 * 2 + 16384 * 8);
  size_t dcap = (ws_size > base) ? (ws_size - base) : 0;
  int cb = (int)(dcap / perBatch);
  if (cb > NB) cb = NB;
  if (cb < 1) cb = 1;
  int nmc = 2 * cb;

  unsigned short* Dreg = (unsigned short*)(ws + base);
  unsigned short* Hi = Dreg + (size_t)nmc * NN2;
  unsigned short* Lo = Hi + (size_t)nmc * NN2;
  unsigned long long* DcG = (unsigned long long*)(Lo + (size_t)nmc * NN2);

  hipMemsetAsync(d_out, 0, sizeof(float), stream);
  hipMemsetAsync(maxBits, 0, 64 * sizeof(unsigned), stream);

  for (int b0 = 0; b0 < NB; b0 += cb) {
    int nb = (NB - b0 < cb) ? (NB - b0) : cb;
    int nm = 2 * nb, m0 = 2 * b0;
    hipMemsetAsync(best1 + (size_t)m0 * NN, 0xFF, (size_t)nm * NN * 16, stream);
    split_kernel<<<nm * 256, 256, 0, stream>>>(model, labels, Hi, Lo, sq, m0);
    gemm_dist<<<10 * nm, 256, 0, stream>>>(Hi, Lo, sq, Dreg, maxBits, best1, m0, nm);
    scan2_kernel<<<dim3(8, nm), 512, 0, stream>>>(Dreg, best1, compG, best2, DcG,
                                                  eo, ecntG, m0);
    hook2_kernel<<<nm, 512, 0, stream>>>(best2, compG, comp2g, eo, ecntG, cntG, m0);
    contract_kernel<<<dim3(4, nm), 512, 0, stream>>>(Dreg, comp2g, DcG, m0);
    finish_kernel<<<nm, 1024, 0, stream>>>(Dreg, DcG, comp2g, cntG, eo, ecntG,
                                           maxBits, out, m0);
  }
}

// Round 18
// 140.306 us; speedup vs baseline: 1.3350x; 1.0027x over previous
//
#include <hip/hip_runtime.h>
#include <math.h>

#define NN 512
#define NN2 (NN*NN)
#define NB 32
#define NM 64

typedef __attribute__((ext_vector_type(8))) short short8v;   // 8 bf16 (4 VGPR)
typedef __attribute__((ext_vector_type(4))) float f32x4;     // MFMA acc

typedef const unsigned int __attribute__((address_space(1)))* gas_ptr;
typedef unsigned int __attribute__((address_space(3)))* las_ptr;

__device__ __forceinline__ float sigm(float x) { return 1.0f / (1.0f + expf(-x)); }

__device__ __forceinline__ unsigned short f2bf(float x) {
  unsigned u = __float_as_uint(x);
  return (unsigned short)((u + 0x7fffu + ((u >> 16) & 1u)) >> 16);   // RNE
}
__device__ __forceinline__ float bf2f(unsigned short h) {
  return __uint_as_float(((unsigned)h) << 16);
}
__device__ __forceinline__ unsigned long long u64min(unsigned long long a,
                                                     unsigned long long b) {
  return (b < a) ? b : a;
}
__device__ __forceinline__ void amin64(unsigned long long* p, unsigned long long v) {
  unsigned long long old = *p;
  while (v < old) {
    unsigned long long assumed = old;
    old = atomicCAS(p, assumed, v);
    if (old == assumed) break;
  }
}
template <int CTRL>
__device__ __forceinline__ unsigned long long dpp_min_u64(unsigned long long x) {
  int xlo = (int)(unsigned)x, xhi = (int)(unsigned)(x >> 32);
  int ylo = __builtin_amdgcn_update_dpp(xlo, xlo, CTRL, 0xf, 0xf, false);
  int yhi = __builtin_amdgcn_update_dpp(xhi, xhi, CTRL, 0xf, 0xf, false);
  unsigned long long y = ((unsigned long long)(unsigned)yhi << 32) | (unsigned)ylo;
  return (y < x) ? y : x;
}
__device__ __forceinline__ unsigned long long wave_min_u64(unsigned long long k) {
  k = dpp_min_u64<0x111>(k); k = dpp_min_u64<0x112>(k);
  k = dpp_min_u64<0x114>(k); k = dpp_min_u64<0x118>(k);
  k = dpp_min_u64<0x142>(k); k = dpp_min_u64<0x143>(k);
  return k;
}
__device__ __forceinline__ unsigned long long grp16_min_u64(unsigned long long k) {
  k = dpp_min_u64<0x111>(k); k = dpp_min_u64<0x112>(k);
  k = dpp_min_u64<0x114>(k); k = dpp_min_u64<0x118>(k);
  return k;
}

// -------- sigmoid + bf16 hi/lo split + fused row sums-of-squares ----------------
__global__ __launch_bounds__(256) void split_kernel(const float* __restrict__ model,
                                                    const float* __restrict__ labels,
                                                    unsigned short* __restrict__ Hi,
                                                    unsigned short* __restrict__ Lo,
                                                    float* __restrict__ sq, int m0) {
  int b = blockIdx.x;
  int mL = b >> 8;
  int m = m0 + mL;
  int tid = threadIdx.x;
  size_t off = (size_t)(b & 255) * 1024 + tid * 4;
  const float* src = ((m & 1) ? labels + (size_t)(m >> 1) * NN2
                              : model + (size_t)(m >> 1) * NN2) + off;
  float4 v = *(const float4*)src;
  if (!(m & 1)) { v.x = sigm(v.x); v.y = sigm(v.y); v.z = sigm(v.z); v.w = sigm(v.w); }
  ushort4 h, l;
  h.x = f2bf(v.x); l.x = f2bf(v.x - bf2f(h.x));
  h.y = f2bf(v.y); l.y = f2bf(v.y - bf2f(h.y));
  h.z = f2bf(v.z); l.z = f2bf(v.z - bf2f(h.z));
  h.w = f2bf(v.w); l.w = f2bf(v.w - bf2f(h.w));
  *(ushort4*)(Hi + (size_t)mL * NN2 + off) = h;
  *(ushort4*)(Lo + (size_t)mL * NN2 + off) = l;
  float s = v.x * v.x + v.y * v.y + v.z * v.z + v.w * v.w;
  #pragma unroll
  for (int o = 32; o > 0; o >>= 1) s += __shfl_down(s, o);
  __shared__ float red[4];
  if ((tid & 63) == 0) red[tid >> 6] = s;
  __syncthreads();
  if (tid == 0) {
    int row0 = (b & 255) * 2;
    sq[(size_t)m * NN + row0]     = red[0] + red[1];
    sq[(size_t)m * NN + row0 + 1] = red[2] + red[3];
  }
}

// ------- distance matrix: r13 k-loop; D bf16; single-conversion epilogue --------
__global__ __launch_bounds__(256, 3) void gemm_dist(const unsigned short* __restrict__ Hi,
                                                    const unsigned short* __restrict__ Lo,
                                                    const float* __restrict__ sq,
                                                    unsigned short* __restrict__ Dreg,
                                                    unsigned* __restrict__ maxBits,
                                                    unsigned long long* __restrict__ best1,
                                                    int m0, int nm) {
  __shared__ unsigned short P[4][4096];   // Ah, Al, Bh, Bl (8 KB each; 32 KB)
  int id = blockIdx.x;
  int p, mL;
  if ((nm & 7) == 0) {
    int x = id & 7, t = id >> 3;
    p = t % 10;
    mL = x + 8 * (t / 10);
  } else {
    p = id % 10;
    mL = id / 10;
  }
  int by = (p >= 4) + (p >= 7) + (p >= 9);
  int bx = p - ((by * (7 - by)) >> 1);
  bool diag = (by == bx);
  int m = m0 + mL;
  const unsigned short* Hm = Hi + (size_t)mL * NN2;
  const unsigned short* Lm = Lo + (size_t)mL * NN2;

  int tid = threadIdx.x;
  int wid = tid >> 6, lane = tid & 63;
  int wy = wid >> 1, wx = wid & 1;
  int lr = lane & 15, lk = lane >> 4;

  const unsigned short* wsrcM = (wid & 1) ? Lm : Hm;
  int wrow0 = (wid < 2) ? by * 128 : bx * 128;
  bool stage = (!diag) || (wid < 2);
  int srow = lane >> 2;
  int schunk = (lane & 3) ^ ((lane >> 3) & 3);
  const unsigned short* gsrc = wsrcM + (size_t)(wrow0 + srow) * NN + schunk * 8;
  unsigned short* ldst = &P[wid & 3][0];

  f32x4 acc[4][4];
  #pragma unroll
  for (int i = 0; i < 4; ++i)
    #pragma unroll
    for (int j = 0; j < 4; ++j) acc[i][j] = (f32x4){0.f, 0.f, 0.f, 0.f};

  const unsigned short* bAh = &P[0][0];
  const unsigned short* bAl = &P[1][0];
  const unsigned short* bBh = diag ? &P[0][0] : &P[2][0];
  const unsigned short* bBl = diag ? &P[1][0] : &P[3][0];
  int sw = (lr >> 1) & 3;
  int rao = (wy * 64 + lr) * 32 + (lk ^ sw) * 8;
  int rbo = (wx * 64 + lr) * 32 + (lk ^ sw) * 8;

  for (int s = 0; s < 16; ++s) {
    int k0 = s * 32;
    if (stage) {
      #pragma unroll
      for (int i = 0; i < 8; ++i)
        __builtin_amdgcn_global_load_lds(
            (gas_ptr)(const void*)(gsrc + k0 + (size_t)i * 16 * NN),
            (las_ptr)(void*)(ldst + i * 512), 16, 0, 0);
    }
    __syncthreads();

    short8v fa[4], fb[4], fb2[4];
    #pragma unroll
    for (int i = 0; i < 4; ++i) {
      fa[i] = *(const short8v*)(bAh + rao + i * 512);   // Ah
      fb[i] = *(const short8v*)(bBh + rbo + i * 512);   // Bh
    }
    #pragma unroll
    for (int mi = 0; mi < 4; ++mi)
      #pragma unroll
      for (int ni = 0; ni < 4; ++ni)
        acc[mi][ni] = __builtin_amdgcn_mfma_f32_16x16x32_bf16(fa[mi], fb[ni], acc[mi][ni], 0, 0, 0);
    #pragma unroll
    for (int i = 0; i < 4; ++i)
      fb2[i] = *(const short8v*)(bBl + rbo + i * 512);  // Bl
    #pragma unroll
    for (int mi = 0; mi < 4; ++mi)
      #pragma unroll
      for (int ni = 0; ni < 4; ++ni)
        acc[mi][ni] = __builtin_amdgcn_mfma_f32_16x16x32_bf16(fa[mi], fb2[ni], acc[mi][ni], 0, 0, 0);
    #pragma unroll
    for (int i = 0; i < 4; ++i)
      fa[i] = *(const short8v*)(bAl + rao + i * 512);   // Al
    #pragma unroll
    for (int mi = 0; mi < 4; ++mi)
      #pragma unroll
      for (int ni = 0; ni < 4; ++ni)
        acc[mi][ni] = __builtin_amdgcn_mfma_f32_16x16x32_bf16(fa[mi], fb[ni], acc[mi][ni], 0, 0, 0);
    __syncthreads();
  }

  const float* sqm = sq + (size_t)m * NN;
  unsigned short* Dm = Dreg + (size_t)mL * NN2;
  int gr0 = by * 128 + wy * 64;
  int gc0 = bx * 128 + wx * 64;
  unsigned hmax = 0;                       // bf16 bits; integer order == float order (>=0)
  unsigned long long* b1 = best1 + (size_t)m * NN;
  unsigned long long ck[4];
  #pragma unroll
  for (int i = 0; i < 4; ++i) ck[i] = ~0ull;
  unsigned short us[4][4][4];              // [mi][ni][rg] bf16 distances (single conv)

  #pragma unroll
  for (int mi = 0; mi < 4; ++mi) {
    int rb = gr0 + mi * 16 + lk * 4;
    float sqi0 = sqm[rb + 0], sqi1 = sqm[rb + 1], sqi2 = sqm[rb + 2], sqi3 = sqm[rb + 3];
    unsigned long long rk[4];
    #pragma unroll
    for (int j = 0; j < 4; ++j) rk[j] = ~0ull;
    #pragma unroll
    for (int ni = 0; ni < 4; ++ni) {
      int col = gc0 + ni * 16 + lr;
      float sqj = sqm[col];
      f32x4 a = acc[mi][ni];
      unsigned short h0 = f2bf(sqrtf(fmaxf(sqi0 + sqj - 2.f * a[0], 0.f)));
      unsigned short h1 = f2bf(sqrtf(fmaxf(sqi1 + sqj - 2.f * a[1], 0.f)));
      unsigned short h2 = f2bf(sqrtf(fmaxf(sqi2 + sqj - 2.f * a[2], 0.f)));
      unsigned short h3 = f2bf(sqrtf(fmaxf(sqi3 + sqj - 2.f * a[3], 0.f)));
      us[mi][ni][0] = h0; us[mi][ni][1] = h1;
      us[mi][ni][2] = h2; us[mi][ni][3] = h3;
      unsigned hm01 = (h0 > h1) ? h0 : h1;
      unsigned hm23 = (h2 > h3) ? h2 : h3;
      unsigned hm = (hm01 > hm23) ? hm01 : hm23;
      hmax = (hm > hmax) ? hm : hmax;
      unsigned short hh[4] = {h0, h1, h2, h3};
      #pragma unroll
      for (int rg = 0; rg < 4; ++rg) {
        int row = rb + rg;
        if (!diag || col != row) {
          unsigned lo = (row < col) ? (unsigned)(row * NN + col)
                                    : (unsigned)(col * NN + row);
          unsigned long long key = ((unsigned long long)hh[rg] << 48) | lo;
          rk[rg] = u64min(rk[rg], key);
          ck[ni] = u64min(ck[ni], key);
        }
      }
    }
    #pragma unroll
    for (int rg = 0; rg < 4; ++rg) {
      unsigned long long k = grp16_min_u64(rk[rg]);
      if (lr == 15) atomicMin(&b1[rb + rg], k);
    }
  }
  if (!diag) {
    #pragma unroll
    for (int ni = 0; ni < 4; ++ni) {
      unsigned long long k = ck[ni];
      k = u64min(k, __shfl_xor(k, 16));
      k = u64min(k, __shfl_xor(k, 32));
      if (lk == 0) atomicMin(&b1[gc0 + ni * 16 + lr], k);
    }
  }

  // ---- coalesced bf16 D stores via per-wave LDS ushort transpose ----
  __syncthreads();                                   // staging LDS dead
  unsigned short* W = &P[0][0] + wid * 1216;         // 16 x 76 ushort per-wave
  int rlo = lane >> 4, cq = lane & 15;
  #pragma unroll
  for (int mi = 0; mi < 4; ++mi) {
    #pragma unroll
    for (int ni = 0; ni < 4; ++ni)
      #pragma unroll
      for (int j = 0; j < 4; ++j)
        W[(lk * 4 + j) * 76 + ni * 16 + lr] = us[mi][ni][j];
    #pragma unroll
    for (int g = 0; g < 4; ++g) {
      int r16 = g * 4 + rlo;
      ushort4 t = *(const ushort4*)&W[r16 * 76 + cq * 4];
      *(ushort4*)(Dm + (size_t)(gr0 + mi * 16 + r16) * NN + gc0 + cq * 4) = t;
    }
  }
  if (!diag) {
    #pragma unroll
    for (int ni = 0; ni < 4; ++ni) {
      #pragma unroll
      for (int mi = 0; mi < 4; ++mi)
        *(ushort4*)&W[lr * 76 + mi * 16 + lk * 4] =
            make_ushort4(us[mi][ni][0], us[mi][ni][1], us[mi][ni][2], us[mi][ni][3]);
      #pragma unroll
      for (int g = 0; g < 4; ++g) {
        int r16 = g * 4 + rlo;
        ushort4 t = *(const ushort4*)&W[r16 * 76 + cq * 4];
        *(ushort4*)(Dm + (size_t)(gc0 + ni * 16 + r16) * NN + gr0 + cq * 4) = t;
      }
    }
  }

  #pragma unroll
  for (int off = 32; off > 0; off >>= 1) {
    unsigned o = (unsigned)__shfl_down((int)hmax, off);
    hmax = (o > hmax) ? o : hmax;
  }
  if (lane == 0) atomicMax(&maxBits[m], hmax << 16);
}

// -------- phase-2 scan + inlined phase-1 hook + DcG init (bf16 D reads) ---------
__global__ __launch_bounds__(512) void scan2_kernel(const unsigned short* __restrict__ Dreg,
                                                    const unsigned long long* __restrict__ best1,
                                                    int* __restrict__ compG,
                                                    unsigned long long* __restrict__ best2,
                                                    unsigned long long* __restrict__ DcG,
                                                    int2* __restrict__ eo_all,
                                                    int* __restrict__ ecntG, int m0) {
  int sblk = blockIdx.x, mL = blockIdx.y, m = m0 + mL;
  const unsigned short* D = Dreg + (size_t)mL * NN2;
  __shared__ int compP[NN + 64];
  __shared__ int hook[NN], parent[NN];
  __shared__ int ecnt;
  int tid = threadIdx.x;
  int wave = tid >> 6, lane = tid & 63;
  int c0 = lane * 8;

  unsigned long long* dginit = DcG + (size_t)mL * 16384 + sblk * 2048;
  #pragma unroll
  for (int i = 0; i < 4; ++i) dginit[tid + i * 512] = ~0ull;

  if (tid == 0) ecnt = 0;
  unsigned long long b = best1[(size_t)m * NN + tid];
  int h;
  if (b != ~0ull) {
    int idx = (int)(unsigned)b & 0x3ffff;
    int er = idx >> 9, ec = idx & 511;
    h = (er == tid) ? ec : er;
  } else h = tid;
  hook[tid] = h;
  __syncthreads();
  bool active = (b != ~0ull);
  int p = h;
  bool mutual = active && (hook[p] == tid);
  parent[tid] = (!active) ? tid : ((mutual && tid < p) ? tid : p);
  if (sblk == 0 && active && (!mutual || tid > p)) {
    int idx = (int)(unsigned)b & 0x3ffff;
    int e = atomicAdd(&ecnt, 1);
    eo_all[(size_t)m * (NN - 1) + e] = make_int2(idx >> 9, idx & 511);
  }
  __syncthreads();
  int c = tid, pp = parent[c];
  while (pp != c) { c = pp; pp = parent[c]; }
  compP[tid + (tid >> 3)] = c;
  if (sblk == 0) {
    compG[(size_t)m * NN + tid] = c;
    if (tid == 0) ecntG[m] = ecnt;
  }
  __syncthreads();

  unsigned long long* b2 = best2 + (size_t)m * NN;
  #pragma unroll
  for (int rr = 0; rr < 8; ++rr) {
    int r = sblk * 64 + wave * 8 + rr;
    int cr = compP[r + (r >> 3)];
    uint4 dv = *(const uint4*)(D + (size_t)r * NN + c0);
    int4 cc0 = *(const int4*)(compP + c0 + (c0 >> 3));
    int4 cc1 = *(const int4*)(compP + c0 + 4 + (c0 >> 3));
    unsigned hh[8] = {dv.x & 0xffffu, dv.x >> 16, dv.y & 0xffffu, dv.y >> 16,
                      dv.z & 0xffffu, dv.z >> 16, dv.w & 0xffffu, dv.w >> 16};
    int cv[8] = {cc0.x, cc0.y, cc0.z, cc0.w, cc1.x, cc1.y, cc1.z, cc1.w};
    unsigned long long k = ~0ull;
    #pragma unroll
    for (int e = 0; e < 8; ++e) {
      if (cv[e] != cr) {
        int col = c0 + e;
        int lo = (r < col) ? r * NN + col : col * NN + r;
        unsigned long long key = ((unsigned long long)hh[e] << 48) | (unsigned)lo;
        k = u64min(k, key);
      }
    }
    k = wave_min_u64(k);
    if (lane == 63 && k != ~0ull) atomicMin(&b2[cr], k);
  }
}

// -------- phase-2 hook + dense remap (C <= 128 guaranteed) ----------------------
__global__ __launch_bounds__(512) void hook2_kernel(const unsigned long long* __restrict__ best2,
                                                    const int* __restrict__ compG,
                                                    int* __restrict__ comp2g,
                                                    int2* __restrict__ eo_all,
                                                    int* __restrict__ ecntG,
                                                    int* __restrict__ cntG, int m0) {
  int mL = blockIdx.x, m = m0 + mL;
  const unsigned long long* b2 = best2 + (size_t)m * NN;
  int2* eo = eo_all + (size_t)m * (NN - 1);
  __shared__ int comp[NN], hook[NN], parent[NN], dmap[NN];
  __shared__ int ecnt, ccnt;
  int tid = threadIdx.x;
  if (tid == 0) { ecnt = ecntG[m]; ccnt = 0; }
  comp[tid] = compG[(size_t)m * NN + tid];
  __syncthreads();
  unsigned long long b = b2[tid];
  int h;
  if (b != ~0ull) {
    int idx = (int)(unsigned)b & 0x3ffff;
    int er = idx >> 9, ec = idx & 511;
    int c1 = comp[er], c2 = comp[ec];
    h = (c1 == tid) ? c2 : c1;
  } else h = tid;
  hook[tid] = h;
  __syncthreads();
  bool active = (b != ~0ull);
  int p = h;
  bool mutual = active && (hook[p] == tid);
  parent[tid] = (!active) ? tid : ((mutual && tid < p) ? tid : p);
  if (active && (!mutual || tid > p)) {
    int idx = (int)(unsigned)b & 0x3ffff;
    int e = atomicAdd(&ecnt, 1);
    eo[e] = make_int2(idx >> 9, idx & 511);
  }
  __syncthreads();
  int c = comp[tid], pp = parent[c];
  while (pp != c) { c = pp; pp = parent[c]; }
  __syncthreads();
  comp[tid] = c;
  __syncthreads();
  if (comp[tid] == tid) dmap[tid] = atomicAdd(&ccnt, 1);
  __syncthreads();
  comp2g[(size_t)m * NN + tid] = dmap[comp[tid]];
  if (tid == 0) { ecntG[m] = ecnt; cntG[m] = ccnt; }
}

// -------- contraction: 4 blocks/matrix build LDS-partial Dc, merge to global ----
__global__ __launch_bounds__(512) void contract_kernel(const unsigned short* __restrict__ Dreg,
                                                       const int* __restrict__ comp2g,
                                                       unsigned long long* __restrict__ DcG,
                                                       int m0) {
  int q = blockIdx.x, mL = blockIdx.y, m = m0 + mL;
  const unsigned short* D = Dreg + (size_t)mL * NN2;
  __shared__ unsigned long long Dc[128 * 128];
  __shared__ int c2P[NN + 64];
  int tid = threadIdx.x;
  int wave = tid >> 6, lane = tid & 63;
  int c0 = lane * 8;
  if (tid < NN) c2P[tid + (tid >> 3)] = comp2g[(size_t)m * NN + tid];
  for (int i = tid; i < 16384; i += 512) Dc[i] = ~0ull;
  __syncthreads();
  #pragma unroll
  for (int rr = 0; rr < 16; ++rr) {
    int r = q * 128 + wave * 16 + rr;
    int di = c2P[r + (r >> 3)];
    uint4 dv = *(const uint4*)(D + (size_t)r * NN + c0);
    int4 cc0 = *(const int4*)(c2P + c0 + (c0 >> 3));
    int4 cc1 = *(const int4*)(c2P + c0 + 4 + (c0 >> 3));
    unsigned hh[8] = {dv.x & 0xffffu, dv.x >> 16, dv.y & 0xffffu, dv.y >> 16,
                      dv.z & 0xffffu, dv.z >> 16, dv.w & 0xffffu, dv.w >> 16};
    int cv[8] = {cc0.x, cc0.y, cc0.z, cc0.w, cc1.x, cc1.y, cc1.z, cc1.w};
    #pragma unroll
    for (int e = 0; e < 8; ++e) {
      if (cv[e] != di) {
        int col = c0 + e;
        int lo = (r < col) ? r * NN + col : col * NN + r;
        unsigned long long key = ((unsigned long long)hh[e] << 48) | (unsigned)lo;
        amin64(&Dc[di * 128 + cv[e]], key);
      }
    }
  }
  __syncthreads();
  unsigned long long* dg = DcG + (size_t)mL * 16384;
  for (int i = tid; i < 16384; i += 512) {
    unsigned long long v = Dc[i];
    if (v != ~0ull) atomicMin(&dg[i], v);
  }
}

// -------- finish: LDS-resident phases on contracted matrix + fused gather -------
__global__ __launch_bounds__(1024) void finish_kernel(const unsigned short* __restrict__ Dreg,
                                                      const unsigned long long* __restrict__ DcG,
                                                      const int* __restrict__ comp2g,
                                                      const int* __restrict__ cntG,
                                                      int2* __restrict__ eo_all,
                                                      int* __restrict__ ecntG,
                                                      const unsigned* __restrict__ maxBits,
                                                      float* __restrict__ out, int m0) {
  int mL = blockIdx.x, m = m0 + mL;
  __shared__ unsigned long long Dc[16384];
  __shared__ int c2n[NN];
  __shared__ unsigned long long best[128];
  __shared__ int comp2[128], hook128[128], parent128[128];
  __shared__ float fred[16];
  __shared__ int ecnt;
  int tid = threadIdx.x;
  int wave = tid >> 6, lane = tid & 63;
  const unsigned long long* dg = DcG + (size_t)mL * 16384;
  for (int i = tid; i < 16384; i += 1024) Dc[i] = dg[i];
  if (tid < NN) c2n[tid] = comp2g[(size_t)m * NN + tid];
  if (tid < 128) comp2[tid] = tid;
  if (tid == 0) ecnt = ecntG[m];
  __syncthreads();
  int C = cntG[m];
  int2* eo = eo_all + (size_t)m * (NN - 1);

  for (int ph = 0; ph < 7; ++ph) {
    if (ecnt >= NN - 1) break;
    if (tid < 128) best[tid] = ~0ull;
    __syncthreads();
    for (int i = tid; i < C * 128; i += 1024) {
      unsigned long long key = Dc[i];
      if (key == ~0ull) continue;
      int a = i >> 7, bb = i & 127;
      int ca = comp2[a], cb = comp2[bb];
      if (ca != cb) amin64(&best[ca], key);
    }
    __syncthreads();
    if (tid < C) {
      unsigned long long b = best[tid];
      int h;
      if (b != ~0ull) {
        int pid = (int)(unsigned)b & 0x3ffff;
        int er = pid >> 9, ec = pid & 511;
        int c1 = comp2[c2n[er]], c2v = comp2[c2n[ec]];
        h = (c1 == tid) ? c2v : c1;
      } else h = tid;
      hook128[tid] = h;
    }
    __syncthreads();
    if (tid < C) {
      unsigned long long b = best[tid];
      bool active = (b != ~0ull);
      int p = hook128[tid];
      bool mutual = active && (hook128[p] == tid);
      parent128[tid] = (!active) ? tid : ((mutual && tid < p) ? tid : p);
      if (active && (!mutual || tid > p)) {
        int pid = (int)(unsigned)b & 0x3ffff;
        int e = atomicAdd(&ecnt, 1);
        eo[e] = make_int2(pid >> 9, pid & 511);
      }
    }
    __syncthreads();
    if (tid < C) {
      int c = comp2[tid], pp = parent128[c];
      while (pp != c) { c = pp; pp = parent128[c]; }
      comp2[tid] = c;
    }
    __syncthreads();
  }
  __syncthreads();

  // fused loss gather (bf16 D)
  int b = m >> 1;
  float mxX = fmaxf(__uint_as_float(maxBits[2 * b]), 1e-12f);
  float mxZ = fmaxf(__uint_as_float(maxBits[2 * b + 1]), 1e-12f);
  float rX = 1.0f / mxX, rZ = 1.0f / mxZ;
  const unsigned short* Dx = Dreg + (size_t)(mL & ~1) * NN2;
  const unsigned short* Dz = Dx + NN2;
  float acc = 0.f;
  if (tid < NN - 1) {
    int2 e = eo[tid];
    size_t off = (size_t)e.x * NN + e.y;
    float d = bf2f(Dx[off]) * rX - bf2f(Dz[off]) * rZ;
    acc = d * d;
  }
  #pragma unroll
  for (int o = 32; o > 0; o >>= 1) acc += __shfl_down(acc, o);
  if (lane == 0) fred[wave] = acc;
  __syncthreads();
  if (tid == 0) {
    float t = 0.f;
    #pragma unroll
    for (int i = 0; i < 16; ++i) t += fred[i];
    atomicAdd(out, t * (1.0f / NB));
  }
}

extern "C" void kernel_launch(void* const* d_in, const int* in_sizes, int n_in,
                              void* d_out, int out_size, void* d_ws, size_t ws_size,
                              hipStream_t stream) {
  const float* model = (const float*)d_in[0];
  const float* labels = (const float*)d_in[1];
  float* out = (float*)d_out;
  char* ws = (char*)d_ws;

  float*              sq      = (float*)(ws);                       // 131072
  unsigned*           maxBits = (unsigned*)(ws + 131072);           // -> 132096
  int2*               eo      = (int2*)(ws + 132096);               // -> 393728
  unsigned long long* best1   = (unsigned long long*)(ws + 393728); // -> 655872
  unsigned long long* best2   = (unsigned long long*)(ws + 655872); // -> 918016
  int*                compG   = (int*)(ws + 918016);                // -> 1049088
  int*                comp2g  = (int*)(ws + 1049088);               // -> 1180160
  int*                ecntG   = (int*)(ws + 1180160);               // -> 1180416
  int*                cntG    = (int*)(ws + 1180416);               // -> 1180672
  size_t base = 1181696;

  // per batch (2 matrices): D bf16 1MB + Hi 1MB + Lo 1MB + Dc 256KB
  size_t perBatch = 2ull * (NN2 * 2 + 2ull * NN2 * 2 + 16384 * 8);
  size_t dcap = (ws_size > base) ? (ws_size - base) : 0;
  int cb = (int)(dcap / perBatch);
  if (cb > NB) cb = NB;
  if (cb < 1) cb = 1;
  int nmc = 2 * cb;

  unsigned short* Dreg = (unsigned short*)(ws + base);
  unsigned short* Hi = Dreg + (size_t)nmc * NN2;
  unsigned short* Lo = Hi + (size_t)nmc * NN2;
  unsigned long long* DcG = (unsigned long long*)(Lo + (size_t)nmc * NN2);

  hipMemsetAsync(d_out, 0, sizeof(float), stream);
  hipMemsetAsync(maxBits, 0, 64 * sizeof(unsigned), stream);

  for (int b0 = 0; b0 < NB; b0 += cb) {
    int nb = (NB - b0 < cb) ? (NB - b0) : cb;
    int nm = 2 * nb, m0 = 2 * b0;
    hipMemsetAsync(best1 + (size_t)m0 * NN, 0xFF, (size_t)nm * NN * 16, stream);
    split_kernel<<<nm * 256, 256, 0, stream>>>(model, labels, Hi, Lo, sq, m0);
    gemm_dist<<<10 * nm, 256, 0, stream>>>(Hi, Lo, sq, Dreg, maxBits, best1, m0, nm);
    scan2_kernel<<<dim3(8, nm), 512, 0, stream>>>(Dreg, best1, compG, best2, DcG,
                                                  eo, ecntG, m0);
    hook2_kernel<<<nm, 512, 0, stream>>>(best2, compG, comp2g, eo, ecntG, cntG, m0);
    contract_kernel<<<dim3(4, nm), 512, 0, stream>>>(Dreg, comp2g, DcG, m0);
    finish_kernel<<<nm, 1024, 0, stream>>>(Dreg, DcG, comp2g, cntG, eo, ecntG,
                                           maxBits, out, m0);
  }
}

// Round 20
// 136.905 us; speedup vs baseline: 1.3682x; 1.0248x over previous
//
#include <hip/hip_runtime.h>
#include <math.h>

#define NN 512
#define NN2 (NN*NN)
#define NB 32
#define NM 64

typedef __attribute__((ext_vector_type(8))) short short8v;   // 8 bf16 (4 VGPR)
typedef __attribute__((ext_vector_type(4))) float f32x4;     // MFMA acc

typedef const unsigned int __attribute__((address_space(1)))* gas_ptr;
typedef unsigned int __attribute__((address_space(3)))* las_ptr;

__device__ __forceinline__ float sigm(float x) { return 1.0f / (1.0f + expf(-x)); }

__device__ __forceinline__ unsigned short f2bf(float x) {
  unsigned u = __float_as_uint(x);
  return (unsigned short)((u + 0x7fffu + ((u >> 16) & 1u)) >> 16);   // RNE
}
__device__ __forceinline__ float bf2f(unsigned short h) {
  return __uint_as_float(((unsigned)h) << 16);
}
__device__ __forceinline__ unsigned long long u64min(unsigned long long a,
                                                     unsigned long long b) {
  return (b < a) ? b : a;
}
__device__ __forceinline__ void amin64(unsigned long long* p, unsigned long long v) {
  unsigned long long old = *p;
  while (v < old) {
    unsigned long long assumed = old;
    old = atomicCAS(p, assumed, v);
    if (old == assumed) break;
  }
}
template <int CTRL>
__device__ __forceinline__ unsigned long long dpp_min_u64(unsigned long long x) {
  int xlo = (int)(unsigned)x, xhi = (int)(unsigned)(x >> 32);
  int ylo = __builtin_amdgcn_update_dpp(xlo, xlo, CTRL, 0xf, 0xf, false);
  int yhi = __builtin_amdgcn_update_dpp(xhi, xhi, CTRL, 0xf, 0xf, false);
  unsigned long long y = ((unsigned long long)(unsigned)yhi << 32) | (unsigned)ylo;
  return (y < x) ? y : x;
}
__device__ __forceinline__ unsigned long long wave_min_u64(unsigned long long k) {
  k = dpp_min_u64<0x111>(k); k = dpp_min_u64<0x112>(k);
  k = dpp_min_u64<0x114>(k); k = dpp_min_u64<0x118>(k);
  k = dpp_min_u64<0x142>(k); k = dpp_min_u64<0x143>(k);
  return k;
}
__device__ __forceinline__ unsigned long long grp16_min_u64(unsigned long long k) {
  k = dpp_min_u64<0x111>(k); k = dpp_min_u64<0x112>(k);
  k = dpp_min_u64<0x114>(k); k = dpp_min_u64<0x118>(k);
  return k;
}

// -------- sigmoid + bf16 hi/lo split + fused sq + best1/2 init ------------------
__global__ __launch_bounds__(256) void split_kernel(const float* __restrict__ model,
                                                    const float* __restrict__ labels,
                                                    unsigned short* __restrict__ Hi,
                                                    unsigned short* __restrict__ Lo,
                                                    float* __restrict__ sq,
                                                    unsigned long long* __restrict__ best1,
                                                    unsigned long long* __restrict__ best2,
                                                    int m0) {
  int b = blockIdx.x;
  int mL = b >> 8;
  int m = m0 + mL;
  int tid = threadIdx.x;
  size_t off = (size_t)(b & 255) * 1024 + tid * 4;
  const float* src = ((m & 1) ? labels + (size_t)(m >> 1) * NN2
                              : model + (size_t)(m >> 1) * NN2) + off;
  float4 v = *(const float4*)src;
  if (!(m & 1)) { v.x = sigm(v.x); v.y = sigm(v.y); v.z = sigm(v.z); v.w = sigm(v.w); }
  ushort4 h, l;
  h.x = f2bf(v.x); l.x = f2bf(v.x - bf2f(h.x));
  h.y = f2bf(v.y); l.y = f2bf(v.y - bf2f(h.y));
  h.z = f2bf(v.z); l.z = f2bf(v.z - bf2f(h.z));
  h.w = f2bf(v.w); l.w = f2bf(v.w - bf2f(h.w));
  *(ushort4*)(Hi + (size_t)mL * NN2 + off) = h;
  *(ushort4*)(Lo + (size_t)mL * NN2 + off) = l;
  if (tid == 0) {
    int bi = (b & 255) * 2;
    best1[(size_t)m * NN + bi]     = ~0ull;
    best1[(size_t)m * NN + bi + 1] = ~0ull;
    best2[(size_t)m * NN + bi]     = ~0ull;
    best2[(size_t)m * NN + bi + 1] = ~0ull;
  }
  float s = v.x * v.x + v.y * v.y + v.z * v.z + v.w * v.w;
  #pragma unroll
  for (int o = 32; o > 0; o >>= 1) s += __shfl_down(s, o);
  __shared__ float red[4];
  if ((tid & 63) == 0) red[tid >> 6] = s;
  __syncthreads();
  if (tid == 0) {
    int row0 = (b & 255) * 2;
    sq[(size_t)m * NN + row0]     = red[0] + red[1];
    sq[(size_t)m * NN + row0 + 1] = red[2] + red[3];
  }
}

// ------- distance matrix: r18 (unchanged, current best) -------------------------
__global__ __launch_bounds__(256, 3) void gemm_dist(const unsigned short* __restrict__ Hi,
                                                    const unsigned short* __restrict__ Lo,
                                                    const float* __restrict__ sq,
                                                    unsigned short* __restrict__ Dreg,
                                                    unsigned* __restrict__ maxBits,
                                                    unsigned long long* __restrict__ best1,
                                                    int m0, int nm) {
  __shared__ unsigned short P[4][4096];   // Ah, Al, Bh, Bl (8 KB each; 32 KB)
  int id = blockIdx.x;
  int p, mL;
  if ((nm & 7) == 0) {
    int x = id & 7, t = id >> 3;
    p = t % 10;
    mL = x + 8 * (t / 10);
  } else {
    p = id % 10;
    mL = id / 10;
  }
  int by = (p >= 4) + (p >= 7) + (p >= 9);
  int bx = p - ((by * (7 - by)) >> 1);
  bool diag = (by == bx);
  int m = m0 + mL;
  const unsigned short* Hm = Hi + (size_t)mL * NN2;
  const unsigned short* Lm = Lo + (size_t)mL * NN2;

  int tid = threadIdx.x;
  int wid = tid >> 6, lane = tid & 63;
  int wy = wid >> 1, wx = wid & 1;
  int lr = lane & 15, lk = lane >> 4;

  const unsigned short* wsrcM = (wid & 1) ? Lm : Hm;
  int wrow0 = (wid < 2) ? by * 128 : bx * 128;
  bool stage = (!diag) || (wid < 2);
  int srow = lane >> 2;
  int schunk = (lane & 3) ^ ((lane >> 3) & 3);
  const unsigned short* gsrc = wsrcM + (size_t)(wrow0 + srow) * NN + schunk * 8;
  unsigned short* ldst = &P[wid & 3][0];

  f32x4 acc[4][4];
  #pragma unroll
  for (int i = 0; i < 4; ++i)
    #pragma unroll
    for (int j = 0; j < 4; ++j) acc[i][j] = (f32x4){0.f, 0.f, 0.f, 0.f};

  const unsigned short* bAh = &P[0][0];
  const unsigned short* bAl = &P[1][0];
  const unsigned short* bBh = diag ? &P[0][0] : &P[2][0];
  const unsigned short* bBl = diag ? &P[1][0] : &P[3][0];
  int sw = (lr >> 1) & 3;
  int rao = (wy * 64 + lr) * 32 + (lk ^ sw) * 8;
  int rbo = (wx * 64 + lr) * 32 + (lk ^ sw) * 8;

  for (int s = 0; s < 16; ++s) {
    int k0 = s * 32;
    if (stage) {
      #pragma unroll
      for (int i = 0; i < 8; ++i)
        __builtin_amdgcn_global_load_lds(
            (gas_ptr)(const void*)(gsrc + k0 + (size_t)i * 16 * NN),
            (las_ptr)(void*)(ldst + i * 512), 16, 0, 0);
    }
    __syncthreads();

    short8v fa[4], fb[4], fb2[4];
    #pragma unroll
    for (int i = 0; i < 4; ++i) {
      fa[i] = *(const short8v*)(bAh + rao + i * 512);   // Ah
      fb[i] = *(const short8v*)(bBh + rbo + i * 512);   // Bh
    }
    #pragma unroll
    for (int mi = 0; mi < 4; ++mi)
      #pragma unroll
      for (int ni = 0; ni < 4; ++ni)
        acc[mi][ni] = __builtin_amdgcn_mfma_f32_16x16x32_bf16(fa[mi], fb[ni], acc[mi][ni], 0, 0, 0);
    #pragma unroll
    for (int i = 0; i < 4; ++i)
      fb2[i] = *(const short8v*)(bBl + rbo + i * 512);  // Bl
    #pragma unroll
    for (int mi = 0; mi < 4; ++mi)
      #pragma unroll
      for (int ni = 0; ni < 4; ++ni)
        acc[mi][ni] = __builtin_amdgcn_mfma_f32_16x16x32_bf16(fa[mi], fb2[ni], acc[mi][ni], 0, 0, 0);
    #pragma unroll
    for (int i = 0; i < 4; ++i)
      fa[i] = *(const short8v*)(bAl + rao + i * 512);   // Al
    #pragma unroll
    for (int mi = 0; mi < 4; ++mi)
      #pragma unroll
      for (int ni = 0; ni < 4; ++ni)
        acc[mi][ni] = __builtin_amdgcn_mfma_f32_16x16x32_bf16(fa[mi], fb[ni], acc[mi][ni], 0, 0, 0);
    __syncthreads();
  }

  const float* sqm = sq + (size_t)m * NN;
  unsigned short* Dm = Dreg + (size_t)mL * NN2;
  int gr0 = by * 128 + wy * 64;
  int gc0 = bx * 128 + wx * 64;
  unsigned hmax = 0;
  unsigned long long* b1 = best1 + (size_t)m * NN;
  unsigned long long ck[4];
  #pragma unroll
  for (int i = 0; i < 4; ++i) ck[i] = ~0ull;
  unsigned short us[4][4][4];

  #pragma unroll
  for (int mi = 0; mi < 4; ++mi) {
    int rb = gr0 + mi * 16 + lk * 4;
    float sqi0 = sqm[rb + 0], sqi1 = sqm[rb + 1], sqi2 = sqm[rb + 2], sqi3 = sqm[rb + 3];
    unsigned long long rk[4];
    #pragma unroll
    for (int j = 0; j < 4; ++j) rk[j] = ~0ull;
    #pragma unroll
    for (int ni = 0; ni < 4; ++ni) {
      int col = gc0 + ni * 16 + lr;
      float sqj = sqm[col];
      f32x4 a = acc[mi][ni];
      unsigned short h0 = f2bf(sqrtf(fmaxf(sqi0 + sqj - 2.f * a[0], 0.f)));
      unsigned short h1 = f2bf(sqrtf(fmaxf(sqi1 + sqj - 2.f * a[1], 0.f)));
      unsigned short h2 = f2bf(sqrtf(fmaxf(sqi2 + sqj - 2.f * a[2], 0.f)));
      unsigned short h3 = f2bf(sqrtf(fmaxf(sqi3 + sqj - 2.f * a[3], 0.f)));
      us[mi][ni][0] = h0; us[mi][ni][1] = h1;
      us[mi][ni][2] = h2; us[mi][ni][3] = h3;
      unsigned hm01 = (h0 > h1) ? h0 : h1;
      unsigned hm23 = (h2 > h3) ? h2 : h3;
      unsigned hm = (hm01 > hm23) ? hm01 : hm23;
      hmax = (hm > hmax) ? hm : hmax;
      unsigned short hh[4] = {h0, h1, h2, h3};
      #pragma unroll
      for (int rg = 0; rg < 4; ++rg) {
        int row = rb + rg;
        if (!diag || col != row) {
          unsigned lo = (row < col) ? (unsigned)(row * NN + col)
                                    : (unsigned)(col * NN + row);
          unsigned long long key = ((unsigned long long)hh[rg] << 48) | lo;
          rk[rg] = u64min(rk[rg], key);
          ck[ni] = u64min(ck[ni], key);
        }
      }
    }
    #pragma unroll
    for (int rg = 0; rg < 4; ++rg) {
      unsigned long long k = grp16_min_u64(rk[rg]);
      if (lr == 15) atomicMin(&b1[rb + rg], k);
    }
  }
  if (!diag) {
    #pragma unroll
    for (int ni = 0; ni < 4; ++ni) {
      unsigned long long k = ck[ni];
      k = u64min(k, __shfl_xor(k, 16));
      k = u64min(k, __shfl_xor(k, 32));
      if (lk == 0) atomicMin(&b1[gc0 + ni * 16 + lr], k);
    }
  }

  __syncthreads();                                   // staging LDS dead
  unsigned short* W = &P[0][0] + wid * 1216;         // 16 x 76 ushort per-wave
  int rlo = lane >> 4, cq = lane & 15;
  #pragma unroll
  for (int mi = 0; mi < 4; ++mi) {
    #pragma unroll
    for (int ni = 0; ni < 4; ++ni)
      #pragma unroll
      for (int j = 0; j < 4; ++j)
        W[(lk * 4 + j) * 76 + ni * 16 + lr] = us[mi][ni][j];
    #pragma unroll
    for (int g = 0; g < 4; ++g) {
      int r16 = g * 4 + rlo;
      ushort4 t = *(const ushort4*)&W[r16 * 76 + cq * 4];
      *(ushort4*)(Dm + (size_t)(gr0 + mi * 16 + r16) * NN + gc0 + cq * 4) = t;
    }
  }
  if (!diag) {
    #pragma unroll
    for (int ni = 0; ni < 4; ++ni) {
      #pragma unroll
      for (int mi = 0; mi < 4; ++mi)
        *(ushort4*)&W[lr * 76 + mi * 16 + lk * 4] =
            make_ushort4(us[mi][ni][0], us[mi][ni][1], us[mi][ni][2], us[mi][ni][3]);
      #pragma unroll
      for (int g = 0; g < 4; ++g) {
        int r16 = g * 4 + rlo;
        ushort4 t = *(const ushort4*)&W[r16 * 76 + cq * 4];
        *(ushort4*)(Dm + (size_t)(gc0 + ni * 16 + r16) * NN + gr0 + cq * 4) = t;
      }
    }
  }

  #pragma unroll
  for (int off = 32; off > 0; off >>= 1) {
    unsigned o = (unsigned)__shfl_down((int)hmax, off);
    hmax = (o > hmax) ? o : hmax;
  }
  if (lane == 0) atomicMax(&maxBits[m], hmax << 16);
}

// -------- phase-2 scan + inlined phase-1 hook + DcG init (r18, unchanged) -------
__global__ __launch_bounds__(512) void scan2_kernel(const unsigned short* __restrict__ Dreg,
                                                    const unsigned long long* __restrict__ best1,
                                                    int* __restrict__ compG,
                                                    unsigned long long* __restrict__ best2,
                                                    unsigned long long* __restrict__ DcG,
                                                    int2* __restrict__ eo_all,
                                                    int* __restrict__ ecntG, int m0) {
  int sblk = blockIdx.x, mL = blockIdx.y, m = m0 + mL;
  const unsigned short* D = Dreg + (size_t)mL * NN2;
  __shared__ int compP[NN + 64];
  __shared__ int hook[NN], parent[NN];
  __shared__ int ecnt;
  int tid = threadIdx.x;
  int wave = tid >> 6, lane = tid & 63;
  int c0 = lane * 8;

  unsigned long long* dginit = DcG + (size_t)mL * 16384 + sblk * 2048;
  #pragma unroll
  for (int i = 0; i < 4; ++i) dginit[tid + i * 512] = ~0ull;

  if (tid == 0) ecnt = 0;
  unsigned long long b = best1[(size_t)m * NN + tid];
  int h;
  if (b != ~0ull) {
    int idx = (int)(unsigned)b & 0x3ffff;
    int er = idx >> 9, ec = idx & 511;
    h = (er == tid) ? ec : er;
  } else h = tid;
  hook[tid] = h;
  __syncthreads();
  bool active = (b != ~0ull);
  int p = h;
  bool mutual = active && (hook[p] == tid);
  parent[tid] = (!active) ? tid : ((mutual && tid < p) ? tid : p);
  if (sblk == 0 && active && (!mutual || tid > p)) {
    int idx = (int)(unsigned)b & 0x3ffff;
    int e = atomicAdd(&ecnt, 1);
    eo_all[(size_t)m * (NN - 1) + e] = make_int2(idx >> 9, idx & 511);
  }
  __syncthreads();
  int c = tid, pp = parent[c];
  while (pp != c) { c = pp; pp = parent[c]; }
  compP[tid + (tid >> 3)] = c;
  if (sblk == 0) {
    compG[(size_t)m * NN + tid] = c;
    if (tid == 0) ecntG[m] = ecnt;
  }
  __syncthreads();

  unsigned long long* b2 = best2 + (size_t)m * NN;
  #pragma unroll
  for (int rr = 0; rr < 8; ++rr) {
    int r = sblk * 64 + wave * 8 + rr;
    int cr = compP[r + (r >> 3)];
    uint4 dv = *(const uint4*)(D + (size_t)r * NN + c0);
    int4 cc0 = *(const int4*)(compP + c0 + (c0 >> 3));
    int4 cc1 = *(const int4*)(compP + c0 + 4 + (c0 >> 3));
    unsigned hh[8] = {dv.x & 0xffffu, dv.x >> 16, dv.y & 0xffffu, dv.y >> 16,
                      dv.z & 0xffffu, dv.z >> 16, dv.w & 0xffffu, dv.w >> 16};
    int cv[8] = {cc0.x, cc0.y, cc0.z, cc0.w, cc1.x, cc1.y, cc1.z, cc1.w};
    unsigned long long k = ~0ull;
    #pragma unroll
    for (int e = 0; e < 8; ++e) {
      if (cv[e] != cr) {
        int col = c0 + e;
        int lo = (r < col) ? r * NN + col : col * NN + r;
        unsigned long long key = ((unsigned long long)hh[e] << 48) | (unsigned)lo;
        k = u64min(k, key);
      }
    }
    k = wave_min_u64(k);
    if (lane == 63 && k != ~0ull) atomicMin(&b2[cr], k);
  }
}

// ---- deterministic inline hook2 (BARRIER-UNIFORM: call from ALL threads) -------
// dense id of a phase-2 root r = #roots with node-id < r (ballot prefix).
// Pure function of best2/compG -> identical result in every block.
__device__ __forceinline__ void hook2_inline(const unsigned long long* b2m,
                                             const int* compG_m, int tid, bool valid,
                                             int wave, int lane, bool emit,
                                             int2* eo, int* ecnt,
                                             int* comp, int* hookA, int* parentA,
                                             unsigned long long* rootMask,
                                             int* denseOut, int* Cout) {
  unsigned long long b = ~0ull;
  if (valid) { comp[tid] = compG_m[tid]; b = b2m[tid]; }
  __syncthreads();
  int h = tid;
  if (valid && b != ~0ull) {
    int idx = (int)(unsigned)b & 0x3ffff;
    int er = idx >> 9, ec = idx & 511;
    int c1 = comp[er], c2 = comp[ec];
    h = (c1 == tid) ? c2 : c1;
  }
  if (valid) hookA[tid] = h;
  __syncthreads();
  if (valid) {
    bool active = (b != ~0ull);
    int p = h;
    bool mutual = active && (hookA[p] == tid);
    parentA[tid] = (!active) ? tid : ((mutual && tid < p) ? tid : p);
    if (emit && active && (!mutual || tid > p)) {
      int idx = (int)(unsigned)b & 0x3ffff;
      int e = atomicAdd(ecnt, 1);
      eo[e] = make_int2(idx >> 9, idx & 511);
    }
  }
  __syncthreads();
  int c = 0;
  bool isRoot = false;
  if (valid) {
    c = comp[tid];
    int pp = parentA[c];
    while (pp != c) { c = pp; pp = parentA[c]; }
    isRoot = (c == tid);
  }
  unsigned long long rm = __ballot(isRoot);
  if (valid && lane == 0) rootMask[wave] = rm;   // valid => wave < 8
  __syncthreads();
  int cw = c >> 6, cl = c & 63;
  int dense = 0, C = 0;
  #pragma unroll
  for (int w = 0; w < 8; ++w) {
    int pc = __popcll(rootMask[w]);
    C += pc;
    if (w < cw) dense += pc;
  }
  dense += __popcll(rootMask[cw] & (cl ? ((~0ull) >> (64 - cl)) : 0ull));
  *denseOut = dense;
  *Cout = C;
}

// -------- contraction (+inlined hook2): build Dc from bf16 D --------------------
__global__ __launch_bounds__(512) void contract_kernel(const unsigned short* __restrict__ Dreg,
                                                       const unsigned long long* __restrict__ best2,
                                                       const int* __restrict__ compG,
                                                       unsigned long long* __restrict__ DcG,
                                                       int2* __restrict__ eo_all,
                                                       int* __restrict__ ecntG, int m0) {
  int q = blockIdx.x, mL = blockIdx.y, m = m0 + mL;
  const unsigned short* D = Dreg + (size_t)mL * NN2;
  __shared__ unsigned long long Dc[128 * 128];
  __shared__ int comp[NN], hookA[NN], parentA[NN];
  __shared__ int c2P[NN + 64];
  __shared__ unsigned long long rootMask[8];
  __shared__ int ecnt;
  int tid = threadIdx.x;
  int wave = tid >> 6, lane = tid & 63;
  int c0 = lane * 8;
  for (int i = tid; i < 16384; i += 512) Dc[i] = ~0ull;
  if (tid == 0) ecnt = ecntG[m];
  __syncthreads();
  int dense, C;
  hook2_inline(best2 + (size_t)m * NN, compG + (size_t)m * NN, tid, true, wave, lane,
               q == 0, eo_all + (size_t)m * (NN - 1), &ecnt,
               comp, hookA, parentA, rootMask, &dense, &C);
  c2P[tid + (tid >> 3)] = dense;
  __syncthreads();
  if (q == 0 && tid == 0) ecntG[m] = ecnt;     // emits complete before this barrier

  #pragma unroll
  for (int rr = 0; rr < 16; ++rr) {
    int r = q * 128 + wave * 16 + rr;
    int di = c2P[r + (r >> 3)];
    uint4 dv = *(const uint4*)(D + (size_t)r * NN + c0);
    int4 cc0 = *(const int4*)(c2P + c0 + (c0 >> 3));
    int4 cc1 = *(const int4*)(c2P + c0 + 4 + (c0 >> 3));
    unsigned hh[8] = {dv.x & 0xffffu, dv.x >> 16, dv.y & 0xffffu, dv.y >> 16,
                      dv.z & 0xffffu, dv.z >> 16, dv.w & 0xffffu, dv.w >> 16};
    int cv[8] = {cc0.x, cc0.y, cc0.z, cc0.w, cc1.x, cc1.y, cc1.z, cc1.w};
    #pragma unroll
    for (int e = 0; e < 8; ++e) {
      if (cv[e] != di) {
        int col = c0 + e;
        int lo = (r < col) ? r * NN + col : col * NN + r;
        unsigned long long key = ((unsigned long long)hh[e] << 48) | (unsigned)lo;
        amin64(&Dc[di * 128 + cv[e]], key);
      }
    }
  }
  __syncthreads();
  unsigned long long* dg = DcG + (size_t)mL * 16384;
  for (int i = tid; i < 16384; i += 512) {
    unsigned long long v = Dc[i];
    if (v != ~0ull) atomicMin(&dg[i], v);
  }
}

// -------- finish (+inlined hook2 labels): LDS phases + fused gather -------------
__global__ __launch_bounds__(1024) void finish_kernel(const unsigned short* __restrict__ Dreg,
                                                      const unsigned long long* __restrict__ DcG,
                                                      const unsigned long long* __restrict__ best2,
                                                      const int* __restrict__ compG,
                                                      int2* __restrict__ eo_all,
                                                      int* __restrict__ ecntG,
                                                      const unsigned* __restrict__ maxBits,
                                                      float* __restrict__ out, int m0) {
  int mL = blockIdx.x, m = m0 + mL;
  __shared__ unsigned long long Dc[16384];
  __shared__ int c2n[NN];
  __shared__ int comp[NN], hookA[NN], parentA[NN];
  __shared__ unsigned long long rootMask[8];
  __shared__ unsigned long long best[128];
  __shared__ int comp2[128], hook128[128], parent128[128];
  __shared__ float fred[16];
  __shared__ int ecnt, Csh;
  int tid = threadIdx.x;
  int wave = tid >> 6, lane = tid & 63;
  const unsigned long long* dg = DcG + (size_t)mL * 16384;
  for (int i = tid; i < 16384; i += 1024) Dc[i] = dg[i];
  if (tid < 128) comp2[tid] = tid;
  if (tid == 0) ecnt = ecntG[m];     // includes phase-2 edges (written by contract)
  __syncthreads();
  {
    int dense, C;
    hook2_inline(best2 + (size_t)m * NN, compG + (size_t)m * NN, tid, tid < NN,
                 wave, lane, false, nullptr, nullptr,
                 comp, hookA, parentA, rootMask, &dense, &C);
    if (tid < NN) c2n[tid] = dense;
    if (tid == 0) Csh = C;
  }
  __syncthreads();
  int C = Csh;
  int2* eo = eo_all + (size_t)m * (NN - 1);

  for (int ph = 0; ph < 7; ++ph) {
    if (ecnt >= NN - 1) break;
    if (tid < 128) best[tid] = ~0ull;
    __syncthreads();
    for (int i = tid; i < C * 128; i += 1024) {
      unsigned long long key = Dc[i];
      if (key == ~0ull) continue;
      int a = i >> 7, bb = i & 127;
      int ca = comp2[a], cb = comp2[bb];
      if (ca != cb) amin64(&best[ca], key);
    }
    __syncthreads();
    if (tid < C) {
      unsigned long long b = best[tid];
      int h;
      if (b != ~0ull) {
        int pid = (int)(unsigned)b & 0x3ffff;
        int er = pid >> 9, ec = pid & 511;
        int c1 = comp2[c2n[er]], c2v = comp2[c2n[ec]];
        h = (c1 == tid) ? c2v : c1;
      } else h = tid;
      hook128[tid] = h;
    }
    __syncthreads();
    if (tid < C) {
      unsigned long long b = best[tid];
      bool active = (b != ~0ull);
      int p = hook128[tid];
      bool mutual = active && (hook128[p] == tid);
      parent128[tid] = (!active) ? tid : ((mutual && tid < p) ? tid : p);
      if (active && (!mutual || tid > p)) {
        int pid = (int)(unsigned)b & 0x3ffff;
        int e = atomicAdd(&ecnt, 1);
        eo[e] = make_int2(pid >> 9, pid & 511);
      }
    }
    __syncthreads();
    if (tid < C) {
      int c = comp2[tid], pp = parent128[c];
      while (pp != c) { c = pp; pp = parent128[c]; }
      comp2[tid] = c;
    }
    __syncthreads();
  }
  __syncthreads();

  // fused loss gather (bf16 D)
  int b = m >> 1;
  float mxX = fmaxf(__uint_as_float(maxBits[2 * b]), 1e-12f);
  float mxZ = fmaxf(__uint_as_float(maxBits[2 * b + 1]), 1e-12f);
  float rX = 1.0f / mxX, rZ = 1.0f / mxZ;
  const unsigned short* Dx = Dreg + (size_t)(mL & ~1) * NN2;
  const unsigned short* Dz = Dx + NN2;
  float acc = 0.f;
  if (tid < NN - 1) {
    int2 e = eo[tid];
    size_t off = (size_t)e.x * NN + e.y;
    float d = bf2f(Dx[off]) * rX - bf2f(Dz[off]) * rZ;
    acc = d * d;
  }
  #pragma unroll
  for (int o = 32; o > 0; o >>= 1) acc += __shfl_down(acc, o);
  if (lane == 0) fred[wave] = acc;
  __syncthreads();
  if (tid == 0) {
    float t = 0.f;
    #pragma unroll
    for (int i = 0; i < 16; ++i) t += fred[i];
    atomicAdd(out, t * (1.0f / NB));
  }
}

extern "C" void kernel_launch(void* const* d_in, const int* in_sizes, int n_in,
                              void* d_out, int out_size, void* d_ws, size_t ws_size,
                              hipStream_t stream) {
  const float* model = (const float*)d_in[0];
  const float* labels = (const float*)d_in[1];
  float* out = (float*)d_out;
  char* ws = (char*)d_ws;

  float*              sq      = (float*)(ws);                       // 131072
  unsigned*           maxBits = (unsigned*)(ws + 131072);           // -> 132096
  int2*               eo      = (int2*)(ws + 132096);               // -> 393728
  unsigned long long* best1   = (unsigned long long*)(ws + 393728); // -> 655872
  unsigned long long* best2   = (unsigned long long*)(ws + 655872); // -> 918016
  int*                compG   = (int*)(ws + 918016);                // -> 1049088
  int*                ecntG   = (int*)(ws + 1049088);               // -> 1049344
  size_t base = 1050624;

  // per batch (2 matrices): D bf16 1MB + Hi 1MB + Lo 1MB + Dc 256KB
  size_t perBatch = 2ull * (NN2 * 2 + 2ull * NN2 * 2 + 16384 * 8);
  size_t dcap = (ws_size > base) ? (ws_size - base) : 0;
  int cb = (int)(dcap / perBatch);
  if (cb > NB) cb = NB;
  if (cb < 1) cb = 1;
  int nmc = 2 * cb;

  unsigned short* Dreg = (unsigned short*)(ws + base);
  unsigned short* Hi = Dreg + (size_t)nmc * NN2;
  unsigned short* Lo = Hi + (size_t)nmc * NN2;
  unsigned long long* DcG = (unsigned long long*)(Lo + (size_t)nmc * NN2);

  hipMemsetAsync(d_out, 0, sizeof(float), stream);
  hipMemsetAsync(maxBits, 0, 64 * sizeof(unsigned), stream);

  for (int b0 = 0; b0 < NB; b0 += cb) {
    int nb = (NB - b0 < cb) ? (NB - b0) : cb;
    int nm = 2 * nb, m0 = 2 * b0;
    split_kernel<<<nm * 256, 256, 0, stream>>>(model, labels, Hi, Lo, sq,
                                               best1, best2, m0);
    gemm_dist<<<10 * nm, 256, 0, stream>>>(Hi, Lo, sq, Dreg, maxBits, best1, m0, nm);
    scan2_kernel<<<dim3(8, nm), 512, 0, stream>>>(Dreg, best1, compG, best2, DcG,
                                                  eo, ecntG, m0);
    contract_kernel<<<dim3(4, nm), 512, 0, stream>>>(Dreg, best2, compG, DcG,
                                                     eo, ecntG, m0);
    finish_kernel<<<nm, 1024, 0, stream>>>(Dreg, DcG, best2, compG, eo, ecntG,
                                           maxBits, out, m0);
  }
}

// Round 21
// 133.375 us; speedup vs baseline: 1.4044x; 1.0265x over previous
//
#include <hip/hip_runtime.h>
#include <math.h>

#define NN 512
#define NN2 (NN*NN)
#define NB 32
#define NM 64

typedef __attribute__((ext_vector_type(8))) short short8v;   // 8 bf16 (4 VGPR)
typedef __attribute__((ext_vector_type(4))) float f32x4;     // MFMA acc

typedef const unsigned int __attribute__((address_space(1)))* gas_ptr;
typedef unsigned int __attribute__((address_space(3)))* las_ptr;

__device__ __forceinline__ float sigm(float x) { return 1.0f / (1.0f + expf(-x)); }

__device__ __forceinline__ unsigned short f2bf(float x) {
  unsigned u = __float_as_uint(x);
  return (unsigned short)((u + 0x7fffu + ((u >> 16) & 1u)) >> 16);   // RNE
}
__device__ __forceinline__ float bf2f(unsigned short h) {
  return __uint_as_float(((unsigned)h) << 16);
}
__device__ __forceinline__ unsigned long long u64min(unsigned long long a,
                                                     unsigned long long b) {
  return (b < a) ? b : a;
}
__device__ __forceinline__ void amin64(unsigned long long* p, unsigned long long v) {
  unsigned long long old = *p;
  while (v < old) {
    unsigned long long assumed = old;
    old = atomicCAS(p, assumed, v);
    if (old == assumed) break;
  }
}
template <int CTRL>
__device__ __forceinline__ unsigned long long dpp_min_u64(unsigned long long x) {
  int xlo = (int)(unsigned)x, xhi = (int)(unsigned)(x >> 32);
  int ylo = __builtin_amdgcn_update_dpp(xlo, xlo, CTRL, 0xf, 0xf, false);
  int yhi = __builtin_amdgcn_update_dpp(xhi, xhi, CTRL, 0xf, 0xf, false);
  unsigned long long y = ((unsigned long long)(unsigned)yhi << 32) | (unsigned)ylo;
  return (y < x) ? y : x;
}
__device__ __forceinline__ unsigned long long wave_min_u64(unsigned long long k) {
  k = dpp_min_u64<0x111>(k); k = dpp_min_u64<0x112>(k);
  k = dpp_min_u64<0x114>(k); k = dpp_min_u64<0x118>(k);
  k = dpp_min_u64<0x142>(k); k = dpp_min_u64<0x143>(k);
  return k;
}
__device__ __forceinline__ unsigned long long grp16_min_u64(unsigned long long k) {
  k = dpp_min_u64<0x111>(k); k = dpp_min_u64<0x112>(k);
  k = dpp_min_u64<0x114>(k); k = dpp_min_u64<0x118>(k);
  return k;
}

// -------- sigmoid + bf16 hi/lo split + fused sq + best1/2 init ------------------
__global__ __launch_bounds__(256) void split_kernel(const float* __restrict__ model,
                                                    const float* __restrict__ labels,
                                                    unsigned short* __restrict__ Hi,
                                                    unsigned short* __restrict__ Lo,
                                                    float* __restrict__ sq,
                                                    unsigned long long* __restrict__ best1,
                                                    unsigned long long* __restrict__ best2,
                                                    int m0) {
  int b = blockIdx.x;
  int mL = b >> 8;
  int m = m0 + mL;
  int tid = threadIdx.x;
  size_t off = (size_t)(b & 255) * 1024 + tid * 4;
  const float* src = ((m & 1) ? labels + (size_t)(m >> 1) * NN2
                              : model + (size_t)(m >> 1) * NN2) + off;
  float4 v = *(const float4*)src;
  if (!(m & 1)) { v.x = sigm(v.x); v.y = sigm(v.y); v.z = sigm(v.z); v.w = sigm(v.w); }
  ushort4 h, l;
  h.x = f2bf(v.x); l.x = f2bf(v.x - bf2f(h.x));
  h.y = f2bf(v.y); l.y = f2bf(v.y - bf2f(h.y));
  h.z = f2bf(v.z); l.z = f2bf(v.z - bf2f(h.z));
  h.w = f2bf(v.w); l.w = f2bf(v.w - bf2f(h.w));
  *(ushort4*)(Hi + (size_t)mL * NN2 + off) = h;
  *(ushort4*)(Lo + (size_t)mL * NN2 + off) = l;
  if (tid == 0) {
    int bi = (b & 255) * 2;
    best1[(size_t)m * NN + bi]     = ~0ull;
    best1[(size_t)m * NN + bi + 1] = ~0ull;
    best2[(size_t)m * NN + bi]     = ~0ull;
    best2[(size_t)m * NN + bi + 1] = ~0ull;
  }
  float s = v.x * v.x + v.y * v.y + v.z * v.z + v.w * v.w;
  #pragma unroll
  for (int o = 32; o > 0; o >>= 1) s += __shfl_down(s, o);
  __shared__ float red[4];
  if ((tid & 63) == 0) red[tid >> 6] = s;
  __syncthreads();
  if (tid == 0) {
    int row0 = (b & 255) * 2;
    sq[(size_t)m * NN + row0]     = red[0] + red[1];
    sq[(size_t)m * NN + row0 + 1] = red[2] + red[3];
  }
}

// ------- distance matrix: 2-pass off-diag (hh + h*l, mirror-symmetric),
//         3-pass diag; bf16 D; single-conversion epilogue -----------------------
__global__ __launch_bounds__(256, 3) void gemm_dist(const unsigned short* __restrict__ Hi,
                                                    const unsigned short* __restrict__ Lo,
                                                    const float* __restrict__ sq,
                                                    unsigned short* __restrict__ Dreg,
                                                    unsigned* __restrict__ maxBits,
                                                    unsigned long long* __restrict__ best1,
                                                    int m0, int nm) {
  __shared__ unsigned short P[4][4096];   // Ah, Al, Bh, Bl (8 KB each; 32 KB)
  int id = blockIdx.x;
  int p, mL;
  if ((nm & 7) == 0) {
    int x = id & 7, t = id >> 3;
    p = t % 10;
    mL = x + 8 * (t / 10);
  } else {
    p = id % 10;
    mL = id / 10;
  }
  int by = (p >= 4) + (p >= 7) + (p >= 9);
  int bx = p - ((by * (7 - by)) >> 1);
  bool diag = (by == bx);
  int m = m0 + mL;
  const unsigned short* Hm = Hi + (size_t)mL * NN2;
  const unsigned short* Lm = Lo + (size_t)mL * NN2;

  int tid = threadIdx.x;
  int wid = tid >> 6, lane = tid & 63;
  int wy = wid >> 1, wx = wid & 1;
  int lr = lane & 15, lk = lane >> 4;

  const unsigned short* wsrcM = (wid & 1) ? Lm : Hm;
  int wrow0 = (wid < 2) ? by * 128 : bx * 128;
  // diag: stage Ah,Al (waves 0,1). non-diag: stage Ah,Bh,Bl (waves 0,2,3) — Al unused.
  bool stage = diag ? (wid < 2) : (wid != 1);
  int srow = lane >> 2;
  int schunk = (lane & 3) ^ ((lane >> 3) & 3);
  const unsigned short* gsrc = wsrcM + (size_t)(wrow0 + srow) * NN + schunk * 8;
  unsigned short* ldst = &P[wid & 3][0];

  f32x4 acc[4][4];
  #pragma unroll
  for (int i = 0; i < 4; ++i)
    #pragma unroll
    for (int j = 0; j < 4; ++j) acc[i][j] = (f32x4){0.f, 0.f, 0.f, 0.f};

  const unsigned short* bAh = &P[0][0];
  const unsigned short* bAl = &P[1][0];
  const unsigned short* bBh = diag ? &P[0][0] : &P[2][0];
  const unsigned short* bBl = diag ? &P[1][0] : &P[3][0];
  int sw = (lr >> 1) & 3;
  int rao = (wy * 64 + lr) * 32 + (lk ^ sw) * 8;
  int rbo = (wx * 64 + lr) * 32 + (lk ^ sw) * 8;

  for (int s = 0; s < 16; ++s) {
    int k0 = s * 32;
    if (stage) {
      #pragma unroll
      for (int i = 0; i < 8; ++i)
        __builtin_amdgcn_global_load_lds(
            (gas_ptr)(const void*)(gsrc + k0 + (size_t)i * 16 * NN),
            (las_ptr)(void*)(ldst + i * 512), 16, 0, 0);
    }
    __syncthreads();

    short8v fa[4], fb[4], fb2[4];
    #pragma unroll
    for (int i = 0; i < 4; ++i) {
      fa[i] = *(const short8v*)(bAh + rao + i * 512);   // Ah
      fb[i] = *(const short8v*)(bBh + rbo + i * 512);   // Bh
    }
    #pragma unroll
    for (int mi = 0; mi < 4; ++mi)
      #pragma unroll
      for (int ni = 0; ni < 4; ++ni)
        acc[mi][ni] = __builtin_amdgcn_mfma_f32_16x16x32_bf16(fa[mi], fb[ni], acc[mi][ni], 0, 0, 0);
    #pragma unroll
    for (int i = 0; i < 4; ++i)
      fb2[i] = *(const short8v*)(bBl + rbo + i * 512);  // Bl
    #pragma unroll
    for (int mi = 0; mi < 4; ++mi)
      #pragma unroll
      for (int ni = 0; ni < 4; ++ni)
        acc[mi][ni] = __builtin_amdgcn_mfma_f32_16x16x32_bf16(fa[mi], fb2[ni], acc[mi][ni], 0, 0, 0);
    if (diag) {                      // lh pass only for diagonal tiles (symmetry)
      #pragma unroll
      for (int i = 0; i < 4; ++i)
        fa[i] = *(const short8v*)(bAl + rao + i * 512); // Al
      #pragma unroll
      for (int mi = 0; mi < 4; ++mi)
        #pragma unroll
        for (int ni = 0; ni < 4; ++ni)
          acc[mi][ni] = __builtin_amdgcn_mfma_f32_16x16x32_bf16(fa[mi], fb[ni], acc[mi][ni], 0, 0, 0);
    }
    __syncthreads();
  }

  const float* sqm = sq + (size_t)m * NN;
  unsigned short* Dm = Dreg + (size_t)mL * NN2;
  int gr0 = by * 128 + wy * 64;
  int gc0 = bx * 128 + wx * 64;
  unsigned hmax = 0;
  unsigned long long* b1 = best1 + (size_t)m * NN;
  unsigned long long ck[4];
  #pragma unroll
  for (int i = 0; i < 4; ++i) ck[i] = ~0ull;
  unsigned short us[4][4][4];

  #pragma unroll
  for (int mi = 0; mi < 4; ++mi) {
    int rb = gr0 + mi * 16 + lk * 4;
    float sqi0 = sqm[rb + 0], sqi1 = sqm[rb + 1], sqi2 = sqm[rb + 2], sqi3 = sqm[rb + 3];
    unsigned long long rk[4];
    #pragma unroll
    for (int j = 0; j < 4; ++j) rk[j] = ~0ull;
    #pragma unroll
    for (int ni = 0; ni < 4; ++ni) {
      int col = gc0 + ni * 16 + lr;
      float sqj = sqm[col];
      f32x4 a = acc[mi][ni];
      unsigned short h0 = f2bf(sqrtf(fmaxf(sqi0 + sqj - 2.f * a[0], 0.f)));
      unsigned short h1 = f2bf(sqrtf(fmaxf(sqi1 + sqj - 2.f * a[1], 0.f)));
      unsigned short h2 = f2bf(sqrtf(fmaxf(sqi2 + sqj - 2.f * a[2], 0.f)));
      unsigned short h3 = f2bf(sqrtf(fmaxf(sqi3 + sqj - 2.f * a[3], 0.f)));
      us[mi][ni][0] = h0; us[mi][ni][1] = h1;
      us[mi][ni][2] = h2; us[mi][ni][3] = h3;
      unsigned hm01 = (h0 > h1) ? h0 : h1;
      unsigned hm23 = (h2 > h3) ? h2 : h3;
      unsigned hm = (hm01 > hm23) ? hm01 : hm23;
      hmax = (hm > hmax) ? hm : hmax;
      unsigned short hh[4] = {h0, h1, h2, h3};
      #pragma unroll
      for (int rg = 0; rg < 4; ++rg) {
        int row = rb + rg;
        if (!diag || col != row) {
          unsigned lo = (row < col) ? (unsigned)(row * NN + col)
                                    : (unsigned)(col * NN + row);
          unsigned long long key = ((unsigned long long)hh[rg] << 48) | lo;
          rk[rg] = u64min(rk[rg], key);
          ck[ni] = u64min(ck[ni], key);
        }
      }
    }
    #pragma unroll
    for (int rg = 0; rg < 4; ++rg) {
      unsigned long long k = grp16_min_u64(rk[rg]);
      if (lr == 15) atomicMin(&b1[rb + rg], k);
    }
  }
  if (!diag) {
    #pragma unroll
    for (int ni = 0; ni < 4; ++ni) {
      unsigned long long k = ck[ni];
      k = u64min(k, __shfl_xor(k, 16));
      k = u64min(k, __shfl_xor(k, 32));
      if (lk == 0) atomicMin(&b1[gc0 + ni * 16 + lr], k);
    }
  }

  __syncthreads();                                   // staging LDS dead
  unsigned short* W = &P[0][0] + wid * 1216;         // 16 x 76 ushort per-wave
  int rlo = lane >> 4, cq = lane & 15;
  #pragma unroll
  for (int mi = 0; mi < 4; ++mi) {
    #pragma unroll
    for (int ni = 0; ni < 4; ++ni)
      #pragma unroll
      for (int j = 0; j < 4; ++j)
        W[(lk * 4 + j) * 76 + ni * 16 + lr] = us[mi][ni][j];
    #pragma unroll
    for (int g = 0; g < 4; ++g) {
      int r16 = g * 4 + rlo;
      ushort4 t = *(const ushort4*)&W[r16 * 76 + cq * 4];
      *(ushort4*)(Dm + (size_t)(gr0 + mi * 16 + r16) * NN + gc0 + cq * 4) = t;
    }
  }
  if (!diag) {
    #pragma unroll
    for (int ni = 0; ni < 4; ++ni) {
      #pragma unroll
      for (int mi = 0; mi < 4; ++mi)
        *(ushort4*)&W[lr * 76 + mi * 16 + lk * 4] =
            make_ushort4(us[mi][ni][0], us[mi][ni][1], us[mi][ni][2], us[mi][ni][3]);
      #pragma unroll
      for (int g = 0; g < 4; ++g) {
        int r16 = g * 4 + rlo;
        ushort4 t = *(const ushort4*)&W[r16 * 76 + cq * 4];
        *(ushort4*)(Dm + (size_t)(gc0 + ni * 16 + r16) * NN + gr0 + cq * 4) = t;
      }
    }
  }

  #pragma unroll
  for (int off = 32; off > 0; off >>= 1) {
    unsigned o = (unsigned)__shfl_down((int)hmax, off);
    hmax = (o > hmax) ? o : hmax;
  }
  if (lane == 0) atomicMax(&maxBits[m], hmax << 16);
}

// -------- phase-2 scan + inlined phase-1 hook + DcG init (r20, unchanged) -------
__global__ __launch_bounds__(512) void scan2_kernel(const unsigned short* __restrict__ Dreg,
                                                    const unsigned long long* __restrict__ best1,
                                                    int* __restrict__ compG,
                                                    unsigned long long* __restrict__ best2,
                                                    unsigned long long* __restrict__ DcG,
                                                    int2* __restrict__ eo_all,
                                                    int* __restrict__ ecntG, int m0) {
  int sblk = blockIdx.x, mL = blockIdx.y, m = m0 + mL;
  const unsigned short* D = Dreg + (size_t)mL * NN2;
  __shared__ int compP[NN + 64];
  __shared__ int hook[NN], parent[NN];
  __shared__ int ecnt;
  int tid = threadIdx.x;
  int wave = tid >> 6, lane = tid & 63;
  int c0 = lane * 8;

  unsigned long long* dginit = DcG + (size_t)mL * 16384 + sblk * 2048;
  #pragma unroll
  for (int i = 0; i < 4; ++i) dginit[tid + i * 512] = ~0ull;

  if (tid == 0) ecnt = 0;
  unsigned long long b = best1[(size_t)m * NN + tid];
  int h;
  if (b != ~0ull) {
    int idx = (int)(unsigned)b & 0x3ffff;
    int er = idx >> 9, ec = idx & 511;
    h = (er == tid) ? ec : er;
  } else h = tid;
  hook[tid] = h;
  __syncthreads();
  bool active = (b != ~0ull);
  int p = h;
  bool mutual = active && (hook[p] == tid);
  parent[tid] = (!active) ? tid : ((mutual && tid < p) ? tid : p);
  if (sblk == 0 && active && (!mutual || tid > p)) {
    int idx = (int)(unsigned)b & 0x3ffff;
    int e = atomicAdd(&ecnt, 1);
    eo_all[(size_t)m * (NN - 1) + e] = make_int2(idx >> 9, idx & 511);
  }
  __syncthreads();
  int c = tid, pp = parent[c];
  while (pp != c) { c = pp; pp = parent[c]; }
  compP[tid + (tid >> 3)] = c;
  if (sblk == 0) {
    compG[(size_t)m * NN + tid] = c;
    if (tid == 0) ecntG[m] = ecnt;
  }
  __syncthreads();

  unsigned long long* b2 = best2 + (size_t)m * NN;
  #pragma unroll
  for (int rr = 0; rr < 8; ++rr) {
    int r = sblk * 64 + wave * 8 + rr;
    int cr = compP[r + (r >> 3)];
    uint4 dv = *(const uint4*)(D + (size_t)r * NN + c0);
    int4 cc0 = *(const int4*)(compP + c0 + (c0 >> 3));
    int4 cc1 = *(const int4*)(compP + c0 + 4 + (c0 >> 3));
    unsigned hh[8] = {dv.x & 0xffffu, dv.x >> 16, dv.y & 0xffffu, dv.y >> 16,
                      dv.z & 0xffffu, dv.z >> 16, dv.w & 0xffffu, dv.w >> 16};
    int cv[8] = {cc0.x, cc0.y, cc0.z, cc0.w, cc1.x, cc1.y, cc1.z, cc1.w};
    unsigned long long k = ~0ull;
    #pragma unroll
    for (int e = 0; e < 8; ++e) {
      if (cv[e] != cr) {
        int col = c0 + e;
        int lo = (r < col) ? r * NN + col : col * NN + r;
        unsigned long long key = ((unsigned long long)hh[e] << 48) | (unsigned)lo;
        k = u64min(k, key);
      }
    }
    k = wave_min_u64(k);
    if (lane == 63 && k != ~0ull) atomicMin(&b2[cr], k);
  }
}

// ---- deterministic inline hook2 (BARRIER-UNIFORM: call from ALL threads) -------
__device__ __forceinline__ void hook2_inline(const unsigned long long* b2m,
                                             const int* compG_m, int tid, bool valid,
                                             int wave, int lane, bool emit,
                                             int2* eo, int* ecnt,
                                             int* comp, int* hookA, int* parentA,
                                             unsigned long long* rootMask,
                                             int* denseOut, int* Cout) {
  unsigned long long b = ~0ull;
  if (valid) { comp[tid] = compG_m[tid]; b = b2m[tid]; }
  __syncthreads();
  int h = tid;
  if (valid && b != ~0ull) {
    int idx = (int)(unsigned)b & 0x3ffff;
    int er = idx >> 9, ec = idx & 511;
    int c1 = comp[er], c2 = comp[ec];
    h = (c1 == tid) ? c2 : c1;
  }
  if (valid) hookA[tid] = h;
  __syncthreads();
  if (valid) {
    bool active = (b != ~0ull);
    int p = h;
    bool mutual = active && (hookA[p] == tid);
    parentA[tid] = (!active) ? tid : ((mutual && tid < p) ? tid : p);
    if (emit && active && (!mutual || tid > p)) {
      int idx = (int)(unsigned)b & 0x3ffff;
      int e = atomicAdd(ecnt, 1);
      eo[e] = make_int2(idx >> 9, idx & 511);
    }
  }
  __syncthreads();
  int c = 0;
  bool isRoot = false;
  if (valid) {
    c = comp[tid];
    int pp = parentA[c];
    while (pp != c) { c = pp; pp = parentA[c]; }
    isRoot = (c == tid);
  }
  unsigned long long rm = __ballot(isRoot);
  if (valid && lane == 0) rootMask[wave] = rm;   // valid => wave < 8
  __syncthreads();
  int cw = c >> 6, cl = c & 63;
  int dense = 0, C = 0;
  #pragma unroll
  for (int w = 0; w < 8; ++w) {
    int pc = __popcll(rootMask[w]);
    C += pc;
    if (w < cw) dense += pc;
  }
  dense += __popcll(rootMask[cw] & (cl ? ((~0ull) >> (64 - cl)) : 0ull));
  *denseOut = dense;
  *Cout = C;
}

// -------- contraction (+inlined hook2): build Dc from bf16 D --------------------
__global__ __launch_bounds__(512) void contract_kernel(const unsigned short* __restrict__ Dreg,
                                                       const unsigned long long* __restrict__ best2,
                                                       const int* __restrict__ compG,
                                                       unsigned long long* __restrict__ DcG,
                                                       int2* __restrict__ eo_all,
                                                       int* __restrict__ ecntG, int m0) {
  int q = blockIdx.x, mL = blockIdx.y, m = m0 + mL;
  const unsigned short* D = Dreg + (size_t)mL * NN2;
  __shared__ unsigned long long Dc[128 * 128];
  __shared__ int comp[NN], hookA[NN], parentA[NN];
  __shared__ int c2P[NN + 64];
  __shared__ unsigned long long rootMask[8];
  __shared__ int ecnt;
  int tid = threadIdx.x;
  int wave = tid >> 6, lane = tid & 63;
  int c0 = lane * 8;
  for (int i = tid; i < 16384; i += 512) Dc[i] = ~0ull;
  if (tid == 0) ecnt = ecntG[m];
  __syncthreads();
  int dense, C;
  hook2_inline(best2 + (size_t)m * NN, compG + (size_t)m * NN, tid, true, wave, lane,
               q == 0, eo_all + (size_t)m * (NN - 1), &ecnt,
               comp, hookA, parentA, rootMask, &dense, &C);
  c2P[tid + (tid >> 3)] = dense;
  __syncthreads();
  if (q == 0 && tid == 0) ecntG[m] = ecnt;

  #pragma unroll
  for (int rr = 0; rr < 16; ++rr) {
    int r = q * 128 + wave * 16 + rr;
    int di = c2P[r + (r >> 3)];
    uint4 dv = *(const uint4*)(D + (size_t)r * NN + c0);
    int4 cc0 = *(const int4*)(c2P + c0 + (c0 >> 3));
    int4 cc1 = *(const int4*)(c2P + c0 + 4 + (c0 >> 3));
    unsigned hh[8] = {dv.x & 0xffffu, dv.x >> 16, dv.y & 0xffffu, dv.y >> 16,
                      dv.z & 0xffffu, dv.z >> 16, dv.w & 0xffffu, dv.w >> 16};
    int cv[8] = {cc0.x, cc0.y, cc0.z, cc0.w, cc1.x, cc1.y, cc1.z, cc1.w};
    #pragma unroll
    for (int e = 0; e < 8; ++e) {
      if (cv[e] != di) {
        int col = c0 + e;
        int lo = (r < col) ? r * NN + col : col * NN + r;
        unsigned long long key = ((unsigned long long)hh[e] << 48) | (unsigned)lo;
        amin64(&Dc[di * 128 + cv[e]], key);
      }
    }
  }
  __syncthreads();
  unsigned long long* dg = DcG + (size_t)mL * 16384;
  for (int i = tid; i < 16384; i += 512) {
    unsigned long long v = Dc[i];
    if (v != ~0ull) atomicMin(&dg[i], v);
  }
}

// -------- finish (+inlined hook2 labels): LDS phases + fused gather -------------
__global__ __launch_bounds__(1024) void finish_kernel(const unsigned short* __restrict__ Dreg,
                                                      const unsigned long long* __restrict__ DcG,
                                                      const unsigned long long* __restrict__ best2,
                                                      const int* __restrict__ compG,
                                                      int2* __restrict__ eo_all,
                                                      int* __restrict__ ecntG,
                                                      const unsigned* __restrict__ maxBits,
                                                      float* __restrict__ out, int m0) {
  int mL = blockIdx.x, m = m0 + mL;
  __shared__ unsigned long long Dc[16384];
  __shared__ int c2n[NN];
  __shared__ int comp[NN], hookA[NN], parentA[NN];
  __shared__ unsigned long long rootMask[8];
  __shared__ unsigned long long best[128];
  __shared__ int comp2[128], hook128[128], parent128[128];
  __shared__ float fred[16];
  __shared__ int ecnt, Csh;
  int tid = threadIdx.x;
  int wave = tid >> 6, lane = tid & 63;
  const unsigned long long* dg = DcG + (size_t)mL * 16384;
  for (int i = tid; i < 16384; i += 1024) Dc[i] = dg[i];
  if (tid < 128) comp2[tid] = tid;
  if (tid == 0) ecnt = ecntG[m];
  __syncthreads();
  {
    int dense, C;
    hook2_inline(best2 + (size_t)m * NN, compG + (size_t)m * NN, tid, tid < NN,
                 wave, lane, false, nullptr, nullptr,
                 comp, hookA, parentA, rootMask, &dense, &C);
    if (tid < NN) c2n[tid] = dense;
    if (tid == 0) Csh = C;
  }
  __syncthreads();
  int C = Csh;
  int2* eo = eo_all + (size_t)m * (NN - 1);

  for (int ph = 0; ph < 7; ++ph) {
    if (ecnt >= NN - 1) break;
    if (tid < 128) best[tid] = ~0ull;
    __syncthreads();
    for (int i = tid; i < C * 128; i += 1024) {
      unsigned long long key = Dc[i];
      if (key == ~0ull) continue;
      int a = i >> 7, bb = i & 127;
      int ca = comp2[a], cb = comp2[bb];
      if (ca != cb) amin64(&best[ca], key);
    }
    __syncthreads();
    if (tid < C) {
      unsigned long long b = best[tid];
      int h;
      if (b != ~0ull) {
        int pid = (int)(unsigned)b & 0x3ffff;
        int er = pid >> 9, ec = pid & 511;
        int c1 = comp2[c2n[er]], c2v = comp2[c2n[ec]];
        h = (c1 == tid) ? c2v : c1;
      } else h = tid;
      hook128[tid] = h;
    }
    __syncthreads();
    if (tid < C) {
      unsigned long long b = best[tid];
      bool active = (b != ~0ull);
      int p = hook128[tid];
      bool mutual = active && (hook128[p] == tid);
      parent128[tid] = (!active) ? tid : ((mutual && tid < p) ? tid : p);
      if (active && (!mutual || tid > p)) {
        int pid = (int)(unsigned)b & 0x3ffff;
        int e = atomicAdd(&ecnt, 1);
        eo[e] = make_int2(pid >> 9, pid & 511);
      }
    }
    __syncthreads();
    if (tid < C) {
      int c = comp2[tid], pp = parent128[c];
      while (pp != c) { c = pp; pp = parent128[c]; }
      comp2[tid] = c;
    }
    __syncthreads();
  }
  __syncthreads();

  // fused loss gather (bf16 D)
  int b = m >> 1;
  float mxX = fmaxf(__uint_as_float(maxBits[2 * b]), 1e-12f);
  float mxZ = fmaxf(__uint_as_float(maxBits[2 * b + 1]), 1e-12f);
  float rX = 1.0f / mxX, rZ = 1.0f / mxZ;
  const unsigned short* Dx = Dreg + (size_t)(mL & ~1) * NN2;
  const unsigned short* Dz = Dx + NN2;
  float acc = 0.f;
  if (tid < NN - 1) {
    int2 e = eo[tid];
    size_t off = (size_t)e.x * NN + e.y;
    float d = bf2f(Dx[off]) * rX - bf2f(Dz[off]) * rZ;
    acc = d * d;
  }
  #pragma unroll
  for (int o = 32; o > 0; o >>= 1) acc += __shfl_down(acc, o);
  if (lane == 0) fred[wave] = acc;
  __syncthreads();
  if (tid == 0) {
    float t = 0.f;
    #pragma unroll
    for (int i = 0; i < 16; ++i) t += fred[i];
    atomicAdd(out, t * (1.0f / NB));
  }
}

extern "C" void kernel_launch(void* const* d_in, const int* in_sizes, int n_in,
                              void* d_out, int out_size, void* d_ws, size_t ws_size,
                              hipStream_t stream) {
  const float* model = (const float*)d_in[0];
  const float* labels = (const float*)d_in[1];
  float* out = (float*)d_out;
  char* ws = (char*)d_ws;

  float*              sq      = (float*)(ws);                       // 131072
  unsigned*           maxBits = (unsigned*)(ws + 131072);           // -> 132096
  int2*               eo      = (int2*)(ws + 132096);               // -> 393728
  unsigned long long* best1   = (unsigned long long*)(ws + 393728); // -> 655872
  unsigned long long* best2   = (unsigned long long*)(ws + 655872); // -> 918016
  int*                compG   = (int*)(ws + 918016);                // -> 1049088
  int*                ecntG   = (int*)(ws + 1049088);               // -> 1049344
  size_t base = 1050624;

  // per batch (2 matrices): D bf16 1MB + Hi 1MB + Lo 1MB + Dc 256KB
  size_t perBatch = 2ull * (NN2 * 2 + 2ull * NN2 * 2 + 16384 * 8);
  size_t dcap = (ws_size > base) ? (ws_size - base) : 0;
  int cb = (int)(dcap / perBatch);
  if (cb > NB) cb = NB;
  if (cb < 1) cb = 1;
  int nmc = 2 * cb;

  unsigned short* Dreg = (unsigned short*)(ws + base);
  unsigned short* Hi = Dreg + (size_t)nmc * NN2;
  unsigned short* Lo = Hi + (size_t)nmc * NN2;
  unsigned long long* DcG = (unsigned long long*)(Lo + (size_t)nmc * NN2);

  hipMemsetAsync(d_out, 0, sizeof(float), stream);
  hipMemsetAsync(maxBits, 0, 64 * sizeof(unsigned), stream);

  for (int b0 = 0; b0 < NB; b0 += cb) {
    int nb = (NB - b0 < cb) ? (NB - b0) : cb;
    int nm = 2 * nb, m0 = 2 * b0;
    split_kernel<<<nm * 256, 256, 0, stream>>>(model, labels, Hi, Lo, sq,
                                               best1, best2, m0);
    gemm_dist<<<10 * nm, 256, 0, stream>>>(Hi, Lo, sq, Dreg, maxBits, best1, m0, nm);
    scan2_kernel<<<dim3(8, nm), 512, 0, stream>>>(Dreg, best1, compG, best2, DcG,
                                                  eo, ecntG, m0);
    contract_kernel<<<dim3(4, nm), 512, 0, stream>>>(Dreg, best2, compG, DcG,
                                                     eo, ecntG, m0);
    finish_kernel<<<nm, 1024, 0, stream>>>(Dreg, DcG, best2, compG, eo, ecntG,
                                           maxBits, out, m0);
  }
}

// Round 22
// 128.845 us; speedup vs baseline: 1.4538x; 1.0352x over previous
//
#include <hip/hip_runtime.h>
#include <math.h>

#define NN 512
#define NN2 (NN*NN)
#define NB 32
#define NM 64

typedef __attribute__((ext_vector_type(8))) short short8v;   // 8 bf16 (4 VGPR)
typedef __attribute__((ext_vector_type(4))) float f32x4;     // MFMA acc

typedef const unsigned int __attribute__((address_space(1)))* gas_ptr;
typedef unsigned int __attribute__((address_space(3)))* las_ptr;

__device__ __forceinline__ float sigm(float x) { return 1.0f / (1.0f + expf(-x)); }

__device__ __forceinline__ unsigned short f2bf(float x) {
  unsigned u = __float_as_uint(x);
  return (unsigned short)((u + 0x7fffu + ((u >> 16) & 1u)) >> 16);   // RNE
}
__device__ __forceinline__ float bf2f(unsigned short h) {
  return __uint_as_float(((unsigned)h) << 16);
}
__device__ __forceinline__ unsigned long long u64min(unsigned long long a,
                                                     unsigned long long b) {
  return (b < a) ? b : a;
}
__device__ __forceinline__ void amin64(unsigned long long* p, unsigned long long v) {
  unsigned long long old = *p;
  while (v < old) {
    unsigned long long assumed = old;
    old = atomicCAS(p, assumed, v);
    if (old == assumed) break;
  }
}
template <int CTRL>
__device__ __forceinline__ unsigned long long dpp_min_u64(unsigned long long x) {
  int xlo = (int)(unsigned)x, xhi = (int)(unsigned)(x >> 32);
  int ylo = __builtin_amdgcn_update_dpp(xlo, xlo, CTRL, 0xf, 0xf, false);
  int yhi = __builtin_amdgcn_update_dpp(xhi, xhi, CTRL, 0xf, 0xf, false);
  unsigned long long y = ((unsigned long long)(unsigned)yhi << 32) | (unsigned)ylo;
  return (y < x) ? y : x;
}
__device__ __forceinline__ unsigned long long wave_min_u64(unsigned long long k) {
  k = dpp_min_u64<0x111>(k); k = dpp_min_u64<0x112>(k);
  k = dpp_min_u64<0x114>(k); k = dpp_min_u64<0x118>(k);
  k = dpp_min_u64<0x142>(k); k = dpp_min_u64<0x143>(k);
  return k;
}
__device__ __forceinline__ unsigned long long grp16_min_u64(unsigned long long k) {
  k = dpp_min_u64<0x111>(k); k = dpp_min_u64<0x112>(k);
  k = dpp_min_u64<0x114>(k); k = dpp_min_u64<0x118>(k);
  return k;
}

// -------- sigmoid + bf16 hi/lo split + fused sq + best1/2 init ------------------
__global__ __launch_bounds__(256) void split_kernel(const float* __restrict__ model,
                                                    const float* __restrict__ labels,
                                                    unsigned short* __restrict__ Hi,
                                                    unsigned short* __restrict__ Lo,
                                                    float* __restrict__ sq,
                                                    unsigned long long* __restrict__ best1,
                                                    unsigned long long* __restrict__ best2,
                                                    int m0) {
  int b = blockIdx.x;
  int mL = b >> 8;
  int m = m0 + mL;
  int tid = threadIdx.x;
  size_t off = (size_t)(b & 255) * 1024 + tid * 4;
  const float* src = ((m & 1) ? labels + (size_t)(m >> 1) * NN2
                              : model + (size_t)(m >> 1) * NN2) + off;
  float4 v = *(const float4*)src;
  if (!(m & 1)) { v.x = sigm(v.x); v.y = sigm(v.y); v.z = sigm(v.z); v.w = sigm(v.w); }
  ushort4 h, l;
  h.x = f2bf(v.x); l.x = f2bf(v.x - bf2f(h.x));
  h.y = f2bf(v.y); l.y = f2bf(v.y - bf2f(h.y));
  h.z = f2bf(v.z); l.z = f2bf(v.z - bf2f(h.z));
  h.w = f2bf(v.w); l.w = f2bf(v.w - bf2f(h.w));
  *(ushort4*)(Hi + (size_t)mL * NN2 + off) = h;
  *(ushort4*)(Lo + (size_t)mL * NN2 + off) = l;
  if (tid == 0) {
    int bi = (b & 255) * 2;
    best1[(size_t)m * NN + bi]     = ~0ull;
    best1[(size_t)m * NN + bi + 1] = ~0ull;
    best2[(size_t)m * NN + bi]     = ~0ull;
    best2[(size_t)m * NN + bi + 1] = ~0ull;
  }
  float s = v.x * v.x + v.y * v.y + v.z * v.z + v.w * v.w;
  #pragma unroll
  for (int o = 32; o > 0; o >>= 1) s += __shfl_down(s, o);
  __shared__ float red[4];
  if ((tid & 63) == 0) red[tid >> 6] = s;
  __syncthreads();
  if (tid == 0) {
    int row0 = (b & 255) * 2;
    sq[(size_t)m * NN + row0]     = red[0] + red[1];
    sq[(size_t)m * NN + row0 + 1] = red[2] + red[3];
  }
}

// ------- distance matrix: 1-pass off-diag (hh, mirror-symmetric),
//         3-pass diag; bf16 D; single-conversion epilogue -----------------------
__global__ __launch_bounds__(256, 3) void gemm_dist(const unsigned short* __restrict__ Hi,
                                                    const unsigned short* __restrict__ Lo,
                                                    const float* __restrict__ sq,
                                                    unsigned short* __restrict__ Dreg,
                                                    unsigned* __restrict__ maxBits,
                                                    unsigned long long* __restrict__ best1,
                                                    int m0, int nm) {
  __shared__ unsigned short P[4][4096];   // Ah, Al, Bh, (Bl unused) (8 KB each)
  int id = blockIdx.x;
  int p, mL;
  if ((nm & 7) == 0) {
    int x = id & 7, t = id >> 3;
    p = t % 10;
    mL = x + 8 * (t / 10);
  } else {
    p = id % 10;
    mL = id / 10;
  }
  int by = (p >= 4) + (p >= 7) + (p >= 9);
  int bx = p - ((by * (7 - by)) >> 1);
  bool diag = (by == bx);
  int m = m0 + mL;
  const unsigned short* Hm = Hi + (size_t)mL * NN2;
  const unsigned short* Lm = Lo + (size_t)mL * NN2;

  int tid = threadIdx.x;
  int wid = tid >> 6, lane = tid & 63;
  int wy = wid >> 1, wx = wid & 1;
  int lr = lane & 15, lk = lane >> 4;

  const unsigned short* wsrcM = (wid & 1) ? Lm : Hm;
  int wrow0 = (wid < 2) ? by * 128 : bx * 128;
  // diag: stage Ah,Al (waves 0,1). non-diag: stage Ah (wave0), Bh (wave2) only.
  bool stage = diag ? (wid < 2) : (wid == 0 || wid == 2);
  int srow = lane >> 2;
  int schunk = (lane & 3) ^ ((lane >> 3) & 3);
  const unsigned short* gsrc = wsrcM + (size_t)(wrow0 + srow) * NN + schunk * 8;
  unsigned short* ldst = &P[wid & 3][0];

  f32x4 acc[4][4];
  #pragma unroll
  for (int i = 0; i < 4; ++i)
    #pragma unroll
    for (int j = 0; j < 4; ++j) acc[i][j] = (f32x4){0.f, 0.f, 0.f, 0.f};

  const unsigned short* bAh = &P[0][0];
  const unsigned short* bAl = &P[1][0];
  const unsigned short* bBh = diag ? &P[0][0] : &P[2][0];
  int sw = (lr >> 1) & 3;
  int rao = (wy * 64 + lr) * 32 + (lk ^ sw) * 8;
  int rbo = (wx * 64 + lr) * 32 + (lk ^ sw) * 8;

  for (int s = 0; s < 16; ++s) {
    int k0 = s * 32;
    if (stage) {
      #pragma unroll
      for (int i = 0; i < 8; ++i)
        __builtin_amdgcn_global_load_lds(
            (gas_ptr)(const void*)(gsrc + k0 + (size_t)i * 16 * NN),
            (las_ptr)(void*)(ldst + i * 512), 16, 0, 0);
    }
    __syncthreads();

    short8v fa[4], fb[4], fb2[4];
    #pragma unroll
    for (int i = 0; i < 4; ++i) {
      fa[i] = *(const short8v*)(bAh + rao + i * 512);   // Ah
      fb[i] = *(const short8v*)(bBh + rbo + i * 512);   // Bh (diag: Ah)
    }
    #pragma unroll
    for (int mi = 0; mi < 4; ++mi)
      #pragma unroll
      for (int ni = 0; ni < 4; ++ni)
        acc[mi][ni] = __builtin_amdgcn_mfma_f32_16x16x32_bf16(fa[mi], fb[ni], acc[mi][ni], 0, 0, 0);
    if (diag) {                      // hl + lh passes only for diagonal tiles
      #pragma unroll
      for (int i = 0; i < 4; ++i)
        fb2[i] = *(const short8v*)(bAl + rbo + i * 512);  // Al as B
      #pragma unroll
      for (int mi = 0; mi < 4; ++mi)
        #pragma unroll
        for (int ni = 0; ni < 4; ++ni)
          acc[mi][ni] = __builtin_amdgcn_mfma_f32_16x16x32_bf16(fa[mi], fb2[ni], acc[mi][ni], 0, 0, 0);
      #pragma unroll
      for (int i = 0; i < 4; ++i)
        fa[i] = *(const short8v*)(bAl + rao + i * 512);   // Al as A
      #pragma unroll
      for (int mi = 0; mi < 4; ++mi)
        #pragma unroll
        for (int ni = 0; ni < 4; ++ni)
          acc[mi][ni] = __builtin_amdgcn_mfma_f32_16x16x32_bf16(fa[mi], fb[ni], acc[mi][ni], 0, 0, 0);
    }
    __syncthreads();
  }

  const float* sqm = sq + (size_t)m * NN;
  unsigned short* Dm = Dreg + (size_t)mL * NN2;
  int gr0 = by * 128 + wy * 64;
  int gc0 = bx * 128 + wx * 64;
  unsigned hmax = 0;
  unsigned long long* b1 = best1 + (size_t)m * NN;
  unsigned long long ck[4];
  #pragma unroll
  for (int i = 0; i < 4; ++i) ck[i] = ~0ull;
  unsigned short us[4][4][4];

  #pragma unroll
  for (int mi = 0; mi < 4; ++mi) {
    int rb = gr0 + mi * 16 + lk * 4;
    float sqi0 = sqm[rb + 0], sqi1 = sqm[rb + 1], sqi2 = sqm[rb + 2], sqi3 = sqm[rb + 3];
    unsigned long long rk[4];
    #pragma unroll
    for (int j = 0; j < 4; ++j) rk[j] = ~0ull;
    #pragma unroll
    for (int ni = 0; ni < 4; ++ni) {
      int col = gc0 + ni * 16 + lr;
      float sqj = sqm[col];
      f32x4 a = acc[mi][ni];
      unsigned short h0 = f2bf(sqrtf(fmaxf(sqi0 + sqj - 2.f * a[0], 0.f)));
      unsigned short h1 = f2bf(sqrtf(fmaxf(sqi1 + sqj - 2.f * a[1], 0.f)));
      unsigned short h2 = f2bf(sqrtf(fmaxf(sqi2 + sqj - 2.f * a[2], 0.f)));
      unsigned short h3 = f2bf(sqrtf(fmaxf(sqi3 + sqj - 2.f * a[3], 0.f)));
      us[mi][ni][0] = h0; us[mi][ni][1] = h1;
      us[mi][ni][2] = h2; us[mi][ni][3] = h3;
      unsigned hm01 = (h0 > h1) ? h0 : h1;
      unsigned hm23 = (h2 > h3) ? h2 : h3;
      unsigned hm = (hm01 > hm23) ? hm01 : hm23;
      hmax = (hm > hmax) ? hm : hmax;
      unsigned short hh[4] = {h0, h1, h2, h3};
      #pragma unroll
      for (int rg = 0; rg < 4; ++rg) {
        int row = rb + rg;
        if (!diag || col != row) {
          unsigned lo = (row < col) ? (unsigned)(row * NN + col)
                                    : (unsigned)(col * NN + row);
          unsigned long long key = ((unsigned long long)hh[rg] << 48) | lo;
          rk[rg] = u64min(rk[rg], key);
          ck[ni] = u64min(ck[ni], key);
        }
      }
    }
    #pragma unroll
    for (int rg = 0; rg < 4; ++rg) {
      unsigned long long k = grp16_min_u64(rk[rg]);
      if (lr == 15) atomicMin(&b1[rb + rg], k);
    }
  }
  if (!diag) {
    #pragma unroll
    for (int ni = 0; ni < 4; ++ni) {
      unsigned long long k = ck[ni];
      k = u64min(k, __shfl_xor(k, 16));
      k = u64min(k, __shfl_xor(k, 32));
      if (lk == 0) atomicMin(&b1[gc0 + ni * 16 + lr], k);
    }
  }

  __syncthreads();                                   // staging LDS dead
  unsigned short* W = &P[0][0] + wid * 1216;         // 16 x 76 ushort per-wave
  int rlo = lane >> 4, cq = lane & 15;
  #pragma unroll
  for (int mi = 0; mi < 4; ++mi) {
    #pragma unroll
    for (int ni = 0; ni < 4; ++ni)
      #pragma unroll
      for (int j = 0; j < 4; ++j)
        W[(lk * 4 + j) * 76 + ni * 16 + lr] = us[mi][ni][j];
    #pragma unroll
    for (int g = 0; g < 4; ++g) {
      int r16 = g * 4 + rlo;
      ushort4 t = *(const ushort4*)&W[r16 * 76 + cq * 4];
      *(ushort4*)(Dm + (size_t)(gr0 + mi * 16 + r16) * NN + gc0 + cq * 4) = t;
    }
  }
  if (!diag) {
    #pragma unroll
    for (int ni = 0; ni < 4; ++ni) {
      #pragma unroll
      for (int mi = 0; mi < 4; ++mi)
        *(ushort4*)&W[lr * 76 + mi * 16 + lk * 4] =
            make_ushort4(us[mi][ni][0], us[mi][ni][1], us[mi][ni][2], us[mi][ni][3]);
      #pragma unroll
      for (int g = 0; g < 4; ++g) {
        int r16 = g * 4 + rlo;
        ushort4 t = *(const ushort4*)&W[r16 * 76 + cq * 4];
        *(ushort4*)(Dm + (size_t)(gc0 + ni * 16 + r16) * NN + gr0 + cq * 4) = t;
      }
    }
  }

  #pragma unroll
  for (int off = 32; off > 0; off >>= 1) {
    unsigned o = (unsigned)__shfl_down((int)hmax, off);
    hmax = (o > hmax) ? o : hmax;
  }
  if (lane == 0) atomicMax(&maxBits[m], hmax << 16);
}

// -------- phase-2 scan + inlined phase-1 hook + DcG init (unchanged) ------------
__global__ __launch_bounds__(512) void scan2_kernel(const unsigned short* __restrict__ Dreg,
                                                    const unsigned long long* __restrict__ best1,
                                                    int* __restrict__ compG,
                                                    unsigned long long* __restrict__ best2,
                                                    unsigned long long* __restrict__ DcG,
                                                    int2* __restrict__ eo_all,
                                                    int* __restrict__ ecntG, int m0) {
  int sblk = blockIdx.x, mL = blockIdx.y, m = m0 + mL;
  const unsigned short* D = Dreg + (size_t)mL * NN2;
  __shared__ int compP[NN + 64];
  __shared__ int hook[NN], parent[NN];
  __shared__ int ecnt;
  int tid = threadIdx.x;
  int wave = tid >> 6, lane = tid & 63;
  int c0 = lane * 8;

  unsigned long long* dginit = DcG + (size_t)mL * 16384 + sblk * 2048;
  #pragma unroll
  for (int i = 0; i < 4; ++i) dginit[tid + i * 512] = ~0ull;

  if (tid == 0) ecnt = 0;
  unsigned long long b = best1[(size_t)m * NN + tid];
  int h;
  if (b != ~0ull) {
    int idx = (int)(unsigned)b & 0x3ffff;
    int er = idx >> 9, ec = idx & 511;
    h = (er == tid) ? ec : er;
  } else h = tid;
  hook[tid] = h;
  __syncthreads();
  bool active = (b != ~0ull);
  int p = h;
  bool mutual = active && (hook[p] == tid);
  parent[tid] = (!active) ? tid : ((mutual && tid < p) ? tid : p);
  if (sblk == 0 && active && (!mutual || tid > p)) {
    int idx = (int)(unsigned)b & 0x3ffff;
    int e = atomicAdd(&ecnt, 1);
    eo_all[(size_t)m * (NN - 1) + e] = make_int2(idx >> 9, idx & 511);
  }
  __syncthreads();
  int c = tid, pp = parent[c];
  while (pp != c) { c = pp; pp = parent[c]; }
  compP[tid + (tid >> 3)] = c;
  if (sblk == 0) {
    compG[(size_t)m * NN + tid] = c;
    if (tid == 0) ecntG[m] = ecnt;
  }
  __syncthreads();

  unsigned long long* b2 = best2 + (size_t)m * NN;
  #pragma unroll
  for (int rr = 0; rr < 8; ++rr) {
    int r = sblk * 64 + wave * 8 + rr;
    int cr = compP[r + (r >> 3)];
    uint4 dv = *(const uint4*)(D + (size_t)r * NN + c0);
    int4 cc0 = *(const int4*)(compP + c0 + (c0 >> 3));
    int4 cc1 = *(const int4*)(compP + c0 + 4 + (c0 >> 3));
    unsigned hh[8] = {dv.x & 0xffffu, dv.x >> 16, dv.y & 0xffffu, dv.y >> 16,
                      dv.z & 0xffffu, dv.z >> 16, dv.w & 0xffffu, dv.w >> 16};
    int cv[8] = {cc0.x, cc0.y, cc0.z, cc0.w, cc1.x, cc1.y, cc1.z, cc1.w};
    unsigned long long k = ~0ull;
    #pragma unroll
    for (int e = 0; e < 8; ++e) {
      if (cv[e] != cr) {
        int col = c0 + e;
        int lo = (r < col) ? r * NN + col : col * NN + r;
        unsigned long long key = ((unsigned long long)hh[e] << 48) | (unsigned)lo;
        k = u64min(k, key);
      }
    }
    k = wave_min_u64(k);
    if (lane == 63 && k != ~0ull) atomicMin(&b2[cr], k);
  }
}

// ---- deterministic inline hook2 (BARRIER-UNIFORM: call from ALL threads) -------
__device__ __forceinline__ void hook2_inline(const unsigned long long* b2m,
                                             const int* compG_m, int tid, bool valid,
                                             int wave, int lane, bool emit,
                                             int2* eo, int* ecnt,
                                             int* comp, int* hookA, int* parentA,
                                             unsigned long long* rootMask,
                                             int* denseOut, int* Cout) {
  unsigned long long b = ~0ull;
  if (valid) { comp[tid] = compG_m[tid]; b = b2m[tid]; }
  __syncthreads();
  int h = tid;
  if (valid && b != ~0ull) {
    int idx = (int)(unsigned)b & 0x3ffff;
    int er = idx >> 9, ec = idx & 511;
    int c1 = comp[er], c2 = comp[ec];
    h = (c1 == tid) ? c2 : c1;
  }
  if (valid) hookA[tid] = h;
  __syncthreads();
  if (valid) {
    bool active = (b != ~0ull);
    int p = h;
    bool mutual = active && (hookA[p] == tid);
    parentA[tid] = (!active) ? tid : ((mutual && tid < p) ? tid : p);
    if (emit && active && (!mutual || tid > p)) {
      int idx = (int)(unsigned)b & 0x3ffff;
      int e = atomicAdd(ecnt, 1);
      eo[e] = make_int2(idx >> 9, idx & 511);
    }
  }
  __syncthreads();
  int c = 0;
  bool isRoot = false;
  if (valid) {
    c = comp[tid];
    int pp = parentA[c];
    while (pp != c) { c = pp; pp = parentA[c]; }
    isRoot = (c == tid);
  }
  unsigned long long rm = __ballot(isRoot);
  if (valid && lane == 0) rootMask[wave] = rm;   // valid => wave < 8
  __syncthreads();
  int cw = c >> 6, cl = c & 63;
  int dense = 0, C = 0;
  #pragma unroll
  for (int w = 0; w < 8; ++w) {
    int pc = __popcll(rootMask[w]);
    C += pc;
    if (w < cw) dense += pc;
  }
  dense += __popcll(rootMask[cw] & (cl ? ((~0ull) >> (64 - cl)) : 0ull));
  *denseOut = dense;
  *Cout = C;
}

// -------- contraction (+inlined hook2): build Dc from bf16 D --------------------
__global__ __launch_bounds__(512) void contract_kernel(const unsigned short* __restrict__ Dreg,
                                                       const unsigned long long* __restrict__ best2,
                                                       const int* __restrict__ compG,
                                                       unsigned long long* __restrict__ DcG,
                                                       int2* __restrict__ eo_all,
                                                       int* __restrict__ ecntG, int m0) {
  int q = blockIdx.x, mL = blockIdx.y, m = m0 + mL;
  const unsigned short* D = Dreg + (size_t)mL * NN2;
  __shared__ unsigned long long Dc[128 * 128];
  __shared__ int comp[NN], hookA[NN], parentA[NN];
  __shared__ int c2P[NN + 64];
  __shared__ unsigned long long rootMask[8];
  __shared__ int ecnt;
  int tid = threadIdx.x;
  int wave = tid >> 6, lane = tid & 63;
  int c0 = lane * 8;
  for (int i = tid; i < 16384; i += 512) Dc[i] = ~0ull;
  if (tid == 0) ecnt = ecntG[m];
  __syncthreads();
  int dense, C;
  hook2_inline(best2 + (size_t)m * NN, compG + (size_t)m * NN, tid, true, wave, lane,
               q == 0, eo_all + (size_t)m * (NN - 1), &ecnt,
               comp, hookA, parentA, rootMask, &dense, &C);
  c2P[tid + (tid >> 3)] = dense;
  __syncthreads();
  if (q == 0 && tid == 0) ecntG[m] = ecnt;

  #pragma unroll
  for (int rr = 0; rr < 16; ++rr) {
    int r = q * 128 + wave * 16 + rr;
    int di = c2P[r + (r >> 3)];
    uint4 dv = *(const uint4*)(D + (size_t)r * NN + c0);
    int4 cc0 = *(const int4*)(c2P + c0 + (c0 >> 3));
    int4 cc1 = *(const int4*)(c2P + c0 + 4 + (c0 >> 3));
    unsigned hh[8] = {dv.x & 0xffffu, dv.x >> 16, dv.y & 0xffffu, dv.y >> 16,
                      dv.z & 0xffffu, dv.z >> 16, dv.w & 0xffffu, dv.w >> 16};
    int cv[8] = {cc0.x, cc0.y, cc0.z, cc0.w, cc1.x, cc1.y, cc1.z, cc1.w};
    #pragma unroll
    for (int e = 0; e < 8; ++e) {
      if (cv[e] != di) {
        int col = c0 + e;
        int lo = (r < col) ? r * NN + col : col * NN + r;
        unsigned long long key = ((unsigned long long)hh[e] << 48) | (unsigned)lo;
        amin64(&Dc[di * 128 + cv[e]], key);
      }
    }
  }
  __syncthreads();
  unsigned long long* dg = DcG + (size_t)mL * 16384;
  for (int i = tid; i < 16384; i += 512) {
    unsigned long long v = Dc[i];
    if (v != ~0ull) atomicMin(&dg[i], v);
  }
}

// -------- finish (+inlined hook2 labels): LDS phases + fused gather -------------
__global__ __launch_bounds__(1024) void finish_kernel(const unsigned short* __restrict__ Dreg,
                                                      const unsigned long long* __restrict__ DcG,
                                                      const unsigned long long* __restrict__ best2,
                                                      const int* __restrict__ compG,
                                                      int2* __restrict__ eo_all,
                                                      int* __restrict__ ecntG,
                                                      const unsigned* __restrict__ maxBits,
                                                      float* __restrict__ out, int m0) {
  int mL = blockIdx.x, m = m0 + mL;
  __shared__ unsigned long long Dc[16384];
  __shared__ int c2n[NN];
  __shared__ int comp[NN], hookA[NN], parentA[NN];
  __shared__ unsigned long long rootMask[8];
  __shared__ unsigned long long best[128];
  __shared__ int comp2[128], hook128[128], parent128[128];
  __shared__ float fred[16];
  __shared__ int ecnt, Csh;
  int tid = threadIdx.x;
  int wave = tid >> 6, lane = tid & 63;
  const unsigned long long* dg = DcG + (size_t)mL * 16384;
  for (int i = tid; i < 16384; i += 1024) Dc[i] = dg[i];
  if (tid < 128) comp2[tid] = tid;
  if (tid == 0) ecnt = ecntG[m];
  __syncthreads();
  {
    int dense, C;
    hook2_inline(best2 + (size_t)m * NN, compG + (size_t)m * NN, tid, tid < NN,
                 wave, lane, false, nullptr, nullptr,
                 comp, hookA, parentA, rootMask, &dense, &C);
    if (tid < NN) c2n[tid] = dense;
    if (tid == 0) Csh = C;
  }
  __syncthreads();
  int C = Csh;
  int2* eo = eo_all + (size_t)m * (NN - 1);

  for (int ph = 0; ph < 7; ++ph) {
    if (ecnt >= NN - 1) break;
    if (tid < 128) best[tid] = ~0ull;
    __syncthreads();
    for (int i = tid; i < C * 128; i += 1024) {
      unsigned long long key = Dc[i];
      if (key == ~0ull) continue;
      int a = i >> 7, bb = i & 127;
      int ca = comp2[a], cb = comp2[bb];
      if (ca != cb) amin64(&best[ca], key);
    }
    __syncthreads();
    if (tid < C) {
      unsigned long long b = best[tid];
      int h;
      if (b != ~0ull) {
        int pid = (int)(unsigned)b & 0x3ffff;
        int er = pid >> 9, ec = pid & 511;
        int c1 = comp2[c2n[er]], c2v = comp2[c2n[ec]];
        h = (c1 == tid) ? c2v : c1;
      } else h = tid;
      hook128[tid] = h;
    }
    __syncthreads();
    if (tid < C) {
      unsigned long long b = best[tid];
      bool active = (b != ~0ull);
      int p = hook128[tid];
      bool mutual = active && (hook128[p] == tid);
      parent128[tid] = (!active) ? tid : ((mutual && tid < p) ? tid : p);
      if (active && (!mutual || tid > p)) {
        int pid = (int)(unsigned)b & 0x3ffff;
        int e = atomicAdd(&ecnt, 1);
        eo[e] = make_int2(pid >> 9, pid & 511);
      }
    }
    __syncthreads();
    if (tid < C) {
      int c = comp2[tid], pp = parent128[c];
      while (pp != c) { c = pp; pp = parent128[c]; }
      comp2[tid] = c;
    }
    __syncthreads();
  }
  __syncthreads();

  // fused loss gather (bf16 D)
  int b = m >> 1;
  float mxX = fmaxf(__uint_as_float(maxBits[2 * b]), 1e-12f);
  float mxZ = fmaxf(__uint_as_float(maxBits[2 * b + 1]), 1e-12f);
  float rX = 1.0f / mxX, rZ = 1.0f / mxZ;
  const unsigned short* Dx = Dreg + (size_t)(mL & ~1) * NN2;
  const unsigned short* Dz = Dx + NN2;
  float acc = 0.f;
  if (tid < NN - 1) {
    int2 e = eo[tid];
    size_t off = (size_t)e.x * NN + e.y;
    float d = bf2f(Dx[off]) * rX - bf2f(Dz[off]) * rZ;
    acc = d * d;
  }
  #pragma unroll
  for (int o = 32; o > 0; o >>= 1) acc += __shfl_down(acc, o);
  if (lane == 0) fred[wave] = acc;
  __syncthreads();
  if (tid == 0) {
    float t = 0.f;
    #pragma unroll
    for (int i = 0; i < 16; ++i) t += fred[i];
    atomicAdd(out, t * (1.0f / NB));
  }
}

extern "C" void kernel_launch(void* const* d_in, const int* in_sizes, int n_in,
                              void* d_out, int out_size, void* d_ws, size_t ws_size,
                              hipStream_t stream) {
  const float* model = (const float*)d_in[0];
  const float* labels = (const float*)d_in[1];
  float* out = (float*)d_out;
  char* ws = (char*)d_ws;

  float*              sq      = (float*)(ws);                       // 131072
  unsigned*           maxBits = (unsigned*)(ws + 131072);           // -> 132096
  int2*               eo      = (int2*)(ws + 132096);               // -> 393728
  unsigned long long* best1   = (unsigned long long*)(ws + 393728); // -> 655872
  unsigned long long* best2   = (unsigned long long*)(ws + 655872); // -> 918016
  int*                compG   = (int*)(ws + 918016);                // -> 1049088
  int*                ecntG   = (int*)(ws + 1049088);               // -> 1049344
  size_t base = 1050624;

  // per batch (2 matrices): D bf16 1MB + Hi 1MB + Lo 1MB + Dc 256KB
  size_t perBatch = 2ull * (NN2 * 2 + 2ull * NN2 * 2 + 16384 * 8);
  size_t dcap = (ws_size > base) ? (ws_size - base) : 0;
  int cb = (int)(dcap / perBatch);
  if (cb > NB) cb = NB;
  if (cb < 1) cb = 1;
  int nmc = 2 * cb;

  unsigned short* Dreg = (unsigned short*)(ws + base);
  unsigned short* Hi = Dreg + (size_t)nmc * NN2;
  unsigned short* Lo = Hi + (size_t)nmc * NN2;
  unsigned long long* DcG = (unsigned long long*)(Lo + (size_t)nmc * NN2);

  hipMemsetAsync(d_out, 0, sizeof(float), stream);
  hipMemsetAsync(maxBits, 0, 64 * sizeof(unsigned), stream);

  for (int b0 = 0; b0 < NB; b0 += cb) {
    int nb = (NB - b0 < cb) ? (NB - b0) : cb;
    int nm = 2 * nb, m0 = 2 * b0;
    split_kernel<<<nm * 256, 256, 0, stream>>>(model, labels, Hi, Lo, sq,
                                               best1, best2, m0);
    gemm_dist<<<10 * nm, 256, 0, stream>>>(Hi, Lo, sq, Dreg, maxBits, best1, m0, nm);
    scan2_kernel<<<dim3(8, nm), 512, 0, stream>>>(Dreg, best1, compG, best2, DcG,
                                                  eo, ecntG, m0);
    contract_kernel<<<dim3(4, nm), 512, 0, stream>>>(Dreg, best2, compG, DcG,
                                                     eo, ecntG, m0);
    finish_kernel<<<nm, 1024, 0, stream>>>(Dreg, DcG, best2, compG, eo, ecntG,
                                           maxBits, out, m0);
  }
}

// Round 23
// 123.967 us; speedup vs baseline: 1.5110x; 1.0394x over previous
//
#include <hip/hip_runtime.h>
#include <math.h>

#define NN 512
#define NN2 (NN*NN)
#define NB 32
#define NM 64

typedef __attribute__((ext_vector_type(8))) short short8v;   // 8 bf16 (4 VGPR)
typedef __attribute__((ext_vector_type(4))) float f32x4;     // MFMA acc

typedef const unsigned int __attribute__((address_space(1)))* gas_ptr;
typedef unsigned int __attribute__((address_space(3)))* las_ptr;

__device__ __forceinline__ float sigm(float x) { return 1.0f / (1.0f + expf(-x)); }

__device__ __forceinline__ unsigned short f2bf(float x) {
  unsigned u = __float_as_uint(x);
  return (unsigned short)((u + 0x7fffu + ((u >> 16) & 1u)) >> 16);   // RNE
}
__device__ __forceinline__ float bf2f(unsigned short h) {
  return __uint_as_float(((unsigned)h) << 16);
}
__device__ __forceinline__ unsigned long long u64min(unsigned long long a,
                                                     unsigned long long b) {
  return (b < a) ? b : a;
}
__device__ __forceinline__ void amin64(unsigned long long* p, unsigned long long v) {
  unsigned long long old = *p;
  while (v < old) {
    unsigned long long assumed = old;
    old = atomicCAS(p, assumed, v);
    if (old == assumed) break;
  }
}
template <int CTRL>
__device__ __forceinline__ unsigned long long dpp_min_u64(unsigned long long x) {
  int xlo = (int)(unsigned)x, xhi = (int)(unsigned)(x >> 32);
  int ylo = __builtin_amdgcn_update_dpp(xlo, xlo, CTRL, 0xf, 0xf, false);
  int yhi = __builtin_amdgcn_update_dpp(xhi, xhi, CTRL, 0xf, 0xf, false);
  unsigned long long y = ((unsigned long long)(unsigned)yhi << 32) | (unsigned)ylo;
  return (y < x) ? y : x;
}
__device__ __forceinline__ unsigned long long wave_min_u64(unsigned long long k) {
  k = dpp_min_u64<0x111>(k); k = dpp_min_u64<0x112>(k);
  k = dpp_min_u64<0x114>(k); k = dpp_min_u64<0x118>(k);
  k = dpp_min_u64<0x142>(k); k = dpp_min_u64<0x143>(k);
  return k;
}
__device__ __forceinline__ unsigned long long grp16_min_u64(unsigned long long k) {
  k = dpp_min_u64<0x111>(k); k = dpp_min_u64<0x112>(k);
  k = dpp_min_u64<0x114>(k); k = dpp_min_u64<0x118>(k);
  return k;
}

// -------- sigmoid + bf16 quantize + fused sq + best1/2 init ---------------------
__global__ __launch_bounds__(256) void split_kernel(const float* __restrict__ model,
                                                    const float* __restrict__ labels,
                                                    unsigned short* __restrict__ Hi,
                                                    float* __restrict__ sq,
                                                    unsigned long long* __restrict__ best1,
                                                    unsigned long long* __restrict__ best2,
                                                    int m0) {
  int b = blockIdx.x;
  int mL = b >> 8;
  int m = m0 + mL;
  int tid = threadIdx.x;
  size_t off = (size_t)(b & 255) * 1024 + tid * 4;
  const float* src = ((m & 1) ? labels + (size_t)(m >> 1) * NN2
                              : model + (size_t)(m >> 1) * NN2) + off;
  float4 v = *(const float4*)src;
  if (!(m & 1)) { v.x = sigm(v.x); v.y = sigm(v.y); v.z = sigm(v.z); v.w = sigm(v.w); }
  ushort4 h;
  h.x = f2bf(v.x); h.y = f2bf(v.y); h.z = f2bf(v.z); h.w = f2bf(v.w);
  *(ushort4*)(Hi + (size_t)mL * NN2 + off) = h;
  if (tid == 0) {
    int bi = (b & 255) * 2;
    best1[(size_t)m * NN + bi]     = ~0ull;
    best1[(size_t)m * NN + bi + 1] = ~0ull;
    best2[(size_t)m * NN + bi]     = ~0ull;
    best2[(size_t)m * NN + bi + 1] = ~0ull;
  }
  float s = v.x * v.x + v.y * v.y + v.z * v.z + v.w * v.w;
  #pragma unroll
  for (int o = 32; o > 0; o >>= 1) s += __shfl_down(s, o);
  __shared__ float red[4];
  if ((tid & 63) == 0) red[tid >> 6] = s;
  __syncthreads();
  if (tid == 0) {
    int row0 = (b & 255) * 2;
    sq[(size_t)m * NN + row0]     = red[0] + red[1];
    sq[(size_t)m * NN + row0 + 1] = red[2] + red[3];
  }
}

// ------- distance matrix: hh-only (symmetric everywhere); bf16 D ----------------
__global__ __launch_bounds__(256, 3) void gemm_dist(const unsigned short* __restrict__ Hi,
                                                    const float* __restrict__ sq,
                                                    unsigned short* __restrict__ Dreg,
                                                    unsigned* __restrict__ maxBits,
                                                    unsigned long long* __restrict__ best1,
                                                    int m0, int nm) {
  __shared__ unsigned short P[4][4096];   // Ah (0), Bh (2); 1,3 used as scratch only
  int id = blockIdx.x;
  int p, mL;
  if ((nm & 7) == 0) {
    int x = id & 7, t = id >> 3;
    p = t % 10;
    mL = x + 8 * (t / 10);
  } else {
    p = id % 10;
    mL = id / 10;
  }
  int by = (p >= 4) + (p >= 7) + (p >= 9);
  int bx = p - ((by * (7 - by)) >> 1);
  bool diag = (by == bx);
  int m = m0 + mL;
  const unsigned short* Hm = Hi + (size_t)mL * NN2;

  int tid = threadIdx.x;
  int wid = tid >> 6, lane = tid & 63;
  int wy = wid >> 1, wx = wid & 1;
  int lr = lane & 15, lk = lane >> 4;

  int wrow0 = (wid < 2) ? by * 128 : bx * 128;
  // stage Ah (wave 0); non-diag also Bh (wave 2)
  bool stage = (wid == 0) || (!diag && wid == 2);
  int srow = lane >> 2;
  int schunk = (lane & 3) ^ ((lane >> 3) & 3);
  const unsigned short* gsrc = Hm + (size_t)(wrow0 + srow) * NN + schunk * 8;
  unsigned short* ldst = &P[wid & 3][0];

  f32x4 acc[4][4];
  #pragma unroll
  for (int i = 0; i < 4; ++i)
    #pragma unroll
    for (int j = 0; j < 4; ++j) acc[i][j] = (f32x4){0.f, 0.f, 0.f, 0.f};

  const unsigned short* bAh = &P[0][0];
  const unsigned short* bBh = diag ? &P[0][0] : &P[2][0];
  int sw = (lr >> 1) & 3;
  int rao = (wy * 64 + lr) * 32 + (lk ^ sw) * 8;
  int rbo = (wx * 64 + lr) * 32 + (lk ^ sw) * 8;

  for (int s = 0; s < 16; ++s) {
    int k0 = s * 32;
    if (stage) {
      #pragma unroll
      for (int i = 0; i < 8; ++i)
        __builtin_amdgcn_global_load_lds(
            (gas_ptr)(const void*)(gsrc + k0 + (size_t)i * 16 * NN),
            (las_ptr)(void*)(ldst + i * 512), 16, 0, 0);
    }
    __syncthreads();

    short8v fa[4], fb[4];
    #pragma unroll
    for (int i = 0; i < 4; ++i) {
      fa[i] = *(const short8v*)(bAh + rao + i * 512);   // Ah
      fb[i] = *(const short8v*)(bBh + rbo + i * 512);   // Bh (diag: Ah)
    }
    #pragma unroll
    for (int mi = 0; mi < 4; ++mi)
      #pragma unroll
      for (int ni = 0; ni < 4; ++ni)
        acc[mi][ni] = __builtin_amdgcn_mfma_f32_16x16x32_bf16(fa[mi], fb[ni], acc[mi][ni], 0, 0, 0);
    __syncthreads();
  }

  const float* sqm = sq + (size_t)m * NN;
  unsigned short* Dm = Dreg + (size_t)mL * NN2;
  int gr0 = by * 128 + wy * 64;
  int gc0 = bx * 128 + wx * 64;
  unsigned hmax = 0;
  unsigned long long* b1 = best1 + (size_t)m * NN;
  unsigned long long ck[4];
  #pragma unroll
  for (int i = 0; i < 4; ++i) ck[i] = ~0ull;
  unsigned short us[4][4][4];

  #pragma unroll
  for (int mi = 0; mi < 4; ++mi) {
    int rb = gr0 + mi * 16 + lk * 4;
    float sqi0 = sqm[rb + 0], sqi1 = sqm[rb + 1], sqi2 = sqm[rb + 2], sqi3 = sqm[rb + 3];
    unsigned long long rk[4];
    #pragma unroll
    for (int j = 0; j < 4; ++j) rk[j] = ~0ull;
    #pragma unroll
    for (int ni = 0; ni < 4; ++ni) {
      int col = gc0 + ni * 16 + lr;
      float sqj = sqm[col];
      f32x4 a = acc[mi][ni];
      unsigned short h0 = f2bf(sqrtf(fmaxf(sqi0 + sqj - 2.f * a[0], 0.f)));
      unsigned short h1 = f2bf(sqrtf(fmaxf(sqi1 + sqj - 2.f * a[1], 0.f)));
      unsigned short h2 = f2bf(sqrtf(fmaxf(sqi2 + sqj - 2.f * a[2], 0.f)));
      unsigned short h3 = f2bf(sqrtf(fmaxf(sqi3 + sqj - 2.f * a[3], 0.f)));
      us[mi][ni][0] = h0; us[mi][ni][1] = h1;
      us[mi][ni][2] = h2; us[mi][ni][3] = h3;
      unsigned hm01 = (h0 > h1) ? h0 : h1;
      unsigned hm23 = (h2 > h3) ? h2 : h3;
      unsigned hm = (hm01 > hm23) ? hm01 : hm23;
      hmax = (hm > hmax) ? hm : hmax;
      unsigned short hh[4] = {h0, h1, h2, h3};
      #pragma unroll
      for (int rg = 0; rg < 4; ++rg) {
        int row = rb + rg;
        if (!diag || col != row) {
          unsigned lo = (row < col) ? (unsigned)(row * NN + col)
                                    : (unsigned)(col * NN + row);
          unsigned long long key = ((unsigned long long)hh[rg] << 48) | lo;
          rk[rg] = u64min(rk[rg], key);
          ck[ni] = u64min(ck[ni], key);
        }
      }
    }
    #pragma unroll
    for (int rg = 0; rg < 4; ++rg) {
      unsigned long long k = grp16_min_u64(rk[rg]);
      if (lr == 15) atomicMin(&b1[rb + rg], k);
    }
  }
  if (!diag) {
    #pragma unroll
    for (int ni = 0; ni < 4; ++ni) {
      unsigned long long k = ck[ni];
      k = u64min(k, __shfl_xor(k, 16));
      k = u64min(k, __shfl_xor(k, 32));
      if (lk == 0) atomicMin(&b1[gc0 + ni * 16 + lr], k);
    }
  }

  __syncthreads();                                   // staging LDS dead
  unsigned short* W = &P[0][0] + wid * 1216;         // 16 x 76 ushort per-wave
  int rlo = lane >> 4, cq = lane & 15;
  #pragma unroll
  for (int mi = 0; mi < 4; ++mi) {
    #pragma unroll
    for (int ni = 0; ni < 4; ++ni)
      #pragma unroll
      for (int j = 0; j < 4; ++j)
        W[(lk * 4 + j) * 76 + ni * 16 + lr] = us[mi][ni][j];
    #pragma unroll
    for (int g = 0; g < 4; ++g) {
      int r16 = g * 4 + rlo;
      ushort4 t = *(const ushort4*)&W[r16 * 76 + cq * 4];
      *(ushort4*)(Dm + (size_t)(gr0 + mi * 16 + r16) * NN + gc0 + cq * 4) = t;
    }
  }
  if (!diag) {
    #pragma unroll
    for (int ni = 0; ni < 4; ++ni) {
      #pragma unroll
      for (int mi = 0; mi < 4; ++mi)
        *(ushort4*)&W[lr * 76 + mi * 16 + lk * 4] =
            make_ushort4(us[mi][ni][0], us[mi][ni][1], us[mi][ni][2], us[mi][ni][3]);
      #pragma unroll
      for (int g = 0; g < 4; ++g) {
        int r16 = g * 4 + rlo;
        ushort4 t = *(const ushort4*)&W[r16 * 76 + cq * 4];
        *(ushort4*)(Dm + (size_t)(gc0 + ni * 16 + r16) * NN + gr0 + cq * 4) = t;
      }
    }
  }

  #pragma unroll
  for (int off = 32; off > 0; off >>= 1) {
    unsigned o = (unsigned)__shfl_down((int)hmax, off);
    hmax = (o > hmax) ? o : hmax;
  }
  if (lane == 0) atomicMax(&maxBits[m], hmax << 16);
}

// -------- phase-2 scan + inlined phase-1 hook + DcG init (unchanged) ------------
__global__ __launch_bounds__(512) void scan2_kernel(const unsigned short* __restrict__ Dreg,
                                                    const unsigned long long* __restrict__ best1,
                                                    int* __restrict__ compG,
                                                    unsigned long long* __restrict__ best2,
                                                    unsigned long long* __restrict__ DcG,
                                                    int2* __restrict__ eo_all,
                                                    int* __restrict__ ecntG, int m0) {
  int sblk = blockIdx.x, mL = blockIdx.y, m = m0 + mL;
  const unsigned short* D = Dreg + (size_t)mL * NN2;
  __shared__ int compP[NN + 64];
  __shared__ int hook[NN], parent[NN];
  __shared__ int ecnt;
  int tid = threadIdx.x;
  int wave = tid >> 6, lane = tid & 63;
  int c0 = lane * 8;

  unsigned long long* dginit = DcG + (size_t)mL * 16384 + sblk * 2048;
  #pragma unroll
  for (int i = 0; i < 4; ++i) dginit[tid + i * 512] = ~0ull;

  if (tid == 0) ecnt = 0;
  unsigned long long b = best1[(size_t)m * NN + tid];
  int h;
  if (b != ~0ull) {
    int idx = (int)(unsigned)b & 0x3ffff;
    int er = idx >> 9, ec = idx & 511;
    h = (er == tid) ? ec : er;
  } else h = tid;
  hook[tid] = h;
  __syncthreads();
  bool active = (b != ~0ull);
  int p = h;
  bool mutual = active && (hook[p] == tid);
  parent[tid] = (!active) ? tid : ((mutual && tid < p) ? tid : p);
  if (sblk == 0 && active && (!mutual || tid > p)) {
    int idx = (int)(unsigned)b & 0x3ffff;
    int e = atomicAdd(&ecnt, 1);
    eo_all[(size_t)m * (NN - 1) + e] = make_int2(idx >> 9, idx & 511);
  }
  __syncthreads();
  int c = tid, pp = parent[c];
  while (pp != c) { c = pp; pp = parent[c]; }
  compP[tid + (tid >> 3)] = c;
  if (sblk == 0) {
    compG[(size_t)m * NN + tid] = c;
    if (tid == 0) ecntG[m] = ecnt;
  }
  __syncthreads();

  unsigned long long* b2 = best2 + (size_t)m * NN;
  #pragma unroll
  for (int rr = 0; rr < 8; ++rr) {
    int r = sblk * 64 + wave * 8 + rr;
    int cr = compP[r + (r >> 3)];
    uint4 dv = *(const uint4*)(D + (size_t)r * NN + c0);
    int4 cc0 = *(const int4*)(compP + c0 + (c0 >> 3));
    int4 cc1 = *(const int4*)(compP + c0 + 4 + (c0 >> 3));
    unsigned hh[8] = {dv.x & 0xffffu, dv.x >> 16, dv.y & 0xffffu, dv.y >> 16,
                      dv.z & 0xffffu, dv.z >> 16, dv.w & 0xffffu, dv.w >> 16};
    int cv[8] = {cc0.x, cc0.y, cc0.z, cc0.w, cc1.x, cc1.y, cc1.z, cc1.w};
    unsigned long long k = ~0ull;
    #pragma unroll
    for (int e = 0; e < 8; ++e) {
      if (cv[e] != cr) {
        int col = c0 + e;
        int lo = (r < col) ? r * NN + col : col * NN + r;
        unsigned long long key = ((unsigned long long)hh[e] << 48) | (unsigned)lo;
        k = u64min(k, key);
      }
    }
    k = wave_min_u64(k);
    if (lane == 63 && k != ~0ull) atomicMin(&b2[cr], k);
  }
}

// ---- deterministic inline hook2 (BARRIER-UNIFORM: call from ALL threads) -------
__device__ __forceinline__ void hook2_inline(const unsigned long long* b2m,
                                             const int* compG_m, int tid, bool valid,
                                             int wave, int lane, bool emit,
                                             int2* eo, int* ecnt,
                                             int* comp, int* hookA, int* parentA,
                                             unsigned long long* rootMask,
                                             int* denseOut, int* Cout) {
  unsigned long long b = ~0ull;
  if (valid) { comp[tid] = compG_m[tid]; b = b2m[tid]; }
  __syncthreads();
  int h = tid;
  if (valid && b != ~0ull) {
    int idx = (int)(unsigned)b & 0x3ffff;
    int er = idx >> 9, ec = idx & 511;
    int c1 = comp[er], c2 = comp[ec];
    h = (c1 == tid) ? c2 : c1;
  }
  if (valid) hookA[tid] = h;
  __syncthreads();
  if (valid) {
    bool active = (b != ~0ull);
    int p = h;
    bool mutual = active && (hookA[p] == tid);
    parentA[tid] = (!active) ? tid : ((mutual && tid < p) ? tid : p);
    if (emit && active && (!mutual || tid > p)) {
      int idx = (int)(unsigned)b & 0x3ffff;
      int e = atomicAdd(ecnt, 1);
      eo[e] = make_int2(idx >> 9, idx & 511);
    }
  }
  __syncthreads();
  int c = 0;
  bool isRoot = false;
  if (valid) {
    c = comp[tid];
    int pp = parentA[c];
    while (pp != c) { c = pp; pp = parentA[c]; }
    isRoot = (c == tid);
  }
  unsigned long long rm = __ballot(isRoot);
  if (valid && lane == 0) rootMask[wave] = rm;   // valid => wave < 8
  __syncthreads();
  int cw = c >> 6, cl = c & 63;
  int dense = 0, C = 0;
  #pragma unroll
  for (int w = 0; w < 8; ++w) {
    int pc = __popcll(rootMask[w]);
    C += pc;
    if (w < cw) dense += pc;
  }
  dense += __popcll(rootMask[cw] & (cl ? ((~0ull) >> (64 - cl)) : 0ull));
  *denseOut = dense;
  *Cout = C;
}

// -------- contraction (+inlined hook2): build Dc from bf16 D --------------------
__global__ __launch_bounds__(512) void contract_kernel(const unsigned short* __restrict__ Dreg,
                                                       const unsigned long long* __restrict__ best2,
                                                       const int* __restrict__ compG,
                                                       unsigned long long* __restrict__ DcG,
                                                       int2* __restrict__ eo_all,
                                                       int* __restrict__ ecntG, int m0) {
  int q = blockIdx.x, mL = blockIdx.y, m = m0 + mL;
  const unsigned short* D = Dreg + (size_t)mL * NN2;
  __shared__ unsigned long long Dc[128 * 128];
  __shared__ int comp[NN], hookA[NN], parentA[NN];
  __shared__ int c2P[NN + 64];
  __shared__ unsigned long long rootMask[8];
  __shared__ int ecnt;
  int tid = threadIdx.x;
  int wave = tid >> 6, lane = tid & 63;
  int c0 = lane * 8;
  for (int i = tid; i < 16384; i += 512) Dc[i] = ~0ull;
  if (tid == 0) ecnt = ecntG[m];
  __syncthreads();
  int dense, C;
  hook2_inline(best2 + (size_t)m * NN, compG + (size_t)m * NN, tid, true, wave, lane,
               q == 0, eo_all + (size_t)m * (NN - 1), &ecnt,
               comp, hookA, parentA, rootMask, &dense, &C);
  c2P[tid + (tid >> 3)] = dense;
  __syncthreads();
  if (q == 0 && tid == 0) ecntG[m] = ecnt;

  #pragma unroll
  for (int rr = 0; rr < 16; ++rr) {
    int r = q * 128 + wave * 16 + rr;
    int di = c2P[r + (r >> 3)];
    uint4 dv = *(const uint4*)(D + (size_t)r * NN + c0);
    int4 cc0 = *(const int4*)(c2P + c0 + (c0 >> 3));
    int4 cc1 = *(const int4*)(c2P + c0 + 4 + (c0 >> 3));
    unsigned hh[8] = {dv.x & 0xffffu, dv.x >> 16, dv.y & 0xffffu, dv.y >> 16,
                      dv.z & 0xffffu, dv.z >> 16, dv.w & 0xffffu, dv.w >> 16};
    int cv[8] = {cc0.x, cc0.y, cc0.z, cc0.w, cc1.x, cc1.y, cc1.z, cc1.w};
    #pragma unroll
    for (int e = 0; e < 8; ++e) {
      if (cv[e] != di) {
        int col = c0 + e;
        int lo = (r < col) ? r * NN + col : col * NN + r;
        unsigned long long key = ((unsigned long long)hh[e] << 48) | (unsigned)lo;
        amin64(&Dc[di * 128 + cv[e]], key);
      }
    }
  }
  __syncthreads();
  unsigned long long* dg = DcG + (size_t)mL * 16384;
  for (int i = tid; i < 16384; i += 512) {
    unsigned long long v = Dc[i];
    if (v != ~0ull) atomicMin(&dg[i], v);
  }
}

// -------- finish (+inlined hook2 labels): LDS phases + fused gather -------------
__global__ __launch_bounds__(1024) void finish_kernel(const unsigned short* __restrict__ Dreg,
                                                      const unsigned long long* __restrict__ DcG,
                                                      const unsigned long long* __restrict__ best2,
                                                      const int* __restrict__ compG,
                                                      int2* __restrict__ eo_all,
                                                      int* __restrict__ ecntG,
                                                      const unsigned* __restrict__ maxBits,
                                                      float* __restrict__ out, int m0) {
  int mL = blockIdx.x, m = m0 + mL;
  __shared__ unsigned long long Dc[16384];
  __shared__ int c2n[NN];
  __shared__ int comp[NN], hookA[NN], parentA[NN];
  __shared__ unsigned long long rootMask[8];
  __shared__ unsigned long long best[128];
  __shared__ int comp2[128], hook128[128], parent128[128];
  __shared__ float fred[16];
  __shared__ int ecnt, Csh;
  int tid = threadIdx.x;
  int wave = tid >> 6, lane = tid & 63;
  const unsigned long long* dg = DcG + (size_t)mL * 16384;
  for (int i = tid; i < 16384; i += 1024) Dc[i] = dg[i];
  if (tid < 128) comp2[tid] = tid;
  if (tid == 0) ecnt = ecntG[m];
  __syncthreads();
  {
    int dense, C;
    hook2_inline(best2 + (size_t)m * NN, compG + (size_t)m * NN, tid, tid < NN,
                 wave, lane, false, nullptr, nullptr,
                 comp, hookA, parentA, rootMask, &dense, &C);
    if (tid < NN) c2n[tid] = dense;
    if (tid == 0) Csh = C;
  }
  __syncthreads();
  int C = Csh;
  int2* eo = eo_all + (size_t)m * (NN - 1);

  for (int ph = 0; ph < 7; ++ph) {
    if (ecnt >= NN - 1) break;
    if (tid < 128) best[tid] = ~0ull;
    __syncthreads();
    for (int i = tid; i < C * 128; i += 1024) {
      unsigned long long key = Dc[i];
      if (key == ~0ull) continue;
      int a = i >> 7, bb = i & 127;
      int ca = comp2[a], cb = comp2[bb];
      if (ca != cb) amin64(&best[ca], key);
    }
    __syncthreads();
    if (tid < C) {
      unsigned long long b = best[tid];
      int h;
      if (b != ~0ull) {
        int pid = (int)(unsigned)b & 0x3ffff;
        int er = pid >> 9, ec = pid & 511;
        int c1 = comp2[c2n[er]], c2v = comp2[c2n[ec]];
        h = (c1 == tid) ? c2v : c1;
      } else h = tid;
      hook128[tid] = h;
    }
    __syncthreads();
    if (tid < C) {
      unsigned long long b = best[tid];
      bool active = (b != ~0ull);
      int p = hook128[tid];
      bool mutual = active && (hook128[p] == tid);
      parent128[tid] = (!active) ? tid : ((mutual && tid < p) ? tid : p);
      if (active && (!mutual || tid > p)) {
        int pid = (int)(unsigned)b & 0x3ffff;
        int e = atomicAdd(&ecnt, 1);
        eo[e] = make_int2(pid >> 9, pid & 511);
      }
    }
    __syncthreads();
    if (tid < C) {
      int c = comp2[tid], pp = parent128[c];
      while (pp != c) { c = pp; pp = parent128[c]; }
      comp2[tid] = c;
    }
    __syncthreads();
  }
  __syncthreads();

  // fused loss gather (bf16 D)
  int b = m >> 1;
  float mxX = fmaxf(__uint_as_float(maxBits[2 * b]), 1e-12f);
  float mxZ = fmaxf(__uint_as_float(maxBits[2 * b + 1]), 1e-12f);
  float rX = 1.0f / mxX, rZ = 1.0f / mxZ;
  const unsigned short* Dx = Dreg + (size_t)(mL & ~1) * NN2;
  const unsigned short* Dz = Dx + NN2;
  float acc = 0.f;
  if (tid < NN - 1) {
    int2 e = eo[tid];
    size_t off = (size_t)e.x * NN + e.y;
    float d = bf2f(Dx[off]) * rX - bf2f(Dz[off]) * rZ;
    acc = d * d;
  }
  #pragma unroll
  for (int o = 32; o > 0; o >>= 1) acc += __shfl_down(acc, o);
  if (lane == 0) fred[wave] = acc;
  __syncthreads();
  if (tid == 0) {
    float t = 0.f;
    #pragma unroll
    for (int i = 0; i < 16; ++i) t += fred[i];
    atomicAdd(out, t * (1.0f / NB));
  }
}

extern "C" void kernel_launch(void* const* d_in, const int* in_sizes, int n_in,
                              void* d_out, int out_size, void* d_ws, size_t ws_size,
                              hipStream_t stream) {
  const float* model = (const float*)d_in[0];
  const float* labels = (const float*)d_in[1];
  float* out = (float*)d_out;
  char* ws = (char*)d_ws;

  float*              sq      = (float*)(ws);                       // 131072
  unsigned*           maxBits = (unsigned*)(ws + 131072);           // -> 132096
  int2*               eo      = (int2*)(ws + 132096);               // -> 393728
  unsigned long long* best1   = (unsigned long long*)(ws + 393728); // -> 655872
  unsigned long long* best2   = (unsigned long long*)(ws + 655872); // -> 918016
  int*                compG   = (int*)(ws + 918016);                // -> 1049088
  int*                ecntG   = (int*)(ws + 1049088);               // -> 1049344
  size_t base = 1050624;

  // per batch (2 matrices): D bf16 1MB + Hi 1MB + Dc 256KB
  size_t perBatch = 2ull * (NN2 * 2 + NN2 * 2 + 16384 * 8);
  size_t dcap = (ws_size > base) ? (ws_size - base) : 0;
  int cb = (int)(dcap / perBatch);
  if (cb > NB) cb = NB;
  if (cb < 1) cb = 1;
  int nmc = 2 * cb;

  unsigned short* Dreg = (unsigned short*)(ws + base);
  unsigned short* Hi = Dreg + (size_t)nmc * NN2;
  unsigned long long* DcG = (unsigned long long*)(Hi + (size_t)nmc * NN2);

  hipMemsetAsync(d_out, 0, sizeof(float), stream);
  hipMemsetAsync(maxBits, 0, 64 * sizeof(unsigned), stream);

  for (int b0 = 0; b0 < NB; b0 += cb) {
    int nb = (NB - b0 < cb) ? (NB - b0) : cb;
    int nm = 2 * nb, m0 = 2 * b0;
    split_kernel<<<nm * 256, 256, 0, stream>>>(model, labels, Hi, sq,
                                               best1, best2, m0);
    gemm_dist<<<10 * nm, 256, 0, stream>>>(Hi, sq, Dreg, maxBits, best1, m0, nm);
    scan2_kernel<<<dim3(8, nm), 512, 0, stream>>>(Dreg, best1, compG, best2, DcG,
                                                  eo, ecntG, m0);
    contract_kernel<<<dim3(4, nm), 512, 0, stream>>>(Dreg, best2, compG, DcG,
                                                     eo, ecntG, m0);
    finish_kernel<<<nm, 1024, 0, stream>>>(Dreg, DcG, best2, compG, eo, ecntG,
                                           maxBits, out, m0);
  }
}

// Round 24
// 119.892 us; speedup vs baseline: 1.5623x; 1.0340x over previous
//
#include <hip/hip_runtime.h>
#include <math.h>

#define NN 512
#define NN2 (NN*NN)
#define NB 32
#define NM 64

typedef __attribute__((ext_vector_type(8))) short short8v;   // 8 bf16 (4 VGPR)
typedef __attribute__((ext_vector_type(4))) float f32x4;     // MFMA acc

typedef const unsigned int __attribute__((address_space(1)))* gas_ptr;
typedef unsigned int __attribute__((address_space(3)))* las_ptr;

__device__ __forceinline__ float sigm(float x) { return 1.0f / (1.0f + expf(-x)); }

__device__ __forceinline__ unsigned short f2bf(float x) {
  unsigned u = __float_as_uint(x);
  return (unsigned short)((u + 0x7fffu + ((u >> 16) & 1u)) >> 16);   // RNE
}
__device__ __forceinline__ float bf2f(unsigned short h) {
  return __uint_as_float(((unsigned)h) << 16);
}
__device__ __forceinline__ unsigned long long u64min(unsigned long long a,
                                                     unsigned long long b) {
  return (b < a) ? b : a;
}
__device__ __forceinline__ void amin64(unsigned long long* p, unsigned long long v) {
  unsigned long long old = *p;
  while (v < old) {
    unsigned long long assumed = old;
    old = atomicCAS(p, assumed, v);
    if (old == assumed) break;
  }
}
template <int CTRL>
__device__ __forceinline__ unsigned long long dpp_min_u64(unsigned long long x) {
  int xlo = (int)(unsigned)x, xhi = (int)(unsigned)(x >> 32);
  int ylo = __builtin_amdgcn_update_dpp(xlo, xlo, CTRL, 0xf, 0xf, false);
  int yhi = __builtin_amdgcn_update_dpp(xhi, xhi, CTRL, 0xf, 0xf, false);
  unsigned long long y = ((unsigned long long)(unsigned)yhi << 32) | (unsigned)ylo;
  return (y < x) ? y : x;
}
__device__ __forceinline__ unsigned long long wave_min_u64(unsigned long long k) {
  k = dpp_min_u64<0x111>(k); k = dpp_min_u64<0x112>(k);
  k = dpp_min_u64<0x114>(k); k = dpp_min_u64<0x118>(k);
  k = dpp_min_u64<0x142>(k); k = dpp_min_u64<0x143>(k);
  return k;
}
__device__ __forceinline__ unsigned long long grp16_min_u64(unsigned long long k) {
  k = dpp_min_u64<0x111>(k); k = dpp_min_u64<0x112>(k);
  k = dpp_min_u64<0x114>(k); k = dpp_min_u64<0x118>(k);
  return k;
}

// -------- sigmoid + bf16 quantize + fused sq + best1/2 init ---------------------
__global__ __launch_bounds__(256) void split_kernel(const float* __restrict__ model,
                                                    const float* __restrict__ labels,
                                                    unsigned short* __restrict__ Hi,
                                                    float* __restrict__ sq,
                                                    unsigned long long* __restrict__ best1,
                                                    unsigned long long* __restrict__ best2,
                                                    int m0) {
  int b = blockIdx.x;
  int mL = b >> 8;
  int m = m0 + mL;
  int tid = threadIdx.x;
  size_t off = (size_t)(b & 255) * 1024 + tid * 4;
  const float* src = ((m & 1) ? labels + (size_t)(m >> 1) * NN2
                              : model + (size_t)(m >> 1) * NN2) + off;
  float4 v = *(const float4*)src;
  if (!(m & 1)) { v.x = sigm(v.x); v.y = sigm(v.y); v.z = sigm(v.z); v.w = sigm(v.w); }
  ushort4 h;
  h.x = f2bf(v.x); h.y = f2bf(v.y); h.z = f2bf(v.z); h.w = f2bf(v.w);
  *(ushort4*)(Hi + (size_t)mL * NN2 + off) = h;
  if (tid == 0) {
    int bi = (b & 255) * 2;
    best1[(size_t)m * NN + bi]     = ~0ull;
    best1[(size_t)m * NN + bi + 1] = ~0ull;
    best2[(size_t)m * NN + bi]     = ~0ull;
    best2[(size_t)m * NN + bi + 1] = ~0ull;
  }
  float s = v.x * v.x + v.y * v.y + v.z * v.z + v.w * v.w;
  #pragma unroll
  for (int o = 32; o > 0; o >>= 1) s += __shfl_down(s, o);
  __shared__ float red[4];
  if ((tid & 63) == 0) red[tid >> 6] = s;
  __syncthreads();
  if (tid == 0) {
    int row0 = (b & 255) * 2;
    sq[(size_t)m * NN + row0]     = red[0] + red[1];
    sq[(size_t)m * NN + row0 + 1] = red[2] + red[3];
  }
}

// ------- distance matrix: hh-only, double-buffered staging (P[1],P[3] = buf1) ---
__global__ __launch_bounds__(256, 3) void gemm_dist(const unsigned short* __restrict__ Hi,
                                                    const float* __restrict__ sq,
                                                    unsigned short* __restrict__ Dreg,
                                                    unsigned* __restrict__ maxBits,
                                                    unsigned long long* __restrict__ best1,
                                                    int m0, int nm) {
  __shared__ unsigned short P[4][4096];   // buf0: P[0](A),P[2](B); buf1: P[1],P[3]
  int id = blockIdx.x;
  int p, mL;
  if ((nm & 7) == 0) {
    int x = id & 7, t = id >> 3;
    p = t % 10;
    mL = x + 8 * (t / 10);
  } else {
    p = id % 10;
    mL = id / 10;
  }
  int by = (p >= 4) + (p >= 7) + (p >= 9);
  int bx = p - ((by * (7 - by)) >> 1);
  bool diag = (by == bx);
  int m = m0 + mL;
  const unsigned short* Hm = Hi + (size_t)mL * NN2;

  int tid = threadIdx.x;
  int wid = tid >> 6, lane = tid & 63;
  int wy = wid >> 1, wx = wid & 1;
  int lr = lane & 15, lk = lane >> 4;

  int wrow0 = (wid < 2) ? by * 128 : bx * 128;
  // stage Ah (wave 0); non-diag also Bh (wave 2)
  bool stage = (wid == 0) || (!diag && wid == 2);
  int srow = lane >> 2;
  int schunk = (lane & 3) ^ ((lane >> 3) & 3);
  const unsigned short* gsrc = Hm + (size_t)(wrow0 + srow) * NN + schunk * 8;
  unsigned short* ldst0 = &P[wid & 3][0];       // buf b: ldst0 + b*4096

  f32x4 acc[4][4];
  #pragma unroll
  for (int i = 0; i < 4; ++i)
    #pragma unroll
    for (int j = 0; j < 4; ++j) acc[i][j] = (f32x4){0.f, 0.f, 0.f, 0.f};

  int sw = (lr >> 1) & 3;
  int rao = (wy * 64 + lr) * 32 + (lk ^ sw) * 8;
  int rbo = (wx * 64 + lr) * 32 + (lk ^ sw) * 8;

  // prologue: stage buf 0 (k0 = 0)
  if (stage) {
    #pragma unroll
    for (int i = 0; i < 8; ++i)
      __builtin_amdgcn_global_load_lds(
          (gas_ptr)(const void*)(gsrc + (size_t)i * 16 * NN),
          (las_ptr)(void*)(ldst0 + i * 512), 16, 0, 0);
  }

  for (int s = 0; s < 16; ++s) {
    int buf = s & 1;
    __syncthreads();                 // buf[s&1] landed (vmcnt drained at barrier)
    if (s < 15 && stage) {           // prefetch next step into the other buffer;
      int k0 = (s + 1) * 32;         // latency hides under this step's work
      unsigned short* ld = ldst0 + (buf ^ 1) * 4096;
      #pragma unroll
      for (int i = 0; i < 8; ++i)
        __builtin_amdgcn_global_load_lds(
            (gas_ptr)(const void*)(gsrc + k0 + (size_t)i * 16 * NN),
            (las_ptr)(void*)(ld + i * 512), 16, 0, 0);
    }
    const unsigned short* bAh = &P[buf][0];
    const unsigned short* bBh = diag ? &P[buf][0] : &P[2 + buf][0];

    short8v fa[4], fb[4];
    #pragma unroll
    for (int i = 0; i < 4; ++i) {
      fa[i] = *(const short8v*)(bAh + rao + i * 512);   // Ah
      fb[i] = *(const short8v*)(bBh + rbo + i * 512);   // Bh (diag: Ah)
    }
    #pragma unroll
    for (int mi = 0; mi < 4; ++mi)
      #pragma unroll
      for (int ni = 0; ni < 4; ++ni)
        acc[mi][ni] = __builtin_amdgcn_mfma_f32_16x16x32_bf16(fa[mi], fb[ni], acc[mi][ni], 0, 0, 0);
  }

  const float* sqm = sq + (size_t)m * NN;
  unsigned short* Dm = Dreg + (size_t)mL * NN2;
  int gr0 = by * 128 + wy * 64;
  int gc0 = bx * 128 + wx * 64;
  unsigned hmax = 0;
  unsigned long long* b1 = best1 + (size_t)m * NN;
  unsigned long long ck[4];
  #pragma unroll
  for (int i = 0; i < 4; ++i) ck[i] = ~0ull;
  unsigned short us[4][4][4];

  #pragma unroll
  for (int mi = 0; mi < 4; ++mi) {
    int rb = gr0 + mi * 16 + lk * 4;
    float sqi0 = sqm[rb + 0], sqi1 = sqm[rb + 1], sqi2 = sqm[rb + 2], sqi3 = sqm[rb + 3];
    unsigned long long rk[4];
    #pragma unroll
    for (int j = 0; j < 4; ++j) rk[j] = ~0ull;
    #pragma unroll
    for (int ni = 0; ni < 4; ++ni) {
      int col = gc0 + ni * 16 + lr;
      float sqj = sqm[col];
      f32x4 a = acc[mi][ni];
      unsigned short h0 = f2bf(sqrtf(fmaxf(sqi0 + sqj - 2.f * a[0], 0.f)));
      unsigned short h1 = f2bf(sqrtf(fmaxf(sqi1 + sqj - 2.f * a[1], 0.f)));
      unsigned short h2 = f2bf(sqrtf(fmaxf(sqi2 + sqj - 2.f * a[2], 0.f)));
      unsigned short h3 = f2bf(sqrtf(fmaxf(sqi3 + sqj - 2.f * a[3], 0.f)));
      us[mi][ni][0] = h0; us[mi][ni][1] = h1;
      us[mi][ni][2] = h2; us[mi][ni][3] = h3;
      unsigned hm01 = (h0 > h1) ? h0 : h1;
      unsigned hm23 = (h2 > h3) ? h2 : h3;
      unsigned hm = (hm01 > hm23) ? hm01 : hm23;
      hmax = (hm > hmax) ? hm : hmax;
      unsigned short hh[4] = {h0, h1, h2, h3};
      #pragma unroll
      for (int rg = 0; rg < 4; ++rg) {
        int row = rb + rg;
        if (!diag || col != row) {
          unsigned lo = (row < col) ? (unsigned)(row * NN + col)
                                    : (unsigned)(col * NN + row);
          unsigned long long key = ((unsigned long long)hh[rg] << 48) | lo;
          rk[rg] = u64min(rk[rg], key);
          ck[ni] = u64min(ck[ni], key);
        }
      }
    }
    #pragma unroll
    for (int rg = 0; rg < 4; ++rg) {
      unsigned long long k = grp16_min_u64(rk[rg]);
      if (lr == 15) atomicMin(&b1[rb + rg], k);
    }
  }
  if (!diag) {
    #pragma unroll
    for (int ni = 0; ni < 4; ++ni) {
      unsigned long long k = ck[ni];
      k = u64min(k, __shfl_xor(k, 16));
      k = u64min(k, __shfl_xor(k, 32));
      if (lk == 0) atomicMin(&b1[gc0 + ni * 16 + lr], k);
    }
  }

  __syncthreads();                                   // staging LDS dead
  unsigned short* W = &P[0][0] + wid * 1216;         // 16 x 76 ushort per-wave
  int rlo = lane >> 4, cq = lane & 15;
  #pragma unroll
  for (int mi = 0; mi < 4; ++mi) {
    #pragma unroll
    for (int ni = 0; ni < 4; ++ni)
      #pragma unroll
      for (int j = 0; j < 4; ++j)
        W[(lk * 4 + j) * 76 + ni * 16 + lr] = us[mi][ni][j];
    #pragma unroll
    for (int g = 0; g < 4; ++g) {
      int r16 = g * 4 + rlo;
      ushort4 t = *(const ushort4*)&W[r16 * 76 + cq * 4];
      *(ushort4*)(Dm + (size_t)(gr0 + mi * 16 + r16) * NN + gc0 + cq * 4) = t;
    }
  }
  if (!diag) {
    #pragma unroll
    for (int ni = 0; ni < 4; ++ni) {
      #pragma unroll
      for (int mi = 0; mi < 4; ++mi)
        *(ushort4*)&W[lr * 76 + mi * 16 + lk * 4] =
            make_ushort4(us[mi][ni][0], us[mi][ni][1], us[mi][ni][2], us[mi][ni][3]);
      #pragma unroll
      for (int g = 0; g < 4; ++g) {
        int r16 = g * 4 + rlo;
        ushort4 t = *(const ushort4*)&W[r16 * 76 + cq * 4];
        *(ushort4*)(Dm + (size_t)(gc0 + ni * 16 + r16) * NN + gr0 + cq * 4) = t;
      }
    }
  }

  #pragma unroll
  for (int off = 32; off > 0; off >>= 1) {
    unsigned o = (unsigned)__shfl_down((int)hmax, off);
    hmax = (o > hmax) ? o : hmax;
  }
  if (lane == 0) atomicMax(&maxBits[m], hmax << 16);
}

// -------- phase-2 scan + inlined phase-1 hook + DcG init (unchanged) ------------
__global__ __launch_bounds__(512) void scan2_kernel(const unsigned short* __restrict__ Dreg,
                                                    const unsigned long long* __restrict__ best1,
                                                    int* __restrict__ compG,
                                                    unsigned long long* __restrict__ best2,
                                                    unsigned long long* __restrict__ DcG,
                                                    int2* __restrict__ eo_all,
                                                    int* __restrict__ ecntG, int m0) {
  int sblk = blockIdx.x, mL = blockIdx.y, m = m0 + mL;
  const unsigned short* D = Dreg + (size_t)mL * NN2;
  __shared__ int compP[NN + 64];
  __shared__ int hook[NN], parent[NN];
  __shared__ int ecnt;
  int tid = threadIdx.x;
  int wave = tid >> 6, lane = tid & 63;
  int c0 = lane * 8;

  unsigned long long* dginit = DcG + (size_t)mL * 16384 + sblk * 2048;
  #pragma unroll
  for (int i = 0; i < 4; ++i) dginit[tid + i * 512] = ~0ull;

  if (tid == 0) ecnt = 0;
  unsigned long long b = best1[(size_t)m * NN + tid];
  int h;
  if (b != ~0ull) {
    int idx = (int)(unsigned)b & 0x3ffff;
    int er = idx >> 9, ec = idx & 511;
    h = (er == tid) ? ec : er;
  } else h = tid;
  hook[tid] = h;
  __syncthreads();
  bool active = (b != ~0ull);
  int p = h;
  bool mutual = active && (hook[p] == tid);
  parent[tid] = (!active) ? tid : ((mutual && tid < p) ? tid : p);
  if (sblk == 0 && active && (!mutual || tid > p)) {
    int idx = (int)(unsigned)b & 0x3ffff;
    int e = atomicAdd(&ecnt, 1);
    eo_all[(size_t)m * (NN - 1) + e] = make_int2(idx >> 9, idx & 511);
  }
  __syncthreads();
  int c = tid, pp = parent[c];
  while (pp != c) { c = pp; pp = parent[c]; }
  compP[tid + (tid >> 3)] = c;
  if (sblk == 0) {
    compG[(size_t)m * NN + tid] = c;
    if (tid == 0) ecntG[m] = ecnt;
  }
  __syncthreads();

  unsigned long long* b2 = best2 + (size_t)m * NN;
  #pragma unroll
  for (int rr = 0; rr < 8; ++rr) {
    int r = sblk * 64 + wave * 8 + rr;
    int cr = compP[r + (r >> 3)];
    uint4 dv = *(const uint4*)(D + (size_t)r * NN + c0);
    int4 cc0 = *(const int4*)(compP + c0 + (c0 >> 3));
    int4 cc1 = *(const int4*)(compP + c0 + 4 + (c0 >> 3));
    unsigned hh[8] = {dv.x & 0xffffu, dv.x >> 16, dv.y & 0xffffu, dv.y >> 16,
                      dv.z & 0xffffu, dv.z >> 16, dv.w & 0xffffu, dv.w >> 16};
    int cv[8] = {cc0.x, cc0.y, cc0.z, cc0.w, cc1.x, cc1.y, cc1.z, cc1.w};
    unsigned long long k = ~0ull;
    #pragma unroll
    for (int e = 0; e < 8; ++e) {
      if (cv[e] != cr) {
        int col = c0 + e;
        int lo = (r < col) ? r * NN + col : col * NN + r;
        unsigned long long key = ((unsigned long long)hh[e] << 48) | (unsigned)lo;
        k = u64min(k, key);
      }
    }
    k = wave_min_u64(k);
    if (lane == 63 && k != ~0ull) atomicMin(&b2[cr], k);
  }
}

// ---- deterministic inline hook2 (BARRIER-UNIFORM: call from ALL threads) -------
__device__ __forceinline__ void hook2_inline(const unsigned long long* b2m,
                                             const int* compG_m, int tid, bool valid,
                                             int wave, int lane, bool emit,
                                             int2* eo, int* ecnt,
                                             int* comp, int* hookA, int* parentA,
                                             unsigned long long* rootMask,
                                             int* denseOut, int* Cout) {
  unsigned long long b = ~0ull;
  if (valid) { comp[tid] = compG_m[tid]; b = b2m[tid]; }
  __syncthreads();
  int h = tid;
  if (valid && b != ~0ull) {
    int idx = (int)(unsigned)b & 0x3ffff;
    int er = idx >> 9, ec = idx & 511;
    int c1 = comp[er], c2 = comp[ec];
    h = (c1 == tid) ? c2 : c1;
  }
  if (valid) hookA[tid] = h;
  __syncthreads();
  if (valid) {
    bool active = (b != ~0ull);
    int p = h;
    bool mutual = active && (hookA[p] == tid);
    parentA[tid] = (!active) ? tid : ((mutual && tid < p) ? tid : p);
    if (emit && active && (!mutual || tid > p)) {
      int idx = (int)(unsigned)b & 0x3ffff;
      int e = atomicAdd(ecnt, 1);
      eo[e] = make_int2(idx >> 9, idx & 511);
    }
  }
  __syncthreads();
  int c = 0;
  bool isRoot = false;
  if (valid) {
    c = comp[tid];
    int pp = parentA[c];
    while (pp != c) { c = pp; pp = parentA[c]; }
    isRoot = (c == tid);
  }
  unsigned long long rm = __ballot(isRoot);
  if (valid && lane == 0) rootMask[wave] = rm;   // valid => wave < 8
  __syncthreads();
  int cw = c >> 6, cl = c & 63;
  int dense = 0, C = 0;
  #pragma unroll
  for (int w = 0; w < 8; ++w) {
    int pc = __popcll(rootMask[w]);
    C += pc;
    if (w < cw) dense += pc;
  }
  dense += __popcll(rootMask[cw] & (cl ? ((~0ull) >> (64 - cl)) : 0ull));
  *denseOut = dense;
  *Cout = C;
}

// -------- contraction (+inlined hook2): build Dc from bf16 D --------------------
__global__ __launch_bounds__(512) void contract_kernel(const unsigned short* __restrict__ Dreg,
                                                       const unsigned long long* __restrict__ best2,
                                                       const int* __restrict__ compG,
                                                       unsigned long long* __restrict__ DcG,
                                                       int2* __restrict__ eo_all,
                                                       int* __restrict__ ecntG, int m0) {
  int q = blockIdx.x, mL = blockIdx.y, m = m0 + mL;
  const unsigned short* D = Dreg + (size_t)mL * NN2;
  __shared__ unsigned long long Dc[128 * 128];
  __shared__ int comp[NN], hookA[NN], parentA[NN];
  __shared__ int c2P[NN + 64];
  __shared__ unsigned long long rootMask[8];
  __shared__ int ecnt;
  int tid = threadIdx.x;
  int wave = tid >> 6, lane = tid & 63;
  int c0 = lane * 8;
  for (int i = tid; i < 16384; i += 512) Dc[i] = ~0ull;
  if (tid == 0) ecnt = ecntG[m];
  __syncthreads();
  int dense, C;
  hook2_inline(best2 + (size_t)m * NN, compG + (size_t)m * NN, tid, true, wave, lane,
               q == 0, eo_all + (size_t)m * (NN - 1), &ecnt,
               comp, hookA, parentA, rootMask, &dense, &C);
  c2P[tid + (tid >> 3)] = dense;
  __syncthreads();
  if (q == 0 && tid == 0) ecntG[m] = ecnt;

  #pragma unroll
  for (int rr = 0; rr < 16; ++rr) {
    int r = q * 128 + wave * 16 + rr;
    int di = c2P[r + (r >> 3)];
    uint4 dv = *(const uint4*)(D + (size_t)r * NN + c0);
    int4 cc0 = *(const int4*)(c2P + c0 + (c0 >> 3));
    int4 cc1 = *(const int4*)(c2P + c0 + 4 + (c0 >> 3));
    unsigned hh[8] = {dv.x & 0xffffu, dv.x >> 16, dv.y & 0xffffu, dv.y >> 16,
                      dv.z & 0xffffu, dv.z >> 16, dv.w & 0xffffu, dv.w >> 16};
    int cv[8] = {cc0.x, cc0.y, cc0.z, cc0.w, cc1.x, cc1.y, cc1.z, cc1.w};
    #pragma unroll
    for (int e = 0; e < 8; ++e) {
      if (cv[e] != di) {
        int col = c0 + e;
        int lo = (r < col) ? r * NN + col : col * NN + r;
        unsigned long long key = ((unsigned long long)hh[e] << 48) | (unsigned)lo;
        amin64(&Dc[di * 128 + cv[e]], key);
      }
    }
  }
  __syncthreads();
  unsigned long long* dg = DcG + (size_t)mL * 16384;
  for (int i = tid; i < 16384; i += 512) {
    unsigned long long v = Dc[i];
    if (v != ~0ull) atomicMin(&dg[i], v);
  }
}

// -------- finish (+inlined hook2 labels): LDS phases + fused gather -------------
__global__ __launch_bounds__(1024) void finish_kernel(const unsigned short* __restrict__ Dreg,
                                                      const unsigned long long* __restrict__ DcG,
                                                      const unsigned long long* __restrict__ best2,
                                                      const int* __restrict__ compG,
                                                      int2* __restrict__ eo_all,
                                                      int* __restrict__ ecntG,
                                                      const unsigned* __restrict__ maxBits,
                                                      float* __restrict__ out, int m0) {
  int mL = blockIdx.x, m = m0 + mL;
  __shared__ unsigned long long Dc[16384];
  __shared__ int c2n[NN];
  __shared__ int comp[NN], hookA[NN], parentA[NN];
  __shared__ unsigned long long rootMask[8];
  __shared__ unsigned long long best[128];
  __shared__ int comp2[128], hook128[128], parent128[128];
  __shared__ float fred[16];
  __shared__ int ecnt, Csh;
  int tid = threadIdx.x;
  int wave = tid >> 6, lane = tid & 63;
  const unsigned long long* dg = DcG + (size_t)mL * 16384;
  for (int i = tid; i < 16384; i += 1024) Dc[i] = dg[i];
  if (tid < 128) comp2[tid] = tid;
  if (tid == 0) ecnt = ecntG[m];
  __syncthreads();
  {
    int dense, C;
    hook2_inline(best2 + (size_t)m * NN, compG + (size_t)m * NN, tid, tid < NN,
                 wave, lane, false, nullptr, nullptr,
                 comp, hookA, parentA, rootMask, &dense, &C);
    if (tid < NN) c2n[tid] = dense;
    if (tid == 0) Csh = C;
  }
  __syncthreads();
  int C = Csh;
  int2* eo = eo_all + (size_t)m * (NN - 1);

  for (int ph = 0; ph < 7; ++ph) {
    if (ecnt >= NN - 1) break;
    if (tid < 128) best[tid] = ~0ull;
    __syncthreads();
    for (int i = tid; i < C * 128; i += 1024) {
      unsigned long long key = Dc[i];
      if (key == ~0ull) continue;
      int a = i >> 7, bb = i & 127;
      int ca = comp2[a], cb = comp2[bb];
      if (ca != cb) amin64(&best[ca], key);
    }
    __syncthreads();
    if (tid < C) {
      unsigned long long b = best[tid];
      int h;
      if (b != ~0ull) {
        int pid = (int)(unsigned)b & 0x3ffff;
        int er = pid >> 9, ec = pid & 511;
        int c1 = comp2[c2n[er]], c2v = comp2[c2n[ec]];
        h = (c1 == tid) ? c2v : c1;
      } else h = tid;
      hook128[tid] = h;
    }
    __syncthreads();
    if (tid < C) {
      unsigned long long b = best[tid];
      bool active = (b != ~0ull);
      int p = hook128[tid];
      bool mutual = active && (hook128[p] == tid);
      parent128[tid] = (!active) ? tid : ((mutual && tid < p) ? tid : p);
      if (active && (!mutual || tid > p)) {
        int pid = (int)(unsigned)b & 0x3ffff;
        int e = atomicAdd(&ecnt, 1);
        eo[e] = make_int2(pid >> 9, pid & 511);
      }
    }
    __syncthreads();
    if (tid < C) {
      int c = comp2[tid], pp = parent128[c];
      while (pp != c) { c = pp; pp = parent128[c]; }
      comp2[tid] = c;
    }
    __syncthreads();
  }
  __syncthreads();

  // fused loss gather (bf16 D)
  int b = m >> 1;
  float mxX = fmaxf(__uint_as_float(maxBits[2 * b]), 1e-12f);
  float mxZ = fmaxf(__uint_as_float(maxBits[2 * b + 1]), 1e-12f);
  float rX = 1.0f / mxX, rZ = 1.0f / mxZ;
  const unsigned short* Dx = Dreg + (size_t)(mL & ~1) * NN2;
  const unsigned short* Dz = Dx + NN2;
  float acc = 0.f;
  if (tid < NN - 1) {
    int2 e = eo[tid];
    size_t off = (size_t)e.x * NN + e.y;
    float d = bf2f(Dx[off]) * rX - bf2f(Dz[off]) * rZ;
    acc = d * d;
  }
  #pragma unroll
  for (int o = 32; o > 0; o >>= 1) acc += __shfl_down(acc, o);
  if (lane == 0) fred[wave] = acc;
  __syncthreads();
  if (tid == 0) {
    float t = 0.f;
    #pragma unroll
    for (int i = 0; i < 16; ++i) t += fred[i];
    atomicAdd(out, t * (1.0f / NB));
  }
}

extern "C" void kernel_launch(void* const* d_in, const int* in_sizes, int n_in,
                              void* d_out, int out_size, void* d_ws, size_t ws_size,
                              hipStream_t stream) {
  const float* model = (const float*)d_in[0];
  const float* labels = (const float*)d_in[1];
  float* out = (float*)d_out;
  char* ws = (char*)d_ws;

  float*              sq      = (float*)(ws);                       // 131072
  unsigned*           maxBits = (unsigned*)(ws + 131072);           // -> 132096
  int2*               eo      = (int2*)(ws + 132096);               // -> 393728
  unsigned long long* best1   = (unsigned long long*)(ws + 393728); // -> 655872
  unsigned long long* best2   = (unsigned long long*)(ws + 655872); // -> 918016
  int*                compG   = (int*)(ws + 918016);                // -> 1049088
  int*                ecntG   = (int*)(ws + 1049088);               // -> 1049344
  size_t base = 1050624;

  // per batch (2 matrices): D bf16 1MB + Hi 1MB + Dc 256KB
  size_t perBatch = 2ull * (NN2 * 2 + NN2 * 2 + 16384 * 8);
  size_t dcap = (ws_size > base) ? (ws_size - base) : 0;
  int cb = (int)(dcap / perBatch);
  if (cb > NB) cb = NB;
  if (cb < 1) cb = 1;
  int nmc = 2 * cb;

  unsigned short* Dreg = (unsigned short*)(ws + base);
  unsigned short* Hi = Dreg + (size_t)nmc * NN2;
  unsigned long long* DcG = (unsigned long long*)(Hi + (size_t)nmc * NN2);

  hipMemsetAsync(d_out, 0, sizeof(float), stream);
  hipMemsetAsync(maxBits, 0, 64 * sizeof(unsigned), stream);

  for (int b0 = 0; b0 < NB; b0 += cb) {
    int nb = (NB - b0 < cb) ? (NB - b0) : cb;
    int nm = 2 * nb, m0 = 2 * b0;
    split_kernel<<<nm * 256, 256, 0, stream>>>(model, labels, Hi, sq,
                                               best1, best2, m0);
    gemm_dist<<<10 * nm, 256, 0, stream>>>(Hi, sq, Dreg, maxBits, best1, m0, nm);
    scan2_kernel<<<dim3(8, nm), 512, 0, stream>>>(Dreg, best1, compG, best2, DcG,
                                                  eo, ecntG, m0);
    contract_kernel<<<dim3(4, nm), 512, 0, stream>>>(Dreg, best2, compG, DcG,
                                                     eo, ecntG, m0);
    finish_kernel<<<nm, 1024, 0, stream>>>(Dreg, DcG, best2, compG, eo, ecntG,
                                           maxBits, out, m0);
  }
}